// Round 11
// baseline (1770.879 us; speedup 1.0000x reference)
//
#include <hip/hip_runtime.h>
#include <hip/hip_bf16.h>
#include <math.h>

#define DEV __device__ __forceinline__

namespace {
constexpr int B_ = 4, T_ = 8, N_ = 3000, E_ = 12000;
constexpr int OUTS_ = 45001;  // per-batch output stride: N*7 + E + E + 1
}

using f32x4 = __attribute__((ext_vector_type(4))) float;
using bf16x8 = __attribute__((ext_vector_type(8))) short;

DEV float sigm_(float x) { return 1.0f / (1.0f + expf(-x)); }
DEV float softplus_(float x) { return fmaxf(x, 0.0f) + log1pf(expf(-fabsf(x))); }
DEV float wred_(float v) {
  #pragma unroll
  for (int o = 32; o > 0; o >>= 1) v += __shfl_xor(v, o, 64);
  return v;
}
DEV unsigned short f2bf(float x) {  // RNE fp32->bf16
  unsigned u = __float_as_uint(x);
  return (unsigned short)((u + 0x7FFFu + ((u >> 16) & 1u)) >> 16);
}
DEV unsigned f2bf2(float a, float b) {
  return (unsigned)f2bf(a) | ((unsigned)f2bf(b) << 16);
}
DEV float bfs(unsigned short u) { return __uint_as_float((unsigned)u << 16); }
DEV float bfl(unsigned u) { return __uint_as_float(u << 16); }
DEV float bfh(unsigned u) { return __uint_as_float(u & 0xffff0000u); }

// ---------------------------------------------------------------------------
// Batched weight transpose+convert: L matrices [K][N] -> per-matrix [N][K] bf16
// ---------------------------------------------------------------------------
__global__ void wtb_k(const float* __restrict__ W, unsigned short* __restrict__ Wt,
                      int K, int N, int total)
{
  const int idx = blockIdx.x * blockDim.x + threadIdx.x;
  if (idx >= total) return;
  const int kn = K * N;
  const int l = idx / kn;
  const int r = idx - l * kn;
  const int k = r / N, n = r - k * N;
  Wt[(size_t)l * kn + (size_t)n * K + k] = f2bf(W[idx]);
}

// LSTM weight permute: orig col n = gate*256+d -> newcol = d*4+gate; dense [1024][512]
__global__ void wtp_k(const float* __restrict__ W, unsigned short* __restrict__ Wt,
                      int kOff)
{
  const int idx = blockIdx.x * blockDim.x + threadIdx.x;
  if (idx >= 256 * 1024) return;
  const int k = idx >> 10;
  const int n = idx & 1023;
  const int newcol = (n & 255) * 4 + (n >> 8);
  Wt[(size_t)newcol * 512 + kOff + k] = f2bf(W[idx]);
}

// ---------------------------------------------------------------------------
// CSR build (deterministic)
// ---------------------------------------------------------------------------
__global__ void hist_k(const int* __restrict__ dst, int* __restrict__ deg)
{
  const int e = blockIdx.x * blockDim.x + threadIdx.x;
  if (e < E_) atomicAdd(&deg[dst[e]], 1);
}

__global__ __launch_bounds__(256) void scan_k(const int* __restrict__ deg,
                                              int* __restrict__ roff)
{
  __shared__ int part[256];
  const int t = threadIdx.x;
  int loc[12];
  int s = 0;
  #pragma unroll
  for (int i = 0; i < 12; ++i) {
    const int n = t * 12 + i;
    loc[i] = s;
    s += (n < N_) ? deg[n] : 0;
  }
  part[t] = s;
  __syncthreads();
  if (t == 0) {
    int run = 0;
    for (int i = 0; i < 256; ++i) { const int v = part[i]; part[i] = run; run += v; }
  }
  __syncthreads();
  const int base = part[t];
  #pragma unroll
  for (int i = 0; i < 12; ++i) {
    const int n = t * 12 + i;
    if (n < N_) roff[n] = base + loc[i];
  }
  if (t == 0) roff[N_] = E_;
}

__global__ __launch_bounds__(256) void fill_k(const int* __restrict__ dst,
                                              const int* __restrict__ roff,
                                              int* __restrict__ eord)
{
  const int n = blockIdx.x * 4 + (threadIdx.x >> 6);
  if (n >= N_) return;
  const int lane = threadIdx.x & 63;
  const unsigned long long ltm = (1ull << lane) - 1ull;
  int cnt = roff[n];
  for (int c = 0; c < E_; c += 64) {
    const int e = c + lane;
    const bool m = (e < E_) && (dst[e] == n);
    const unsigned long long mask = __ballot(m);
    if (m) eord[cnt + __popcll(mask & ltm)] = e;
    cnt += __popcll(mask);
  }
}

// ---------------------------------------------------------------------------
// 128x64-tile MFMA bf16 GEMM: C[M,N] = A[M,K](bf16) @ Wt(bf16,[N][K])
// flags: 1 = C += (fp32 C), 2 = relu, 4 = store bf16 C.
// ---------------------------------------------------------------------------
__global__ __launch_bounds__(256) void gemm_bfa_k(
    const unsigned short* __restrict__ A, const unsigned short* __restrict__ Wt,
    const float* __restrict__ bias, void* __restrict__ Cv,
    int M, int N, int K, int lda, int flags)
{
  __shared__ unsigned short Al[128 * 40];
  __shared__ unsigned short Bl[64 * 40];
  const int tid = threadIdx.x;
  const int bm = blockIdx.y * 128;
  const int bn = blockIdx.x * 64;
  const int lane = tid & 63;
  const int wv = tid >> 6;
  const int wm = (wv >> 1) * 64;
  const int wn = (wv & 1) * 32;
  const int s_row = tid >> 1;
  const int s_cb = (tid & 1) * 16;
  const int grow = bm + s_row;
  const unsigned short* Arow = (grow < M) ? A + (size_t)grow * lda : nullptr;
  const int b_col = tid >> 2;
  const int b_ks = (tid & 3) * 8;
  const unsigned short* Wrow = Wt + (size_t)(bn + b_col) * K + b_ks;

  f32x4 acc[4][2] = {};
  const int l15 = lane & 15;
  const int lk = (lane >> 4) * 8;

  for (int k0 = 0; k0 < K; k0 += 32) {
    uint4 a0, a1;
    if (Arow) {
      a0 = *(const uint4*)(Arow + k0 + s_cb);
      a1 = *(const uint4*)(Arow + k0 + s_cb + 8);
    } else {
      a0 = make_uint4(0, 0, 0, 0);
      a1 = a0;
    }
    *(uint4*)&Al[s_row * 40 + s_cb] = a0;
    *(uint4*)&Al[s_row * 40 + s_cb + 8] = a1;
    *(uint4*)&Bl[b_col * 40 + b_ks] = *(const uint4*)(Wrow + k0);
    __syncthreads();
    bf16x8 af[4], bfr[2];
    #pragma unroll
    for (int m = 0; m < 4; ++m)
      af[m] = *(const bf16x8*)&Al[(wm + m * 16 + l15) * 40 + lk];
    #pragma unroll
    for (int n = 0; n < 2; ++n)
      bfr[n] = *(const bf16x8*)&Bl[(wn + n * 16 + l15) * 40 + lk];
    #pragma unroll
    for (int m = 0; m < 4; ++m)
      #pragma unroll
      for (int n = 0; n < 2; ++n)
        acc[m][n] = __builtin_amdgcn_mfma_f32_16x16x32_bf16(af[m], bfr[n], acc[m][n], 0, 0, 0);
    __syncthreads();
  }
  float* Cf = (float*)Cv;
  unsigned short* Cb = (unsigned short*)Cv;
  const int r4 = (lane >> 4) * 4;
  #pragma unroll
  for (int m = 0; m < 4; ++m) {
    #pragma unroll
    for (int n = 0; n < 2; ++n) {
      const int col = bn + wn + n * 16 + l15;
      const float bv = bias ? bias[col] : 0.f;
      #pragma unroll
      for (int r = 0; r < 4; ++r) {
        const int row = bm + wm + m * 16 + r4 + r;
        if (row >= M) continue;
        float v = acc[m][n][r] + bv;
        const size_t ci = (size_t)row * N + col;
        if (flags & 1) v += Cf[ci];
        if (flags & 2) v = fmaxf(v, 0.f);
        if (flags & 4) Cb[ci] = f2bf(v);
        else Cf[ci] = v;
      }
    }
  }
}

// ---------------------------------------------------------------------------
// Fused stage-A kernel: per block = 16 nodes (48 A-rows), full N=768 in-block.
// qkv = [env|infra|robot rows] @ wt_qkv + bqkv (bf16 in LDS only), then
// 3x3 per-head attention + query-average -> obar (bf16, only HBM output).
// LDS: staging Al 48x40 + Bl 768x40 (65,280 B); epilogue reuses as
// P1(qk, stride 520) / P2(v, stride 272) + cs[16][8][3] floats.
// ---------------------------------------------------------------------------
__global__ __launch_bounds__(256) void qkv_attn_k(
    const float* __restrict__ env, const float* __restrict__ infra,
    const float* __restrict__ robot, const unsigned short* __restrict__ Wt,
    const float* __restrict__ bias, unsigned short* __restrict__ obar)
{
  __shared__ unsigned short U[32640];
  unsigned short* Al = U;            // 48*40 = 1920
  unsigned short* Bl = U + 1920;     // 768*40 = 30720
  unsigned short* P  = U;            // epilogue panels
  float* csL = (float*)(U + 25088);  // 16*8*3 floats

  const int tid = threadIdx.x;
  const int lane = tid & 63;
  const int wv = tid >> 6;
  const int l15 = lane & 15;
  const int lk = (lane >> 4) * 8;
  const int r4 = (lane >> 4) * 4;
  const int nodeBase = blockIdx.x * 16;

  // A-staging source (hoisted): threads 0..191, task -> (row, kseg)
  const float* Asrc = nullptr;
  int a_ks = 0, a_row = 0;
  if (tid < 192) {
    a_row = tid >> 2;
    a_ks = (tid & 3) * 8;
    const int grow = blockIdx.x * 48 + a_row;
    const int node = grow / 3, slot = grow % 3;
    const float* sp = (slot == 0 ? env : (slot == 1 ? infra : robot));
    Asrc = sp + (size_t)node * 256 + a_ks;
  }

  f32x4 acc[3][12] = {};

  for (int k0 = 0; k0 < 256; k0 += 32) {
    if (Asrc) {
      const float4 v0 = *(const float4*)(Asrc + k0);
      const float4 v1 = *(const float4*)(Asrc + k0 + 4);
      uint4 o;
      o.x = f2bf2(v0.x, v0.y); o.y = f2bf2(v0.z, v0.w);
      o.z = f2bf2(v1.x, v1.y); o.w = f2bf2(v1.z, v1.w);
      *(uint4*)&Al[a_row * 40 + a_ks] = o;
    }
    #pragma unroll
    for (int i = 0; i < 12; ++i) {
      const int task = tid + i * 256;     // 0..3071
      const int col = task >> 2;
      const int ks = (task & 3) * 8;
      *(uint4*)&Bl[col * 40 + ks] = *(const uint4*)(Wt + (size_t)col * 256 + k0 + ks);
    }
    __syncthreads();
    bf16x8 af[3];
    #pragma unroll
    for (int m = 0; m < 3; ++m)
      af[m] = *(const bf16x8*)&Al[(m * 16 + l15) * 40 + lk];
    #pragma unroll
    for (int n = 0; n < 12; ++n) {
      const bf16x8 bfr = *(const bf16x8*)&Bl[(wv * 192 + n * 16 + l15) * 40 + lk];
      #pragma unroll
      for (int m = 0; m < 3; ++m)
        acc[m][n] = __builtin_amdgcn_mfma_f32_16x16x32_bf16(af[m], bfr, acc[m][n], 0, 0, 0);
    }
    __syncthreads();
  }

  // ---- phase 0: write qk panel (cols < 512), stride 520 ----
  #pragma unroll
  for (int n = 0; n < 12; ++n) {
    const int pcol = wv * 192 + n * 16 + l15;
    if (pcol < 512) {
      const float bv = bias[pcol];
      #pragma unroll
      for (int m = 0; m < 3; ++m)
        #pragma unroll
        for (int r = 0; r < 4; ++r)
          P[(m * 16 + r4 + r) * 520 + pcol] = f2bf(acc[m][n][r] + bv);
    }
  }
  __syncthreads();

  // ---- phase 1: attention dots + softmax -> cs ----
  const int h = lane >> 3;
  const int j = (lane & 7) * 4;
  #pragma unroll
  for (int q = 0; q < 4; ++q) {
    const int nb = wv * 4 + q;
    float qv[3][4], kv[3][4];
    #pragma unroll
    for (int s = 0; s < 3; ++s) {
      const int row = nb * 3 + s;
      const uint2 uq = *(const uint2*)&P[row * 520 + h * 32 + j];
      const uint2 uk = *(const uint2*)&P[row * 520 + 256 + h * 32 + j];
      qv[s][0] = bfl(uq.x); qv[s][1] = bfh(uq.x); qv[s][2] = bfl(uq.y); qv[s][3] = bfh(uq.y);
      kv[s][0] = bfl(uk.x); kv[s][1] = bfh(uk.x); kv[s][2] = bfl(uk.y); kv[s][3] = bfh(uk.y);
    }
    float att[3][3];
    #pragma unroll
    for (int s = 0; s < 3; ++s)
      #pragma unroll
      for (int t = 0; t < 3; ++t) {
        float d = qv[s][0] * kv[t][0] + qv[s][1] * kv[t][1]
                + qv[s][2] * kv[t][2] + qv[s][3] * kv[t][3];
        d += __shfl_xor(d, 1, 64);
        d += __shfl_xor(d, 2, 64);
        d += __shfl_xor(d, 4, 64);
        att[s][t] = d * 0.17677669529663687f;
      }
    float cs[3] = {0.f, 0.f, 0.f};
    #pragma unroll
    for (int s = 0; s < 3; ++s) {
      const float m = fmaxf(att[s][0], fmaxf(att[s][1], att[s][2]));
      const float e0 = expf(att[s][0] - m);
      const float e1 = expf(att[s][1] - m);
      const float e2 = expf(att[s][2] - m);
      const float inv = (1.f / 3.f) / (e0 + e1 + e2);
      cs[0] += e0 * inv; cs[1] += e1 * inv; cs[2] += e2 * inv;
    }
    if ((lane & 7) == 0) {
      csL[nb * 24 + h * 3 + 0] = cs[0];
      csL[nb * 24 + h * 3 + 1] = cs[1];
      csL[nb * 24 + h * 3 + 2] = cs[2];
    }
  }
  __syncthreads();

  // ---- phase 2: write v panel (cols >= 512), stride 272 ----
  #pragma unroll
  for (int n = 0; n < 12; ++n) {
    const int pcol = wv * 192 + n * 16 + l15;
    if (pcol >= 512) {
      const float bv = bias[pcol];
      const int vc = pcol - 512;
      #pragma unroll
      for (int m = 0; m < 3; ++m)
        #pragma unroll
        for (int r = 0; r < 4; ++r)
          P[(m * 16 + r4 + r) * 272 + vc] = f2bf(acc[m][n][r] + bv);
    }
  }
  __syncthreads();

  // ---- phase 3: weighted V-average -> obar ----
  #pragma unroll
  for (int q = 0; q < 4; ++q) {
    const int nb = wv * 4 + q;
    const float c0 = csL[nb * 24 + h * 3 + 0];
    const float c1 = csL[nb * 24 + h * 3 + 1];
    const float c2 = csL[nb * 24 + h * 3 + 2];
    float o[4] = {0.f, 0.f, 0.f, 0.f};
    const float cc[3] = {c0, c1, c2};
    #pragma unroll
    for (int s = 0; s < 3; ++s) {
      const uint2 uv = *(const uint2*)&P[(nb * 3 + s) * 272 + h * 32 + j];
      o[0] += cc[s] * bfl(uv.x);
      o[1] += cc[s] * bfh(uv.x);
      o[2] += cc[s] * bfl(uv.y);
      o[3] += cc[s] * bfh(uv.y);
    }
    uint2 ob;
    ob.x = f2bf2(o[0], o[1]);
    ob.y = f2bf2(o[2], o[3]);
    *(uint2*)(obar + (size_t)(nodeBase + nb) * 256 + lane * 4) = ob;
  }
}

// ---------------------------------------------------------------------------
// Fused LSTM step: gates = [gat_t | h] @ Wt_perm (K=512, newcol = d*4+gate),
// then LSTM pointwise in epilogue via LDS transpose. Writes c, h (fp32), hbOut.
// ---------------------------------------------------------------------------
__global__ __launch_bounds__(256) void gemm_lstm_k(
    const unsigned short* __restrict__ gatall, const unsigned short* __restrict__ hbIn,
    const unsigned short* __restrict__ Wt, const float* __restrict__ b_lstm,
    float* __restrict__ h, float* __restrict__ c, unsigned short* __restrict__ hbOut,
    int t)
{
  __shared__ float Gl[128][65];
  unsigned short* Al = (unsigned short*)&Gl[0][0];
  unsigned short* Bl = Al + 128 * 40;
  const int tid = threadIdx.x;
  const int bm = blockIdx.y * 128;
  const int bn = blockIdx.x * 64;
  const int lane = tid & 63;
  const int wv = tid >> 6;
  const int wm = (wv >> 1) * 64;
  const int wn = (wv & 1) * 32;
  const int s_row = tid >> 1;
  const int s_cb = (tid & 1) * 16;
  const int grow = bm + s_row;
  const unsigned short* Arow1 = nullptr;
  const unsigned short* Arow2 = nullptr;
  if (grow < 12000) {
    const int phys = (grow / N_) * (T_ * N_) + t * N_ + (grow % N_);
    Arow1 = gatall + (size_t)phys * 256;
    Arow2 = hbIn + (size_t)grow * 256;
  }
  const int b_col = tid >> 2;
  const int b_ks = (tid & 3) * 8;
  const unsigned short* Wrow = Wt + (size_t)(bn + b_col) * 512 + b_ks;

  f32x4 acc[4][2] = {};
  const int l15 = lane & 15;
  const int lk = (lane >> 4) * 8;

  for (int k0 = 0; k0 < 512; k0 += 32) {
    uint4 a0, a1;
    if (Arow1) {
      const unsigned short* p = (k0 < 256) ? (Arow1 + k0 + s_cb)
                                           : (Arow2 + (k0 - 256) + s_cb);
      a0 = *(const uint4*)p;
      a1 = *(const uint4*)(p + 8);
    } else {
      a0 = make_uint4(0, 0, 0, 0);
      a1 = a0;
    }
    *(uint4*)&Al[s_row * 40 + s_cb] = a0;
    *(uint4*)&Al[s_row * 40 + s_cb + 8] = a1;
    *(uint4*)&Bl[b_col * 40 + b_ks] = *(const uint4*)(Wrow + k0);
    __syncthreads();
    bf16x8 af[4], bfr[2];
    #pragma unroll
    for (int m = 0; m < 4; ++m)
      af[m] = *(const bf16x8*)&Al[(wm + m * 16 + l15) * 40 + lk];
    #pragma unroll
    for (int n = 0; n < 2; ++n)
      bfr[n] = *(const bf16x8*)&Bl[(wn + n * 16 + l15) * 40 + lk];
    #pragma unroll
    for (int m = 0; m < 4; ++m)
      #pragma unroll
      for (int n = 0; n < 2; ++n)
        acc[m][n] = __builtin_amdgcn_mfma_f32_16x16x32_bf16(af[m], bfr[n], acc[m][n], 0, 0, 0);
    __syncthreads();
  }
  const int r4 = (lane >> 4) * 4;
  #pragma unroll
  for (int m = 0; m < 4; ++m)
    #pragma unroll
    for (int n = 0; n < 2; ++n) {
      const int col = wn + n * 16 + l15;
      #pragma unroll
      for (int r = 0; r < 4; ++r)
        Gl[wm + m * 16 + r4 + r][col] = acc[m][n][r];
    }
  __syncthreads();
  const int fl = lane & 7;
  const int rg = lane >> 3;
  const int dg = ((bn + wn) >> 2) + fl;
  const float bi = b_lstm[dg];
  const float bff = b_lstm[256 + dg];
  const float bg = b_lstm[512 + dg];
  const float bo = b_lstm[768 + dg];
  const int colb = wn + fl * 4;
  #pragma unroll
  for (int i = 0; i < 8; ++i) {
    const int rl = rg + i * 8;
    const int row = bm + wm + rl;
    if (row >= 12000) continue;
    const float g0 = Gl[wm + rl][colb + 0] + bi;
    const float g1 = Gl[wm + rl][colb + 1] + bff;
    const float g2 = Gl[wm + rl][colb + 2] + bg;
    const float g3 = Gl[wm + rl][colb + 3] + bo;
    const size_t idx = (size_t)row * 256 + dg;
    const float cn = sigm_(g1) * c[idx] + sigm_(g0) * tanhf(g2);
    c[idx] = cn;
    const float hn = sigm_(g3) * tanhf(cn);
    h[idx] = hn;
    hbOut[idx] = f2bf(hn);
  }
}

// ---------------------------------------------------------------------------
// fp32 fallback GEMM (only the K=8 edge-emb GEMM); flags&4 -> bf16 C store
// ---------------------------------------------------------------------------
__global__ __launch_bounds__(256) void gemm_k(
    const float* __restrict__ A, const float* __restrict__ W,
    const float* __restrict__ bias, void* __restrict__ Cv,
    int M, int N, int K, int lda, int flags)
{
  __shared__ float As[16][68];
  __shared__ float Ws[16][64];
  const int tid = threadIdx.x;
  const int bm = blockIdx.y * 64;
  const int bn = blockIdx.x * 64;
  const int tx = tid & 15;
  const int ty = tid >> 4;
  const int ar = tid >> 2;
  const int ac = (tid & 3) << 2;
  const int wr = tid >> 4;
  const int wc = (tid & 15) << 2;
  const int grow = bm + ar;
  const float* Arow = (grow < M) ? A + (size_t)grow * lda : nullptr;
  float acc[4][4] = {};
  for (int k0 = 0; k0 < K; k0 += 16) {
    float4 av = make_float4(0.f, 0.f, 0.f, 0.f);
    if (Arow) {
      av.x = (k0 + ac + 0 < K) ? Arow[k0 + ac + 0] : 0.f;
      av.y = (k0 + ac + 1 < K) ? Arow[k0 + ac + 1] : 0.f;
      av.z = (k0 + ac + 2 < K) ? Arow[k0 + ac + 2] : 0.f;
      av.w = (k0 + ac + 3 < K) ? Arow[k0 + ac + 3] : 0.f;
    }
    As[ac + 0][ar] = av.x;
    As[ac + 1][ar] = av.y;
    As[ac + 2][ar] = av.z;
    As[ac + 3][ar] = av.w;
    float4 wv = make_float4(0.f, 0.f, 0.f, 0.f);
    if (k0 + wr < K) {
      const int gc = bn + wc;
      const float* wp = W + (size_t)(k0 + wr) * N + gc;
      wv.x = (gc + 0 < N) ? wp[0] : 0.f;
      wv.y = (gc + 1 < N) ? wp[1] : 0.f;
      wv.z = (gc + 2 < N) ? wp[2] : 0.f;
      wv.w = (gc + 3 < N) ? wp[3] : 0.f;
    }
    *(float4*)&Ws[wr][wc] = wv;
    __syncthreads();
    #pragma unroll
    for (int kk = 0; kk < 16; ++kk) {
      const float4 a = *(const float4*)&As[kk][ty << 2];
      const float4 b = *(const float4*)&Ws[kk][tx << 2];
      acc[0][0] += a.x * b.x; acc[0][1] += a.x * b.y; acc[0][2] += a.x * b.z; acc[0][3] += a.x * b.w;
      acc[1][0] += a.y * b.x; acc[1][1] += a.y * b.y; acc[1][2] += a.y * b.z; acc[1][3] += a.y * b.w;
      acc[2][0] += a.z * b.x; acc[2][1] += a.z * b.y; acc[2][2] += a.z * b.z; acc[2][3] += a.z * b.w;
      acc[3][0] += a.w * b.x; acc[3][1] += a.w * b.y; acc[3][2] += a.w * b.z; acc[3][3] += a.w * b.w;
    }
    __syncthreads();
  }
  float* Cf = (float*)Cv;
  unsigned short* Cb = (unsigned short*)Cv;
  #pragma unroll
  for (int i = 0; i < 4; ++i) {
    const int row = bm + (ty << 2) + i;
    if (row >= M) continue;
    #pragma unroll
    for (int j = 0; j < 4; ++j) {
      const int col = bn + (tx << 2) + j;
      if (col >= N) continue;
      float v = acc[i][j];
      if (bias) v += bias[col];
      if (flags & 2) v = fmaxf(v, 0.f);
      const size_t ci = (size_t)row * N + col;
      if (flags & 4) Cb[ci] = f2bf(v);
      else Cf[ci] = v;
    }
  }
}

// LayerNorm per row; bf16 in, bf16 out. 1 wave per row.
__global__ __launch_bounds__(64) void ln_k(
    const unsigned short* __restrict__ in, const float* __restrict__ g,
    const float* __restrict__ bta, unsigned short* __restrict__ outp)
{
  const int row = blockIdx.x;
  const int d0 = threadIdx.x << 2;
  const uint2 a = *(const uint2*)(in + (size_t)row * 256 + d0);
  float x[4] = { bfl(a.x), bfh(a.x), bfl(a.y), bfh(a.y) };
  float s = x[0] + x[1] + x[2] + x[3];
  s = wred_(s);
  const float mean = s * (1.f / 256.f);
  float vs = 0.f;
  #pragma unroll
  for (int i = 0; i < 4; ++i) { const float dd = x[i] - mean; vs += dd * dd; }
  vs = wred_(vs);
  const float inv = 1.0f / sqrtf(vs * (1.f / 256.f) + 1e-5f);
  const float4 gv = *(const float4*)(g + d0);
  const float4 bv = *(const float4*)(bta + d0);
  uint2 o;
  o.x = f2bf2((x[0] - mean) * inv * gv.x + bv.x, (x[1] - mean) * inv * gv.y + bv.y);
  o.y = f2bf2((x[2] - mean) * inv * gv.z + bv.z, (x[3] - mean) * inv * gv.w + bv.w);
  *(uint2*)(outp + (size_t)row * 256 + d0) = o;
}

// ---------------------------------------------------------------------------
// GAT kernels (bf16 feature inputs)
// ---------------------------------------------------------------------------
__global__ void alphas_k(const unsigned short* __restrict__ xw, const float* __restrict__ as,
                         const float* __restrict__ ad, float* __restrict__ sal,
                         float* __restrict__ dal, int rows)
{
  const int idx = blockIdx.x * blockDim.x + threadIdx.x;
  if (idx >= rows * 8) return;
  const int row = idx >> 3, h = idx & 7;
  const unsigned short* x = xw + (size_t)row * 256 + h * 32;
  const float* a1 = as + h * 32;
  const float* a2 = ad + h * 32;
  float s = 0.f, d = 0.f;
  #pragma unroll
  for (int i = 0; i < 4; ++i) {
    const uint4 ux = *(const uint4*)(x + i * 8);
    const unsigned* p = &ux.x;
    #pragma unroll
    for (int j = 0; j < 4; ++j) {
      const float lo = bfl(p[j]), hi = bfh(p[j]);
      s += lo * a1[i * 8 + 2 * j] + hi * a1[i * 8 + 2 * j + 1];
      d += lo * a2[i * 8 + 2 * j] + hi * a2[i * 8 + 2 * j + 1];
    }
  }
  sal[idx] = s; dal[idx] = d;
}

// all 4 edge-logit sets in one launch; ew is [48000][1024] (4 x 256 packed)
__global__ void elog4_k(const unsigned short* __restrict__ ew,
                        const float* __restrict__ tg_ae, const float* __restrict__ g_ae,
                        float* __restrict__ el)
{
  const int idx = blockIdx.x * blockDim.x + threadIdx.x;
  if (idx >= 4 * 48000 * 8) return;
  const int l = idx / (48000 * 8);
  const int r = idx - l * (48000 * 8);
  const int row = r >> 3, h = r & 7;
  const unsigned short* x = ew + (size_t)row * 1024 + l * 256 + h * 32;
  const float* a1 = (l == 0 ? tg_ae : g_ae + (l - 1) * 256) + h * 32;
  float s = 0.f;
  #pragma unroll
  for (int i = 0; i < 4; ++i) {
    const uint4 ux = *(const uint4*)(x + i * 8);
    const unsigned* p = &ux.x;
    #pragma unroll
    for (int j = 0; j < 4; ++j) {
      s += bfl(p[j]) * a1[i * 8 + 2 * j] + bfh(p[j]) * a1[i * 8 + 2 * j + 1];
    }
  }
  el[l * 384000 + r] = s;
}

// Fused GAT aggregation: one wave per (beta,node). Online softmax over incoming
// edges (CSR). bf16 gathers. OUTBF: 1 -> bf16 out, 0 -> fp32 out.
template<int OUTBF>
__global__ __launch_bounds__(256) void gat_k(
    const unsigned short* __restrict__ xw, const unsigned short* __restrict__ ew,
    const float* __restrict__ sal, const float* __restrict__ dal,
    const float* __restrict__ el, const int* __restrict__ roff,
    const int* __restrict__ eord, const int* __restrict__ srcArr,
    void* __restrict__ outp, int nwaves, int tshift, int ewStride, int ewOff)
{
  const int wid = blockIdx.x * 4 + (threadIdx.x >> 6);
  if (wid >= nwaves) return;
  const int beta = wid / N_;
  const int n = wid - beta * N_;
  const int b = beta >> tshift;
  const int lane = threadIdx.x & 63;
  const int h = lane >> 3;
  const int d0 = lane << 2;
  const float dal_h = dal[(size_t)wid * 8 + h];
  const int p0 = roff[n], p1 = roff[n + 1];
  float m = -1e30f, s = 0.f;
  float4 acc = make_float4(0.f, 0.f, 0.f, 0.f);
  for (int p = p0; p < p1; ++p) {
    const int e = eord[p];
    const int sc = srcArr[e];
    float lg = sal[((size_t)beta * N_ + sc) * 8 + h] + dal_h + el[((size_t)b * E_ + e) * 8 + h];
    lg = lg > 0.f ? lg : 0.2f * lg;
    const float mn = fmaxf(m, lg);
    const float scale = expf(m - mn);
    const float w = expf(lg - mn);
    s = s * scale + w;
    const uint2 ux = *(const uint2*)(xw + ((size_t)beta * N_ + sc) * 256 + d0);
    const uint2 ue = *(const uint2*)(ew + ((size_t)(b * E_ + e)) * ewStride + ewOff + d0);
    acc.x = acc.x * scale + w * (bfl(ux.x) + bfl(ue.x));
    acc.y = acc.y * scale + w * (bfh(ux.x) + bfh(ue.x));
    acc.z = acc.z * scale + w * (bfl(ux.y) + bfl(ue.y));
    acc.w = acc.w * scale + w * (bfh(ux.y) + bfh(ue.y));
    m = mn;
  }
  const float inv = 1.0f / (s + 1e-16f);
  if (OUTBF) {
    uint2 o;
    o.x = f2bf2(acc.x * inv, acc.y * inv);
    o.y = f2bf2(acc.z * inv, acc.w * inv);
    *(uint2*)((unsigned short*)outp + (size_t)wid * 256 + d0) = o;
  } else {
    *(float4*)((float*)outp + (size_t)wid * 256 + d0) =
        make_float4(acc.x * inv, acc.y * inv, acc.z * inv, acc.w * inv);
  }
}

// h = LN(h + add); writes fp32 h and bf16 hb
__global__ __launch_bounds__(64) void resln_k(float* __restrict__ h,
                                              const float* __restrict__ add,
                                              const float* __restrict__ g,
                                              const float* __restrict__ bta,
                                              unsigned short* __restrict__ hb)
{
  const int row = blockIdx.x;
  const int d0 = threadIdx.x << 2;
  float* hp = h + (size_t)row * 256;
  const float4 hv = *(const float4*)(hp + d0);
  const float4 av = *(const float4*)(add + (size_t)row * 256 + d0);
  float x[4] = { hv.x + av.x, hv.y + av.y, hv.z + av.z, hv.w + av.w };
  float s = x[0] + x[1] + x[2] + x[3];
  s = wred_(s);
  const float mean = s * (1.f / 256.f);
  float vs = 0.f;
  #pragma unroll
  for (int i = 0; i < 4; ++i) { const float dd = x[i] - mean; vs += dd * dd; }
  vs = wred_(vs);
  const float inv = 1.0f / sqrtf(vs * (1.f / 256.f) + 1e-5f);
  const float4 gv = *(const float4*)(g + d0);
  const float4 bv = *(const float4*)(bta + d0);
  float o0 = (x[0] - mean) * inv * gv.x + bv.x;
  float o1 = (x[1] - mean) * inv * gv.y + bv.y;
  float o2 = (x[2] - mean) * inv * gv.z + bv.z;
  float o3 = (x[3] - mean) * inv * gv.w + bv.w;
  *(float4*)(hp + d0) = make_float4(o0, o1, o2, o3);
  uint2 ob;
  ob.x = f2bf2(o0, o1);
  ob.y = f2bf2(o2, o3);
  *(uint2*)(hb + (size_t)row * 256 + d0) = ob;
}

// ---------------------------------------------------------------------------
// Head kernels
// ---------------------------------------------------------------------------
__global__ void nh2_k(const float* __restrict__ hidden, const float* __restrict__ w2,
                      const float* __restrict__ b2, float* __restrict__ outp)
{
  const int idx = blockIdx.x * blockDim.x + threadIdx.x;
  if (idx >= B_ * N_ * 7) return;
  const int row = idx / 7, j = idx % 7;
  const float* hp = hidden + (size_t)row * 448 + j * 64;
  const float* wp = w2 + j * 64;
  float a = 0.f;
  #pragma unroll
  for (int u = 0; u < 64; ++u) a += hp[u] * wp[u];
  a += b2[j];
  if (j == 0 || j == 6) a = sigm_(a);
  else if (j == 1) a = softplus_(a);
  const int b = row / N_, n = row % N_;
  outp[(size_t)b * OUTS_ + n * 7 + j] = a;
}

// two-stage deterministic h_global mean
__global__ __launch_bounds__(256) void hglob1_k(const float* __restrict__ h,
                                                float* __restrict__ hgp)
{
  const int b = blockIdx.x;
  const int seg = blockIdx.y;
  const int d = threadIdx.x;
  float s = 0.f;
  const int n0 = seg * 120;
  for (int n = n0; n < n0 + 120; ++n)
    s += h[((size_t)(b * N_ + n)) * 256 + d];
  hgp[((size_t)(b * 25 + seg)) * 256 + d] = s;
}

__global__ __launch_bounds__(256) void hglob2_k(const float* __restrict__ hgp,
                                                float* __restrict__ hg)
{
  const int b = blockIdx.x;
  const int d = threadIdx.x;
  float s = 0.f;
  for (int i = 0; i < 25; ++i) s += hgp[((size_t)(b * 25 + i)) * 256 + d];
  hg[b * 256 + d] = s * (1.f / (float)N_);
}

__global__ __launch_bounds__(64) void freq_k(const float* __restrict__ hg,
                                             const float* __restrict__ w1, const float* __restrict__ b1,
                                             const float* __restrict__ w2, const float* __restrict__ b2,
                                             float* __restrict__ outp)
{
  const int b = blockIdx.x;
  const int u = threadIdx.x;
  float a = b1[u];
  for (int k = 0; k < 256; ++k) a += hg[b * 256 + k] * w1[k * 64 + u];
  a = fmaxf(a, 0.f) * w2[u];
  a = wred_(a);
  if (u == 0) outp[(size_t)b * OUTS_ + 45000] = a + b2[0];
}

// gather ef = [hb[b,src], hb[b,dst]] bf16 (B*E x 512)
__global__ void ef_k(const unsigned short* __restrict__ hb, const int* __restrict__ src,
                     const int* __restrict__ dst, unsigned short* __restrict__ ef)
{
  const int idx = blockIdx.x * blockDim.x + threadIdx.x;
  if (idx >= B_ * E_ * 64) return;
  const int q = idx & 63;
  const int row = idx >> 6;
  const int b = row / E_, e = row % E_;
  const int d = q << 3;
  const unsigned short* p = (d < 256)
      ? hb + ((size_t)(b * N_ + src[e])) * 256 + d
      : hb + ((size_t)(b * N_ + dst[e])) * 256 + (d - 256);
  *(uint4*)(ef + (size_t)row * 512 + d) = *(const uint4*)p;
}

__global__ void eh2_k(const float* __restrict__ hidden, const float* __restrict__ w2,
                      const float* __restrict__ b2, float* __restrict__ outp)
{
  const int idx = blockIdx.x * blockDim.x + threadIdx.x;
  if (idx >= 2 * B_ * E_) return;
  const int jj = idx / (B_ * E_);
  const int r = idx - jj * (B_ * E_);
  const int b = r / E_, e = r % E_;
  const float* hp = hidden + (size_t)r * 128 + jj * 64;
  const float* wp = w2 + jj * 64;
  float a = 0.f;
  #pragma unroll
  for (int u = 0; u < 64; ++u) a += hp[u] * wp[u];
  a += b2[jj];
  outp[(size_t)b * OUTS_ + 21000 + jj * 12000 + e] = a;
}

// ---------------------------------------------------------------------------
extern "C" void kernel_launch(void* const* d_in, const int* in_sizes, int n_in,
                              void* d_out, int out_size, void* d_ws, size_t ws_size,
                              hipStream_t stream)
{
  const float* env      = (const float*)d_in[0];
  const float* infra    = (const float*)d_in[1];
  const float* robot    = (const float*)d_in[2];
  const float* edgeattr = (const float*)d_in[3];
  const int*   eidx     = (const int*)d_in[4];
  const float* wqkv     = (const float*)d_in[5];
  const float* bqkv     = (const float*)d_in[6];
  const float* wo       = (const float*)d_in[7];
  const float* bo       = (const float*)d_in[8];
  const float* lnf_g    = (const float*)d_in[9];
  const float* lnf_b    = (const float*)d_in[10];
  const float* we_emb   = (const float*)d_in[11];
  const float* be_emb   = (const float*)d_in[12];
  const float* tg_W     = (const float*)d_in[13];
  const float* tg_We    = (const float*)d_in[14];
  const float* tg_asrc  = (const float*)d_in[15];
  const float* tg_adst  = (const float*)d_in[16];
  const float* tg_aedge = (const float*)d_in[17];
  const float* w_ih     = (const float*)d_in[18];
  const float* w_hh     = (const float*)d_in[19];
  const float* b_lstm   = (const float*)d_in[20];
  const float* g_W      = (const float*)d_in[21];
  const float* g_We     = (const float*)d_in[22];
  const float* g_asrc   = (const float*)d_in[23];
  const float* g_adst   = (const float*)d_in[24];
  const float* g_aedge  = (const float*)d_in[25];
  const float* g_lng    = (const float*)d_in[26];
  const float* g_lnb    = (const float*)d_in[27];
  const float* hn_w1    = (const float*)d_in[28];
  const float* hn_b1    = (const float*)d_in[29];
  const float* hn_w2    = (const float*)d_in[30];
  const float* hn_b2    = (const float*)d_in[31];
  const float* he_w1    = (const float*)d_in[32];
  const float* he_b1    = (const float*)d_in[33];
  const float* he_w2    = (const float*)d_in[34];
  const float* he_b2    = (const float*)d_in[35];

  const int* src = eidx;
  const int* dst = eidx + E_;
  float* outp = (float*)d_out;
  float* ws = (float*)d_ws;

  // ---- bf16 transposed weights at ws start (short offsets) ----
  unsigned short* wtb0 = (unsigned short*)ws;
  unsigned short* wt_qkv  = wtb0;               // 196,608
  unsigned short* wt_wo   = wtb0 + 196608;      //  65,536
  unsigned short* wt_tgW  = wtb0 + 262144;      //  65,536
  unsigned short* wt_tgWe = wtb0 + 327680;      //  65,536  (rows 0..255 of edge-cat)
  unsigned short* wt_gWe  = wtb0 + 393216;      // 196,608  (rows 256..1023, contiguous)
  unsigned short* wt_lstm = wtb0 + 589824;      // 524,288  permuted [1024][512]
  unsigned short* wt_gW   = wtb0 + 1114112;     // 196,608
  unsigned short* wt_hn   = wtb0 + 1310720;     // 114,688
  unsigned short* wt_he   = wtb0 + 1425408;     //  65,536

  // ---- dynamic regions (float-unit offsets from D0) ----
  const size_t D0 = 1600000;
  // stage A:
  unsigned short* obarb = (unsigned short*)(ws + D0);              // 12.288M f
  unsigned short* tmpAb = (unsigned short*)(ws + D0 + 12288000);   // 12.288M f
  unsigned short* fseqb = (unsigned short*)(ws + D0 + 50688000);   // 12.288M f
  // stage B (obarb/tmpAb dead):
  unsigned short* xwallb  = (unsigned short*)(ws + D0);            // 12.288M f
  unsigned short* gatallb = (unsigned short*)(ws + D0 + 12288000); // 12.288M f
  unsigned short* eembb   = (unsigned short*)(ws + D0 + 24576000); //  6.144M f
  float* h  = ws + D0 + 30720000;                                  //  3.072M
  float* c  = ws + D0 + 33792000;                                  //  3.072M
  unsigned short* hb0 = (unsigned short*)(ws + D0 + 36864000);     //  1.536M f
  unsigned short* hb1 = (unsigned short*)(ws + D0 + 38400000);     //  1.536M f
  unsigned short* ewall = (unsigned short*)(ws + D0 + 62976000);   // 24.576M f
  float* elogall = ws + D0 + 87552000;         //  1.536M (4 x 384000)
  float* sal     = ws + D0 + 89088000;         //    768,000
  float* dal     = ws + D0 + 89856000;         //    768,000
  int* ideg  = (int*)(ws + D0 + 90624000);
  int* iroff = ideg + 3008;
  int* ieord = iroff + 3008;
  float* hg  = ws + D0 + 90650000;
  float* hgp = ws + D0 + 90652048;
  // GAT-layers phase:
  unsigned short* xw_sb = (unsigned short*)(ws + D0 + 40000000);   // 1.536M f
  float* gat_s = ws + D0 + 41600000;           //  3.072M
  // heads (xwallb/gatallb dead):
  float* hidn = ws + D0;                       //  5.376M
  unsigned short* efb = (unsigned short*)(ws + D0 + 5376000);      // 12.288M f
  float* hide = ws + D0 + 17664000;            //  6.144M

  auto mgemm = [&](const unsigned short* A, const unsigned short* Wt, const float* bias,
                   void* C, int M, int N, int K, int lda, int flags) {
    dim3 grid(N / 64, (M + 127) / 128);
    gemm_bfa_k<<<grid, dim3(256), 0, stream>>>(A, Wt, bias, C, M, N, K, lda, flags);
  };
  auto cvtb = [&](const float* W, unsigned short* Wt, int K, int N, int L) {
    const int total = K * N * L;
    wtb_k<<<(total + 255) / 256, 256, 0, stream>>>(W, Wt, K, N, total);
  };

  // ---- weight convert/transpose/permute ----
  cvtb(wqkv, wt_qkv, 256, 768, 1);
  cvtb(wo, wt_wo, 256, 256, 1);
  cvtb(tg_W, wt_tgW, 256, 256, 1);
  cvtb(tg_We, wt_tgWe, 256, 256, 1);
  cvtb(g_We, wt_gWe, 256, 256, 3);
  wtp_k<<<1024, 256, 0, stream>>>(w_ih, wt_lstm, 0);
  wtp_k<<<1024, 256, 0, stream>>>(w_hh, wt_lstm, 256);
  cvtb(g_W, wt_gW, 256, 256, 3);
  cvtb(hn_w1, wt_hn, 256, 64, 7);
  cvtb(he_w1, wt_he, 512, 64, 2);

  // ---- CSR build (deterministic) ----
  hipMemsetAsync(ideg, 0, 3000 * sizeof(int), stream);
  hist_k<<<(E_ + 255) / 256, 256, 0, stream>>>(dst, ideg);
  scan_k<<<1, 256, 0, stream>>>(ideg, iroff);
  fill_k<<<750, 256, 0, stream>>>(dst, iroff, ieord);

  // ---------------- Stage A: fused qkv+attention -> obar ----------------
  qkv_attn_k<<<6000, 256, 0, stream>>>(env, infra, robot, wt_qkv, bqkv, obarb);
  // tmpAb = obar @ wo + bo (bf16), then fseq = LN(tmpAb)
  mgemm(obarb, wt_wo, bo, tmpAb, 96000, 256, 256, 256, 4);
  ln_k<<<96000, 64, 0, stream>>>(tmpAb, lnf_g, lnf_b, fseqb);

  // ---------------- Stage B prep ----------------
  {  // edge_emb = relu(edge_attr @ we_emb + be_emb) -> bf16
    dim3 grid(4, 750);
    gemm_k<<<grid, dim3(256), 0, stream>>>(edgeattr, we_emb, be_emb, eembb,
                                           48000, 256, 8, 8, 2 | 4);
  }
  // one batched edge-transform GEMM: [tgWe | gWe0 | gWe1 | gWe2], N=1024
  mgemm(eembb, wt_tgWe, nullptr, ewall, 48000, 1024, 256, 256, 4);
  elog4_k<<<6000, 256, 0, stream>>>(ewall, tg_aedge, g_aedge, elogall);

  mgemm(fseqb, wt_tgW, nullptr, xwallb, 96000, 256, 256, 256, 4);
  alphas_k<<<3000, 256, 0, stream>>>(xwallb, tg_asrc, tg_adst, sal, dal, 96000);
  gat_k<1><<<24000, 256, 0, stream>>>(xwallb, ewall, sal, dal, elogall, iroff, ieord,
                                      src, gatallb, 96000, 3, 1024, 0);

  // ---------------- LSTM over T (fused GEMM + pointwise) ----------------
  hipMemsetAsync(c, 0, 12288000, stream);
  hipMemsetAsync(hb0, 0, 6144000, stream);
  unsigned short* hbq[2] = { hb0, hb1 };
  for (int t = 0; t < T_; ++t) {
    dim3 grid(16, 94);
    gemm_lstm_k<<<grid, dim3(256), 0, stream>>>(gatallb, hbq[t & 1], wt_lstm, b_lstm,
                                                h, c, hbq[(t + 1) & 1], t);
  }
  unsigned short* hbf = hbq[0];  // T=8 even -> final h in hb0

  // ---------------- 3 GAT layers with residual LN ----------------
  for (int l = 0; l < 3; ++l) {
    mgemm(hbf, wt_gW + (size_t)l * 65536, nullptr, xw_sb, 12000, 256, 256, 256, 4);
    alphas_k<<<375, 256, 0, stream>>>(xw_sb, g_asrc + l * 256, g_adst + l * 256, sal, dal, 12000);
    gat_k<0><<<3000, 256, 0, stream>>>(xw_sb, ewall, sal, dal, elogall + 384000 * (l + 1),
                                       iroff, ieord, src, gat_s, 12000, 0,
                                       1024, 256 * (l + 1));
    resln_k<<<12000, 64, 0, stream>>>(h, gat_s, g_lng + l * 256, g_lnb + l * 256, hbf);
  }

  // ---------------- Heads ----------------
  mgemm(hbf, wt_hn, hn_b1, hidn, 12000, 448, 256, 256, 2);
  nh2_k<<<(84000 + 255) / 256, 256, 0, stream>>>(hidn, hn_w2, hn_b2, outp);

  hglob1_k<<<dim3(4, 25), 256, 0, stream>>>(h, hgp);
  hglob2_k<<<4, 256, 0, stream>>>(hgp, hg);
  freq_k<<<4, 64, 0, stream>>>(hg, hn_w1 + 7 * 16384, hn_b1 + 7 * 64,
                               hn_w2 + 7 * 64, hn_b2 + 7, outp);

  ef_k<<<12000, 256, 0, stream>>>(hbf, src, dst, efb);
  mgemm(efb, wt_he, he_b1, hide, 48000, 128, 512, 512, 2);
  eh2_k<<<(96000 + 255) / 256, 256, 0, stream>>>(hide, he_w2, he_b2, outp);
}

// Round 12
// 1682.328 us; speedup vs baseline: 1.0526x; 1.0526x over previous
//
#include <hip/hip_runtime.h>
#include <hip/hip_bf16.h>
#include <math.h>

#define DEV __device__ __forceinline__

namespace {
constexpr int B_ = 4, T_ = 8, N_ = 3000, E_ = 12000;
constexpr int OUTS_ = 45001;  // per-batch output stride: N*7 + E + E + 1
}

using f32x4 = __attribute__((ext_vector_type(4))) float;
using bf16x8 = __attribute__((ext_vector_type(8))) short;

DEV float sigm_(float x) { return 1.0f / (1.0f + expf(-x)); }
DEV float softplus_(float x) { return fmaxf(x, 0.0f) + log1pf(expf(-fabsf(x))); }
DEV float wred_(float v) {
  #pragma unroll
  for (int o = 32; o > 0; o >>= 1) v += __shfl_xor(v, o, 64);
  return v;
}
DEV unsigned short f2bf(float x) {  // RNE fp32->bf16
  unsigned u = __float_as_uint(x);
  return (unsigned short)((u + 0x7FFFu + ((u >> 16) & 1u)) >> 16);
}
DEV unsigned f2bf2(float a, float b) {
  return (unsigned)f2bf(a) | ((unsigned)f2bf(b) << 16);
}
DEV float bfl(unsigned u) { return __uint_as_float(u << 16); }
DEV float bfh(unsigned u) { return __uint_as_float(u & 0xffff0000u); }

// ---------------------------------------------------------------------------
// Batched weight transpose+convert: L matrices [K][N] -> per-matrix [N][K] bf16
// ---------------------------------------------------------------------------
__global__ void wtb_k(const float* __restrict__ W, unsigned short* __restrict__ Wt,
                      int K, int N, int total)
{
  const int idx = blockIdx.x * blockDim.x + threadIdx.x;
  if (idx >= total) return;
  const int kn = K * N;
  const int l = idx / kn;
  const int r = idx - l * kn;
  const int k = r / N, n = r - k * N;
  Wt[(size_t)l * kn + (size_t)n * K + k] = f2bf(W[idx]);
}

// LSTM weight permute: orig col n = gate*256+d -> newcol = d*4+gate; dense [1024][512]
__global__ void wtp_k(const float* __restrict__ W, unsigned short* __restrict__ Wt,
                      int kOff)
{
  const int idx = blockIdx.x * blockDim.x + threadIdx.x;
  if (idx >= 256 * 1024) return;
  const int k = idx >> 10;
  const int n = idx & 1023;
  const int newcol = (n & 255) * 4 + (n >> 8);
  Wt[(size_t)newcol * 512 + kOff + k] = f2bf(W[idx]);
}

// ---------------------------------------------------------------------------
// CSR build (deterministic)
// ---------------------------------------------------------------------------
__global__ void hist_k(const int* __restrict__ dst, int* __restrict__ deg)
{
  const int e = blockIdx.x * blockDim.x + threadIdx.x;
  if (e < E_) atomicAdd(&deg[dst[e]], 1);
}

__global__ __launch_bounds__(256) void scan_k(const int* __restrict__ deg,
                                              int* __restrict__ roff)
{
  __shared__ int part[256];
  const int t = threadIdx.x;
  int loc[12];
  int s = 0;
  #pragma unroll
  for (int i = 0; i < 12; ++i) {
    const int n = t * 12 + i;
    loc[i] = s;
    s += (n < N_) ? deg[n] : 0;
  }
  part[t] = s;
  __syncthreads();
  if (t == 0) {
    int run = 0;
    for (int i = 0; i < 256; ++i) { const int v = part[i]; part[i] = run; run += v; }
  }
  __syncthreads();
  const int base = part[t];
  #pragma unroll
  for (int i = 0; i < 12; ++i) {
    const int n = t * 12 + i;
    if (n < N_) roff[n] = base + loc[i];
  }
  if (t == 0) roff[N_] = E_;
}

__global__ __launch_bounds__(256) void fill_k(const int* __restrict__ dst,
                                              const int* __restrict__ roff,
                                              int* __restrict__ eord)
{
  const int n = blockIdx.x * 4 + (threadIdx.x >> 6);
  if (n >= N_) return;
  const int lane = threadIdx.x & 63;
  const unsigned long long ltm = (1ull << lane) - 1ull;
  int cnt = roff[n];
  for (int c = 0; c < E_; c += 64) {
    const int e = c + lane;
    const bool m = (e < E_) && (dst[e] == n);
    const unsigned long long mask = __ballot(m);
    if (m) eord[cnt + __popcll(mask & ltm)] = e;
    cnt += __popcll(mask);
  }
}

// ---------------------------------------------------------------------------
// 128x64-tile MFMA bf16 GEMM: C[M,N] = A[M,K](bf16) @ Wt(bf16,[N][K])
// flags: 1 = C += (fp32 C), 2 = relu, 4 = store bf16 C.
// ---------------------------------------------------------------------------
__global__ __launch_bounds__(256) void gemm_bfa_k(
    const unsigned short* __restrict__ A, const unsigned short* __restrict__ Wt,
    const float* __restrict__ bias, void* __restrict__ Cv,
    int M, int N, int K, int lda, int flags)
{
  __shared__ unsigned short Al[128 * 40];
  __shared__ unsigned short Bl[64 * 40];
  const int tid = threadIdx.x;
  const int bm = blockIdx.y * 128;
  const int bn = blockIdx.x * 64;
  const int lane = tid & 63;
  const int wv = tid >> 6;
  const int wm = (wv >> 1) * 64;
  const int wn = (wv & 1) * 32;
  const int s_row = tid >> 1;
  const int s_cb = (tid & 1) * 16;
  const int grow = bm + s_row;
  const unsigned short* Arow = (grow < M) ? A + (size_t)grow * lda : nullptr;
  const int b_col = tid >> 2;
  const int b_ks = (tid & 3) * 8;
  const unsigned short* Wrow = Wt + (size_t)(bn + b_col) * K + b_ks;

  f32x4 acc[4][2] = {};
  const int l15 = lane & 15;
  const int lk = (lane >> 4) * 8;

  for (int k0 = 0; k0 < K; k0 += 32) {
    uint4 a0, a1;
    if (Arow) {
      a0 = *(const uint4*)(Arow + k0 + s_cb);
      a1 = *(const uint4*)(Arow + k0 + s_cb + 8);
    } else {
      a0 = make_uint4(0, 0, 0, 0);
      a1 = a0;
    }
    *(uint4*)&Al[s_row * 40 + s_cb] = a0;
    *(uint4*)&Al[s_row * 40 + s_cb + 8] = a1;
    *(uint4*)&Bl[b_col * 40 + b_ks] = *(const uint4*)(Wrow + k0);
    __syncthreads();
    bf16x8 af[4], bfr[2];
    #pragma unroll
    for (int m = 0; m < 4; ++m)
      af[m] = *(const bf16x8*)&Al[(wm + m * 16 + l15) * 40 + lk];
    #pragma unroll
    for (int n = 0; n < 2; ++n)
      bfr[n] = *(const bf16x8*)&Bl[(wn + n * 16 + l15) * 40 + lk];
    #pragma unroll
    for (int m = 0; m < 4; ++m)
      #pragma unroll
      for (int n = 0; n < 2; ++n)
        acc[m][n] = __builtin_amdgcn_mfma_f32_16x16x32_bf16(af[m], bfr[n], acc[m][n], 0, 0, 0);
    __syncthreads();
  }
  float* Cf = (float*)Cv;
  unsigned short* Cb = (unsigned short*)Cv;
  const int r4 = (lane >> 4) * 4;
  #pragma unroll
  for (int m = 0; m < 4; ++m) {
    #pragma unroll
    for (int n = 0; n < 2; ++n) {
      const int col = bn + wn + n * 16 + l15;
      const float bv = bias ? bias[col] : 0.f;
      #pragma unroll
      for (int r = 0; r < 4; ++r) {
        const int row = bm + wm + m * 16 + r4 + r;
        if (row >= M) continue;
        float v = acc[m][n][r] + bv;
        const size_t ci = (size_t)row * N + col;
        if (flags & 1) v += Cf[ci];
        if (flags & 2) v = fmaxf(v, 0.f);
        if (flags & 4) Cb[ci] = f2bf(v);
        else Cf[ci] = v;
      }
    }
  }
}

// ---------------------------------------------------------------------------
// Stage-A qkv GEMM: A rows are fp32 from 3 interleaved sources
// (row r: slot=r%3, node=nodeBase+r/3). Converts to bf16 in staging.
// ---------------------------------------------------------------------------
__global__ __launch_bounds__(256) void gemm_qkv_k(
    const float* __restrict__ env, const float* __restrict__ infra,
    const float* __restrict__ robot, const unsigned short* __restrict__ Wt,
    const float* __restrict__ bias, unsigned short* __restrict__ Cb,
    int M, int nodeBase)
{
  __shared__ unsigned short Al[128 * 40];
  __shared__ unsigned short Bl[64 * 40];
  const int tid = threadIdx.x;
  const int bm = blockIdx.y * 128;
  const int bn = blockIdx.x * 64;
  const int lane = tid & 63;
  const int wv = tid >> 6;
  const int wm = (wv >> 1) * 64;
  const int wn = (wv & 1) * 32;
  const int s_row = tid >> 1;
  const int s_cb = (tid & 1) * 16;
  const int grow = bm + s_row;
  const float* Arow = nullptr;
  if (grow < M) {
    const int slot = grow % 3;
    const int node = nodeBase + grow / 3;
    const float* srcp = (slot == 0 ? env : (slot == 1 ? infra : robot));
    Arow = srcp + (size_t)node * 256;
  }
  const int b_col = tid >> 2;
  const int b_ks = (tid & 3) * 8;
  const unsigned short* Wrow = Wt + (size_t)(bn + b_col) * 256 + b_ks;

  f32x4 acc[4][2] = {};
  const int l15 = lane & 15;
  const int lk = (lane >> 4) * 8;

  for (int k0 = 0; k0 < 256; k0 += 32) {
    unsigned abuf[8];
    if (Arow) {
      const float* p = Arow + k0 + s_cb;
      #pragma unroll
      for (int i = 0; i < 4; ++i) {
        const float4 v = *(const float4*)(p + i * 4);
        abuf[i * 2 + 0] = f2bf2(v.x, v.y);
        abuf[i * 2 + 1] = f2bf2(v.z, v.w);
      }
    } else {
      #pragma unroll
      for (int i = 0; i < 8; ++i) abuf[i] = 0;
    }
    *(uint4*)&Al[s_row * 40 + s_cb] = *(uint4*)&abuf[0];
    *(uint4*)&Al[s_row * 40 + s_cb + 8] = *(uint4*)&abuf[4];
    *(uint4*)&Bl[b_col * 40 + b_ks] = *(const uint4*)(Wrow + k0);
    __syncthreads();
    bf16x8 af[4], bfr[2];
    #pragma unroll
    for (int m = 0; m < 4; ++m)
      af[m] = *(const bf16x8*)&Al[(wm + m * 16 + l15) * 40 + lk];
    #pragma unroll
    for (int n = 0; n < 2; ++n)
      bfr[n] = *(const bf16x8*)&Bl[(wn + n * 16 + l15) * 40 + lk];
    #pragma unroll
    for (int m = 0; m < 4; ++m)
      #pragma unroll
      for (int n = 0; n < 2; ++n)
        acc[m][n] = __builtin_amdgcn_mfma_f32_16x16x32_bf16(af[m], bfr[n], acc[m][n], 0, 0, 0);
    __syncthreads();
  }
  const int r4 = (lane >> 4) * 4;
  #pragma unroll
  for (int m = 0; m < 4; ++m) {
    #pragma unroll
    for (int n = 0; n < 2; ++n) {
      const int col = bn + wn + n * 16 + l15;
      const float bv = bias[col];
      #pragma unroll
      for (int r = 0; r < 4; ++r) {
        const int row = bm + wm + m * 16 + r4 + r;
        if (row >= M) continue;
        Cb[(size_t)row * 768 + col] = f2bf(acc[m][n][r] + bv);
      }
    }
  }
}

// ---------------------------------------------------------------------------
// Fused LSTM step: gates = [gat_t | h] @ Wt_perm (K=512, newcol = d*4+gate),
// then LSTM pointwise in epilogue via LDS transpose. Writes c, h (fp32), hbOut.
// hbIn (read) and hbOut (write) MUST be different buffers (cross-block race).
// ---------------------------------------------------------------------------
__global__ __launch_bounds__(256) void gemm_lstm_k(
    const unsigned short* __restrict__ gatall, const unsigned short* __restrict__ hbIn,
    const unsigned short* __restrict__ Wt, const float* __restrict__ b_lstm,
    float* __restrict__ h, float* __restrict__ c, unsigned short* __restrict__ hbOut,
    int t)
{
  __shared__ float Gl[128][65];
  unsigned short* Al = (unsigned short*)&Gl[0][0];
  unsigned short* Bl = Al + 128 * 40;
  const int tid = threadIdx.x;
  const int bm = blockIdx.y * 128;
  const int bn = blockIdx.x * 64;
  const int lane = tid & 63;
  const int wv = tid >> 6;
  const int wm = (wv >> 1) * 64;
  const int wn = (wv & 1) * 32;
  const int s_row = tid >> 1;
  const int s_cb = (tid & 1) * 16;
  const int grow = bm + s_row;
  const unsigned short* Arow1 = nullptr;
  const unsigned short* Arow2 = nullptr;
  if (grow < 12000) {
    const int phys = (grow / N_) * (T_ * N_) + t * N_ + (grow % N_);
    Arow1 = gatall + (size_t)phys * 256;
    Arow2 = hbIn + (size_t)grow * 256;
  }
  const int b_col = tid >> 2;
  const int b_ks = (tid & 3) * 8;
  const unsigned short* Wrow = Wt + (size_t)(bn + b_col) * 512 + b_ks;

  f32x4 acc[4][2] = {};
  const int l15 = lane & 15;
  const int lk = (lane >> 4) * 8;

  for (int k0 = 0; k0 < 512; k0 += 32) {
    uint4 a0, a1;
    if (Arow1) {
      const unsigned short* p = (k0 < 256) ? (Arow1 + k0 + s_cb)
                                           : (Arow2 + (k0 - 256) + s_cb);
      a0 = *(const uint4*)p;
      a1 = *(const uint4*)(p + 8);
    } else {
      a0 = make_uint4(0, 0, 0, 0);
      a1 = a0;
    }
    *(uint4*)&Al[s_row * 40 + s_cb] = a0;
    *(uint4*)&Al[s_row * 40 + s_cb + 8] = a1;
    *(uint4*)&Bl[b_col * 40 + b_ks] = *(const uint4*)(Wrow + k0);
    __syncthreads();
    bf16x8 af[4], bfr[2];
    #pragma unroll
    for (int m = 0; m < 4; ++m)
      af[m] = *(const bf16x8*)&Al[(wm + m * 16 + l15) * 40 + lk];
    #pragma unroll
    for (int n = 0; n < 2; ++n)
      bfr[n] = *(const bf16x8*)&Bl[(wn + n * 16 + l15) * 40 + lk];
    #pragma unroll
    for (int m = 0; m < 4; ++m)
      #pragma unroll
      for (int n = 0; n < 2; ++n)
        acc[m][n] = __builtin_amdgcn_mfma_f32_16x16x32_bf16(af[m], bfr[n], acc[m][n], 0, 0, 0);
    __syncthreads();
  }
  const int r4 = (lane >> 4) * 4;
  #pragma unroll
  for (int m = 0; m < 4; ++m)
    #pragma unroll
    for (int n = 0; n < 2; ++n) {
      const int col = wn + n * 16 + l15;
      #pragma unroll
      for (int r = 0; r < 4; ++r)
        Gl[wm + m * 16 + r4 + r][col] = acc[m][n][r];
    }
  __syncthreads();
  const int fl = lane & 7;
  const int rg = lane >> 3;
  const int dg = ((bn + wn) >> 2) + fl;
  const float bi = b_lstm[dg];
  const float bff = b_lstm[256 + dg];
  const float bg = b_lstm[512 + dg];
  const float bo = b_lstm[768 + dg];
  const int colb = wn + fl * 4;
  #pragma unroll
  for (int i = 0; i < 8; ++i) {
    const int rl = rg + i * 8;
    const int row = bm + wm + rl;
    if (row >= 12000) continue;
    const float g0 = Gl[wm + rl][colb + 0] + bi;
    const float g1 = Gl[wm + rl][colb + 1] + bff;
    const float g2 = Gl[wm + rl][colb + 2] + bg;
    const float g3 = Gl[wm + rl][colb + 3] + bo;
    const size_t idx = (size_t)row * 256 + dg;
    const float cn = sigm_(g1) * c[idx] + sigm_(g0) * tanhf(g2);
    c[idx] = cn;
    const float hn = sigm_(g3) * tanhf(cn);
    h[idx] = hn;
    hbOut[idx] = f2bf(hn);
  }
}

// ---------------------------------------------------------------------------
// fp32 fallback GEMM (only the K=8 edge-emb GEMM); flags&4 -> bf16 C store
// ---------------------------------------------------------------------------
__global__ __launch_bounds__(256) void gemm_k(
    const float* __restrict__ A, const float* __restrict__ W,
    const float* __restrict__ bias, void* __restrict__ Cv,
    int M, int N, int K, int lda, int flags)
{
  __shared__ float As[16][68];
  __shared__ float Ws[16][64];
  const int tid = threadIdx.x;
  const int bm = blockIdx.y * 64;
  const int bn = blockIdx.x * 64;
  const int tx = tid & 15;
  const int ty = tid >> 4;
  const int ar = tid >> 2;
  const int ac = (tid & 3) << 2;
  const int wr = tid >> 4;
  const int wc = (tid & 15) << 2;
  const int grow = bm + ar;
  const float* Arow = (grow < M) ? A + (size_t)grow * lda : nullptr;
  float acc[4][4] = {};
  for (int k0 = 0; k0 < K; k0 += 16) {
    float4 av = make_float4(0.f, 0.f, 0.f, 0.f);
    if (Arow) {
      av.x = (k0 + ac + 0 < K) ? Arow[k0 + ac + 0] : 0.f;
      av.y = (k0 + ac + 1 < K) ? Arow[k0 + ac + 1] : 0.f;
      av.z = (k0 + ac + 2 < K) ? Arow[k0 + ac + 2] : 0.f;
      av.w = (k0 + ac + 3 < K) ? Arow[k0 + ac + 3] : 0.f;
    }
    As[ac + 0][ar] = av.x;
    As[ac + 1][ar] = av.y;
    As[ac + 2][ar] = av.z;
    As[ac + 3][ar] = av.w;
    float4 wv = make_float4(0.f, 0.f, 0.f, 0.f);
    if (k0 + wr < K) {
      const int gc = bn + wc;
      const float* wp = W + (size_t)(k0 + wr) * N + gc;
      wv.x = (gc + 0 < N) ? wp[0] : 0.f;
      wv.y = (gc + 1 < N) ? wp[1] : 0.f;
      wv.z = (gc + 2 < N) ? wp[2] : 0.f;
      wv.w = (gc + 3 < N) ? wp[3] : 0.f;
    }
    *(float4*)&Ws[wr][wc] = wv;
    __syncthreads();
    #pragma unroll
    for (int kk = 0; kk < 16; ++kk) {
      const float4 a = *(const float4*)&As[kk][ty << 2];
      const float4 b = *(const float4*)&Ws[kk][tx << 2];
      acc[0][0] += a.x * b.x; acc[0][1] += a.x * b.y; acc[0][2] += a.x * b.z; acc[0][3] += a.x * b.w;
      acc[1][0] += a.y * b.x; acc[1][1] += a.y * b.y; acc[1][2] += a.y * b.z; acc[1][3] += a.y * b.w;
      acc[2][0] += a.z * b.x; acc[2][1] += a.z * b.y; acc[2][2] += a.z * b.z; acc[2][3] += a.z * b.w;
      acc[3][0] += a.w * b.x; acc[3][1] += a.w * b.y; acc[3][2] += a.w * b.z; acc[3][3] += a.w * b.w;
    }
    __syncthreads();
  }
  float* Cf = (float*)Cv;
  unsigned short* Cb = (unsigned short*)Cv;
  #pragma unroll
  for (int i = 0; i < 4; ++i) {
    const int row = bm + (ty << 2) + i;
    if (row >= M) continue;
    #pragma unroll
    for (int j = 0; j < 4; ++j) {
      const int col = bn + (tx << 2) + j;
      if (col >= N) continue;
      float v = acc[i][j];
      if (bias) v += bias[col];
      if (flags & 2) v = fmaxf(v, 0.f);
      const size_t ci = (size_t)row * N + col;
      if (flags & 4) Cb[ci] = f2bf(v);
      else Cf[ci] = v;
    }
  }
}

// ---------------------------------------------------------------------------
// Stage A attention: ONE WAVE PER NODE (coalesced). Lane l -> head l>>3,
// elems (l&7)*4; qkv offset = node*2304 + 4*l. 9 dots reduce over the 8-lane
// subgroup via shfl_xor(1,2,4). 4 waves/block.
// ---------------------------------------------------------------------------
__global__ __launch_bounds__(256) void attn_avg_k(
    const unsigned short* __restrict__ qkv,
    unsigned short* __restrict__ obar, int nodes)
{
  const int node = blockIdx.x * 4 + (threadIdx.x >> 6);
  if (node >= nodes) return;
  const int lane = threadIdx.x & 63;
  const unsigned short* base = qkv + (size_t)node * 2304 + lane * 4;
  float qv[3][4], kv[3][4], vv[3][4];
  #pragma unroll
  for (int s = 0; s < 3; ++s) {
    const uint2 uq = *(const uint2*)(base + s * 768);
    const uint2 uk = *(const uint2*)(base + s * 768 + 256);
    const uint2 uv = *(const uint2*)(base + s * 768 + 512);
    qv[s][0] = bfl(uq.x); qv[s][1] = bfh(uq.x); qv[s][2] = bfl(uq.y); qv[s][3] = bfh(uq.y);
    kv[s][0] = bfl(uk.x); kv[s][1] = bfh(uk.x); kv[s][2] = bfl(uk.y); kv[s][3] = bfh(uk.y);
    vv[s][0] = bfl(uv.x); vv[s][1] = bfh(uv.x); vv[s][2] = bfl(uv.y); vv[s][3] = bfh(uv.y);
  }
  float att[3][3];
  #pragma unroll
  for (int s = 0; s < 3; ++s) {
    #pragma unroll
    for (int t = 0; t < 3; ++t) {
      float d = qv[s][0] * kv[t][0] + qv[s][1] * kv[t][1]
              + qv[s][2] * kv[t][2] + qv[s][3] * kv[t][3];
      d += __shfl_xor(d, 1, 64);
      d += __shfl_xor(d, 2, 64);
      d += __shfl_xor(d, 4, 64);
      att[s][t] = d * 0.17677669529663687f;
    }
  }
  float cs[3] = {0.f, 0.f, 0.f};
  #pragma unroll
  for (int s = 0; s < 3; ++s) {
    const float m = fmaxf(att[s][0], fmaxf(att[s][1], att[s][2]));
    const float e0 = expf(att[s][0] - m);
    const float e1 = expf(att[s][1] - m);
    const float e2 = expf(att[s][2] - m);
    const float inv = (1.f / 3.f) / (e0 + e1 + e2);
    cs[0] += e0 * inv; cs[1] += e1 * inv; cs[2] += e2 * inv;
  }
  float o0 = cs[0] * vv[0][0] + cs[1] * vv[1][0] + cs[2] * vv[2][0];
  float o1 = cs[0] * vv[0][1] + cs[1] * vv[1][1] + cs[2] * vv[2][1];
  float o2 = cs[0] * vv[0][2] + cs[1] * vv[1][2] + cs[2] * vv[2][2];
  float o3 = cs[0] * vv[0][3] + cs[1] * vv[1][3] + cs[2] * vv[2][3];
  uint2 ob;
  ob.x = f2bf2(o0, o1);
  ob.y = f2bf2(o2, o3);
  *(uint2*)(obar + (size_t)node * 256 + lane * 4) = ob;
}

// LayerNorm per row; bf16 in, bf16 out. 1 wave per row.
__global__ __launch_bounds__(64) void ln_k(
    const unsigned short* __restrict__ in, const float* __restrict__ g,
    const float* __restrict__ bta, unsigned short* __restrict__ outp)
{
  const int row = blockIdx.x;
  const int d0 = threadIdx.x << 2;
  const uint2 a = *(const uint2*)(in + (size_t)row * 256 + d0);
  float x[4] = { bfl(a.x), bfh(a.x), bfl(a.y), bfh(a.y) };
  float s = x[0] + x[1] + x[2] + x[3];
  s = wred_(s);
  const float mean = s * (1.f / 256.f);
  float vs = 0.f;
  #pragma unroll
  for (int i = 0; i < 4; ++i) { const float dd = x[i] - mean; vs += dd * dd; }
  vs = wred_(vs);
  const float inv = 1.0f / sqrtf(vs * (1.f / 256.f) + 1e-5f);
  const float4 gv = *(const float4*)(g + d0);
  const float4 bv = *(const float4*)(bta + d0);
  uint2 o;
  o.x = f2bf2((x[0] - mean) * inv * gv.x + bv.x, (x[1] - mean) * inv * gv.y + bv.y);
  o.y = f2bf2((x[2] - mean) * inv * gv.z + bv.z, (x[3] - mean) * inv * gv.w + bv.w);
  *(uint2*)(outp + (size_t)row * 256 + d0) = o;
}

// ---------------------------------------------------------------------------
// GAT kernels (bf16 feature inputs)
// ---------------------------------------------------------------------------
__global__ void alphas_k(const unsigned short* __restrict__ xw, const float* __restrict__ as,
                         const float* __restrict__ ad, float* __restrict__ sal,
                         float* __restrict__ dal, int rows)
{
  const int idx = blockIdx.x * blockDim.x + threadIdx.x;
  if (idx >= rows * 8) return;
  const int row = idx >> 3, h = idx & 7;
  const unsigned short* x = xw + (size_t)row * 256 + h * 32;
  const float* a1 = as + h * 32;
  const float* a2 = ad + h * 32;
  float s = 0.f, d = 0.f;
  #pragma unroll
  for (int i = 0; i < 4; ++i) {
    const uint4 ux = *(const uint4*)(x + i * 8);
    const unsigned* p = &ux.x;
    #pragma unroll
    for (int j = 0; j < 4; ++j) {
      const float lo = bfl(p[j]), hi = bfh(p[j]);
      s += lo * a1[i * 8 + 2 * j] + hi * a1[i * 8 + 2 * j + 1];
      d += lo * a2[i * 8 + 2 * j] + hi * a2[i * 8 + 2 * j + 1];
    }
  }
  sal[idx] = s; dal[idx] = d;
}

// all 4 edge-logit sets in one launch; ew is [48000][1024] (4 x 256 packed)
__global__ void elog4_k(const unsigned short* __restrict__ ew,
                        const float* __restrict__ tg_ae, const float* __restrict__ g_ae,
                        float* __restrict__ el)
{
  const int idx = blockIdx.x * blockDim.x + threadIdx.x;
  if (idx >= 4 * 48000 * 8) return;
  const int l = idx / (48000 * 8);
  const int r = idx - l * (48000 * 8);
  const int row = r >> 3, h = r & 7;
  const unsigned short* x = ew + (size_t)row * 1024 + l * 256 + h * 32;
  const float* a1 = (l == 0 ? tg_ae : g_ae + (l - 1) * 256) + h * 32;
  float s = 0.f;
  #pragma unroll
  for (int i = 0; i < 4; ++i) {
    const uint4 ux = *(const uint4*)(x + i * 8);
    const unsigned* p = &ux.x;
    #pragma unroll
    for (int j = 0; j < 4; ++j) {
      s += bfl(p[j]) * a1[i * 8 + 2 * j] + bfh(p[j]) * a1[i * 8 + 2 * j + 1];
    }
  }
  el[l * 384000 + r] = s;
}

// Fused GAT aggregation: one wave per (beta,node). Online softmax over incoming
// edges (CSR). bf16 gathers. OUTBF: 1 -> bf16 out, 0 -> fp32 out.
template<int OUTBF>
__global__ __launch_bounds__(256) void gat_k(
    const unsigned short* __restrict__ xw, const unsigned short* __restrict__ ew,
    const float* __restrict__ sal, const float* __restrict__ dal,
    const float* __restrict__ el, const int* __restrict__ roff,
    const int* __restrict__ eord, const int* __restrict__ srcArr,
    void* __restrict__ outp, int nwaves, int tshift, int ewStride, int ewOff)
{
  const int wid = blockIdx.x * 4 + (threadIdx.x >> 6);
  if (wid >= nwaves) return;
  const int beta = wid / N_;
  const int n = wid - beta * N_;
  const int b = beta >> tshift;
  const int lane = threadIdx.x & 63;
  const int h = lane >> 3;
  const int d0 = lane << 2;
  const float dal_h = dal[(size_t)wid * 8 + h];
  const int p0 = roff[n], p1 = roff[n + 1];
  float m = -1e30f, s = 0.f;
  float4 acc = make_float4(0.f, 0.f, 0.f, 0.f);
  for (int p = p0; p < p1; ++p) {
    const int e = eord[p];
    const int sc = srcArr[e];
    float lg = sal[((size_t)beta * N_ + sc) * 8 + h] + dal_h + el[((size_t)b * E_ + e) * 8 + h];
    lg = lg > 0.f ? lg : 0.2f * lg;
    const float mn = fmaxf(m, lg);
    const float scale = expf(m - mn);
    const float w = expf(lg - mn);
    s = s * scale + w;
    const uint2 ux = *(const uint2*)(xw + ((size_t)beta * N_ + sc) * 256 + d0);
    const uint2 ue = *(const uint2*)(ew + ((size_t)(b * E_ + e)) * ewStride + ewOff + d0);
    acc.x = acc.x * scale + w * (bfl(ux.x) + bfl(ue.x));
    acc.y = acc.y * scale + w * (bfh(ux.x) + bfh(ue.x));
    acc.z = acc.z * scale + w * (bfl(ux.y) + bfl(ue.y));
    acc.w = acc.w * scale + w * (bfh(ux.y) + bfh(ue.y));
    m = mn;
  }
  const float inv = 1.0f / (s + 1e-16f);
  if (OUTBF) {
    uint2 o;
    o.x = f2bf2(acc.x * inv, acc.y * inv);
    o.y = f2bf2(acc.z * inv, acc.w * inv);
    *(uint2*)((unsigned short*)outp + (size_t)wid * 256 + d0) = o;
  } else {
    *(float4*)((float*)outp + (size_t)wid * 256 + d0) =
        make_float4(acc.x * inv, acc.y * inv, acc.z * inv, acc.w * inv);
  }
}

// h = LN(h + add); writes fp32 h and bf16 hb
__global__ __launch_bounds__(64) void resln_k(float* __restrict__ h,
                                              const float* __restrict__ add,
                                              const float* __restrict__ g,
                                              const float* __restrict__ bta,
                                              unsigned short* __restrict__ hb)
{
  const int row = blockIdx.x;
  const int d0 = threadIdx.x << 2;
  float* hp = h + (size_t)row * 256;
  const float4 hv = *(const float4*)(hp + d0);
  const float4 av = *(const float4*)(add + (size_t)row * 256 + d0);
  float x[4] = { hv.x + av.x, hv.y + av.y, hv.z + av.z, hv.w + av.w };
  float s = x[0] + x[1] + x[2] + x[3];
  s = wred_(s);
  const float mean = s * (1.f / 256.f);
  float vs = 0.f;
  #pragma unroll
  for (int i = 0; i < 4; ++i) { const float dd = x[i] - mean; vs += dd * dd; }
  vs = wred_(vs);
  const float inv = 1.0f / sqrtf(vs * (1.f / 256.f) + 1e-5f);
  const float4 gv = *(const float4*)(g + d0);
  const float4 bv = *(const float4*)(bta + d0);
  float o0 = (x[0] - mean) * inv * gv.x + bv.x;
  float o1 = (x[1] - mean) * inv * gv.y + bv.y;
  float o2 = (x[2] - mean) * inv * gv.z + bv.z;
  float o3 = (x[3] - mean) * inv * gv.w + bv.w;
  *(float4*)(hp + d0) = make_float4(o0, o1, o2, o3);
  uint2 ob;
  ob.x = f2bf2(o0, o1);
  ob.y = f2bf2(o2, o3);
  *(uint2*)(hb + (size_t)row * 256 + d0) = ob;
}

// ---------------------------------------------------------------------------
// Head kernels
// ---------------------------------------------------------------------------
__global__ void nh2_k(const float* __restrict__ hidden, const float* __restrict__ w2,
                      const float* __restrict__ b2, float* __restrict__ outp)
{
  const int idx = blockIdx.x * blockDim.x + threadIdx.x;
  if (idx >= B_ * N_ * 7) return;
  const int row = idx / 7, j = idx % 7;
  const float* hp = hidden + (size_t)row * 448 + j * 64;
  const float* wp = w2 + j * 64;
  float a = 0.f;
  #pragma unroll
  for (int u = 0; u < 64; ++u) a += hp[u] * wp[u];
  a += b2[j];
  if (j == 0 || j == 6) a = sigm_(a);
  else if (j == 1) a = softplus_(a);
  const int b = row / N_, n = row % N_;
  outp[(size_t)b * OUTS_ + n * 7 + j] = a;
}

// two-stage deterministic h_global mean
__global__ __launch_bounds__(256) void hglob1_k(const float* __restrict__ h,
                                                float* __restrict__ hgp)
{
  const int b = blockIdx.x;
  const int seg = blockIdx.y;
  const int d = threadIdx.x;
  float s = 0.f;
  const int n0 = seg * 120;
  for (int n = n0; n < n0 + 120; ++n)
    s += h[((size_t)(b * N_ + n)) * 256 + d];
  hgp[((size_t)(b * 25 + seg)) * 256 + d] = s;
}

__global__ __launch_bounds__(256) void hglob2_k(const float* __restrict__ hgp,
                                                float* __restrict__ hg)
{
  const int b = blockIdx.x;
  const int d = threadIdx.x;
  float s = 0.f;
  for (int i = 0; i < 25; ++i) s += hgp[((size_t)(b * 25 + i)) * 256 + d];
  hg[b * 256 + d] = s * (1.f / (float)N_);
}

__global__ __launch_bounds__(64) void freq_k(const float* __restrict__ hg,
                                             const float* __restrict__ w1, const float* __restrict__ b1,
                                             const float* __restrict__ w2, const float* __restrict__ b2,
                                             float* __restrict__ outp)
{
  const int b = blockIdx.x;
  const int u = threadIdx.x;
  float a = b1[u];
  for (int k = 0; k < 256; ++k) a += hg[b * 256 + k] * w1[k * 64 + u];
  a = fmaxf(a, 0.f) * w2[u];
  a = wred_(a);
  if (u == 0) outp[(size_t)b * OUTS_ + 45000] = a + b2[0];
}

// gather ef = [hb[b,src], hb[b,dst]] bf16 (B*E x 512)
__global__ void ef_k(const unsigned short* __restrict__ hb, const int* __restrict__ src,
                     const int* __restrict__ dst, unsigned short* __restrict__ ef)
{
  const int idx = blockIdx.x * blockDim.x + threadIdx.x;
  if (idx >= B_ * E_ * 64) return;
  const int q = idx & 63;
  const int row = idx >> 6;
  const int b = row / E_, e = row % E_;
  const int d = q << 3;
  const unsigned short* p = (d < 256)
      ? hb + ((size_t)(b * N_ + src[e])) * 256 + d
      : hb + ((size_t)(b * N_ + dst[e])) * 256 + (d - 256);
  *(uint4*)(ef + (size_t)row * 512 + d) = *(const uint4*)p;
}

__global__ void eh2_k(const float* __restrict__ hidden, const float* __restrict__ w2,
                      const float* __restrict__ b2, float* __restrict__ outp)
{
  const int idx = blockIdx.x * blockDim.x + threadIdx.x;
  if (idx >= 2 * B_ * E_) return;
  const int jj = idx / (B_ * E_);
  const int r = idx - jj * (B_ * E_);
  const int b = r / E_, e = r % E_;
  const float* hp = hidden + (size_t)r * 128 + jj * 64;
  const float* wp = w2 + jj * 64;
  float a = 0.f;
  #pragma unroll
  for (int u = 0; u < 64; ++u) a += hp[u] * wp[u];
  a += b2[jj];
  outp[(size_t)b * OUTS_ + 21000 + jj * 12000 + e] = a;
}

// ---------------------------------------------------------------------------
extern "C" void kernel_launch(void* const* d_in, const int* in_sizes, int n_in,
                              void* d_out, int out_size, void* d_ws, size_t ws_size,
                              hipStream_t stream)
{
  const float* env      = (const float*)d_in[0];
  const float* infra    = (const float*)d_in[1];
  const float* robot    = (const float*)d_in[2];
  const float* edgeattr = (const float*)d_in[3];
  const int*   eidx     = (const int*)d_in[4];
  const float* wqkv     = (const float*)d_in[5];
  const float* bqkv     = (const float*)d_in[6];
  const float* wo       = (const float*)d_in[7];
  const float* bo       = (const float*)d_in[8];
  const float* lnf_g    = (const float*)d_in[9];
  const float* lnf_b    = (const float*)d_in[10];
  const float* we_emb   = (const float*)d_in[11];
  const float* be_emb   = (const float*)d_in[12];
  const float* tg_W     = (const float*)d_in[13];
  const float* tg_We    = (const float*)d_in[14];
  const float* tg_asrc  = (const float*)d_in[15];
  const float* tg_adst  = (const float*)d_in[16];
  const float* tg_aedge = (const float*)d_in[17];
  const float* w_ih     = (const float*)d_in[18];
  const float* w_hh     = (const float*)d_in[19];
  const float* b_lstm   = (const float*)d_in[20];
  const float* g_W      = (const float*)d_in[21];
  const float* g_We     = (const float*)d_in[22];
  const float* g_asrc   = (const float*)d_in[23];
  const float* g_adst   = (const float*)d_in[24];
  const float* g_aedge  = (const float*)d_in[25];
  const float* g_lng    = (const float*)d_in[26];
  const float* g_lnb    = (const float*)d_in[27];
  const float* hn_w1    = (const float*)d_in[28];
  const float* hn_b1    = (const float*)d_in[29];
  const float* hn_w2    = (const float*)d_in[30];
  const float* hn_b2    = (const float*)d_in[31];
  const float* he_w1    = (const float*)d_in[32];
  const float* he_b1    = (const float*)d_in[33];
  const float* he_w2    = (const float*)d_in[34];
  const float* he_b2    = (const float*)d_in[35];

  const int* src = eidx;
  const int* dst = eidx + E_;
  float* outp = (float*)d_out;
  float* ws = (float*)d_ws;

  // ---- bf16 transposed weights at ws start (short offsets) ----
  unsigned short* wtb0 = (unsigned short*)ws;
  unsigned short* wt_qkv  = wtb0;               // 196,608
  unsigned short* wt_wo   = wtb0 + 196608;      //  65,536
  unsigned short* wt_tgW  = wtb0 + 262144;      //  65,536
  unsigned short* wt_tgWe = wtb0 + 327680;      //  65,536  (rows 0..255 of edge-cat)
  unsigned short* wt_gWe  = wtb0 + 393216;      // 196,608  (rows 256..1023, contiguous)
  unsigned short* wt_lstm = wtb0 + 589824;      // 524,288  permuted [1024][512]
  unsigned short* wt_gW   = wtb0 + 1114112;     // 196,608
  unsigned short* wt_hn   = wtb0 + 1310720;     // 114,688
  unsigned short* wt_he   = wtb0 + 1425408;     //  65,536

  // ---- dynamic regions (float-unit offsets from D0) ----
  const size_t D0 = 1600000;
  // stage A:
  unsigned short* qkvb  = (unsigned short*)(ws + D0);              // 13.824M f
  unsigned short* tmpAb = (unsigned short*)(ws + D0 + 13824000);   // 12.288M f
  unsigned short* obarb = (unsigned short*)(ws + D0 + 38400000);   // 12.288M f
  unsigned short* fseqb = (unsigned short*)(ws + D0 + 50688000);   // 12.288M f
  // stage B (qkvb/tmpAb/obarb dead):
  unsigned short* xwallb  = (unsigned short*)(ws + D0);            // 12.288M f
  unsigned short* gatallb = (unsigned short*)(ws + D0 + 12288000); // 12.288M f
  unsigned short* eembb   = (unsigned short*)(ws + D0 + 24576000); //  6.144M f
  float* h  = ws + D0 + 30720000;                                  //  3.072M
  float* c  = ws + D0 + 33792000;                                  //  3.072M
  unsigned short* hb0 = (unsigned short*)(ws + D0 + 36864000);     //  1.536M f
  unsigned short* hb1 = (unsigned short*)(ws + D0 + 38400000);     //  1.536M f
  unsigned short* ewall = (unsigned short*)(ws + D0 + 62976000);   // 24.576M f
  float* elogall = ws + D0 + 87552000;         //  1.536M (4 x 384000)
  float* sal     = ws + D0 + 89088000;         //    768,000
  float* dal     = ws + D0 + 89856000;         //    768,000
  int* ideg  = (int*)(ws + D0 + 90624000);
  int* iroff = ideg + 3008;
  int* ieord = iroff + 3008;
  float* hg  = ws + D0 + 90650000;
  float* hgp = ws + D0 + 90652048;
  // GAT-layers phase:
  unsigned short* xw_sb = (unsigned short*)(ws + D0 + 40000000);   // 1.536M f
  float* gat_s = ws + D0 + 41600000;           //  3.072M
  // heads (xwallb/gatallb dead):
  float* hidn = ws + D0;                       //  5.376M
  unsigned short* efb = (unsigned short*)(ws + D0 + 5376000);      // 12.288M f
  float* hide = ws + D0 + 17664000;            //  6.144M

  auto mgemm = [&](const unsigned short* A, const unsigned short* Wt, const float* bias,
                   void* C, int M, int N, int K, int lda, int flags) {
    dim3 grid(N / 64, (M + 127) / 128);
    gemm_bfa_k<<<grid, dim3(256), 0, stream>>>(A, Wt, bias, C, M, N, K, lda, flags);
  };
  auto cvtb = [&](const float* W, unsigned short* Wt, int K, int N, int L) {
    const int total = K * N * L;
    wtb_k<<<(total + 255) / 256, 256, 0, stream>>>(W, Wt, K, N, total);
  };

  // ---- weight convert/transpose/permute ----
  cvtb(wqkv, wt_qkv, 256, 768, 1);
  cvtb(wo, wt_wo, 256, 256, 1);
  cvtb(tg_W, wt_tgW, 256, 256, 1);
  cvtb(tg_We, wt_tgWe, 256, 256, 1);
  cvtb(g_We, wt_gWe, 256, 256, 3);
  wtp_k<<<1024, 256, 0, stream>>>(w_ih, wt_lstm, 0);
  wtp_k<<<1024, 256, 0, stream>>>(w_hh, wt_lstm, 256);
  cvtb(g_W, wt_gW, 256, 256, 3);
  cvtb(hn_w1, wt_hn, 256, 64, 7);
  cvtb(he_w1, wt_he, 512, 64, 2);

  // ---- CSR build (deterministic) ----
  hipMemsetAsync(ideg, 0, 3000 * sizeof(int), stream);
  hist_k<<<(E_ + 255) / 256, 256, 0, stream>>>(dst, ideg);
  scan_k<<<1, 256, 0, stream>>>(ideg, iroff);
  fill_k<<<750, 256, 0, stream>>>(dst, iroff, ieord);

  // ---------------- Stage A ----------------
  for (int chunk = 0; chunk < 8; ++chunk) {
    dim3 grid(768 / 64, (36000 + 127) / 128);
    gemm_qkv_k<<<grid, dim3(256), 0, stream>>>(env, infra, robot, wt_qkv, bqkv,
                                               qkvb, 36000, chunk * 12000);
    attn_avg_k<<<3000, 256, 0, stream>>>(qkvb, obarb + (size_t)chunk * 12000 * 256, 12000);
  }
  // tmpAb = obar @ wo + bo (bf16), then fseq = LN(tmpAb)
  mgemm(obarb, wt_wo, bo, tmpAb, 96000, 256, 256, 256, 4);
  ln_k<<<96000, 64, 0, stream>>>(tmpAb, lnf_g, lnf_b, fseqb);

  // ---------------- Stage B prep ----------------
  {  // edge_emb = relu(edge_attr @ we_emb + be_emb) -> bf16
    dim3 grid(4, 750);
    gemm_k<<<grid, dim3(256), 0, stream>>>(edgeattr, we_emb, be_emb, eembb,
                                           48000, 256, 8, 8, 2 | 4);
  }
  // one batched edge-transform GEMM: [tgWe | gWe0 | gWe1 | gWe2], N=1024
  mgemm(eembb, wt_tgWe, nullptr, ewall, 48000, 1024, 256, 256, 4);
  elog4_k<<<6000, 256, 0, stream>>>(ewall, tg_aedge, g_aedge, elogall);

  mgemm(fseqb, wt_tgW, nullptr, xwallb, 96000, 256, 256, 256, 4);
  alphas_k<<<3000, 256, 0, stream>>>(xwallb, tg_asrc, tg_adst, sal, dal, 96000);
  gat_k<1><<<24000, 256, 0, stream>>>(xwallb, ewall, sal, dal, elogall, iroff, ieord,
                                      src, gatallb, 96000, 3, 1024, 0);

  // ---------------- LSTM over T (fused GEMM + pointwise) ----------------
  hipMemsetAsync(c, 0, 12288000, stream);
  hipMemsetAsync(hb0, 0, 6144000, stream);
  unsigned short* hbq[2] = { hb0, hb1 };
  for (int t = 0; t < T_; ++t) {
    dim3 grid(16, 94);
    gemm_lstm_k<<<grid, dim3(256), 0, stream>>>(gatallb, hbq[t & 1], wt_lstm, b_lstm,
                                                h, c, hbq[(t + 1) & 1], t);
  }
  unsigned short* hbf = hbq[0];  // T=8 even -> final h in hb0

  // ---------------- 3 GAT layers with residual LN ----------------
  for (int l = 0; l < 3; ++l) {
    mgemm(hbf, wt_gW + (size_t)l * 65536, nullptr, xw_sb, 12000, 256, 256, 256, 4);
    alphas_k<<<375, 256, 0, stream>>>(xw_sb, g_asrc + l * 256, g_adst + l * 256, sal, dal, 12000);
    gat_k<0><<<3000, 256, 0, stream>>>(xw_sb, ewall, sal, dal, elogall + 384000 * (l + 1),
                                       iroff, ieord, src, gat_s, 12000, 0,
                                       1024, 256 * (l + 1));
    resln_k<<<12000, 64, 0, stream>>>(h, gat_s, g_lng + l * 256, g_lnb + l * 256, hbf);
  }

  // ---------------- Heads ----------------
  mgemm(hbf, wt_hn, hn_b1, hidn, 12000, 448, 256, 256, 2);
  nh2_k<<<(84000 + 255) / 256, 256, 0, stream>>>(hidn, hn_w2, hn_b2, outp);

  hglob1_k<<<dim3(4, 25), 256, 0, stream>>>(h, hgp);
  hglob2_k<<<4, 256, 0, stream>>>(hgp, hg);
  freq_k<<<4, 64, 0, stream>>>(hg, hn_w1 + 7 * 16384, hn_b1 + 7 * 64,
                               hn_w2 + 7 * 64, hn_b2 + 7, outp);

  ef_k<<<12000, 256, 0, stream>>>(hbf, src, dst, efb);
  mgemm(efb, wt_he, he_b1, hide, 48000, 128, 512, 512, 2);
  eh2_k<<<(96000 + 255) / 256, 256, 0, stream>>>(hide, he_w2, he_b2, outp);
}

// Round 13
// 1626.615 us; speedup vs baseline: 1.0887x; 1.0343x over previous
//
#include <hip/hip_runtime.h>
#include <hip/hip_bf16.h>
#include <math.h>

#define DEV __device__ __forceinline__

namespace {
constexpr int B_ = 4, T_ = 8, N_ = 3000, E_ = 12000;
constexpr int OUTS_ = 45001;  // per-batch output stride: N*7 + E + E + 1
}

using f32x4 = __attribute__((ext_vector_type(4))) float;
using bf16x8 = __attribute__((ext_vector_type(8))) short;

DEV float sigm_(float x) { return 1.0f / (1.0f + expf(-x)); }
DEV float softplus_(float x) { return fmaxf(x, 0.0f) + log1pf(expf(-fabsf(x))); }
DEV float wred_(float v) {
  #pragma unroll
  for (int o = 32; o > 0; o >>= 1) v += __shfl_xor(v, o, 64);
  return v;
}
DEV unsigned short f2bf(float x) {  // RNE fp32->bf16
  unsigned u = __float_as_uint(x);
  return (unsigned short)((u + 0x7FFFu + ((u >> 16) & 1u)) >> 16);
}
DEV unsigned f2bf2(float a, float b) {
  return (unsigned)f2bf(a) | ((unsigned)f2bf(b) << 16);
}
DEV float bfl(unsigned u) { return __uint_as_float(u << 16); }
DEV float bfh(unsigned u) { return __uint_as_float(u & 0xffff0000u); }

// ---------------------------------------------------------------------------
// Batched weight transpose+convert: L matrices [K][N] -> per-matrix [N][K] bf16
// ---------------------------------------------------------------------------
__global__ void wtb_k(const float* __restrict__ W, unsigned short* __restrict__ Wt,
                      int K, int N, int total)
{
  const int idx = blockIdx.x * blockDim.x + threadIdx.x;
  if (idx >= total) return;
  const int kn = K * N;
  const int l = idx / kn;
  const int r = idx - l * kn;
  const int k = r / N, n = r - k * N;
  Wt[(size_t)l * kn + (size_t)n * K + k] = f2bf(W[idx]);
}

// LSTM weight permute: orig col n = gate*256+d -> newcol = d*4+gate; dense [1024][512]
__global__ void wtp_k(const float* __restrict__ W, unsigned short* __restrict__ Wt,
                      int kOff)
{
  const int idx = blockIdx.x * blockDim.x + threadIdx.x;
  if (idx >= 256 * 1024) return;
  const int k = idx >> 10;
  const int n = idx & 1023;
  const int newcol = (n & 255) * 4 + (n >> 8);
  Wt[(size_t)newcol * 512 + kOff + k] = f2bf(W[idx]);
}

// ---------------------------------------------------------------------------
// CSR build (deterministic)
// ---------------------------------------------------------------------------
__global__ void hist_k(const int* __restrict__ dst, int* __restrict__ deg)
{
  const int e = blockIdx.x * blockDim.x + threadIdx.x;
  if (e < E_) atomicAdd(&deg[dst[e]], 1);
}

__global__ __launch_bounds__(256) void scan_k(const int* __restrict__ deg,
                                              int* __restrict__ roff)
{
  __shared__ int part[256];
  const int t = threadIdx.x;
  int loc[12];
  int s = 0;
  #pragma unroll
  for (int i = 0; i < 12; ++i) {
    const int n = t * 12 + i;
    loc[i] = s;
    s += (n < N_) ? deg[n] : 0;
  }
  part[t] = s;
  __syncthreads();
  if (t == 0) {
    int run = 0;
    for (int i = 0; i < 256; ++i) { const int v = part[i]; part[i] = run; run += v; }
  }
  __syncthreads();
  const int base = part[t];
  #pragma unroll
  for (int i = 0; i < 12; ++i) {
    const int n = t * 12 + i;
    if (n < N_) roff[n] = base + loc[i];
  }
  if (t == 0) roff[N_] = E_;
}

__global__ __launch_bounds__(256) void fill_k(const int* __restrict__ dst,
                                              const int* __restrict__ roff,
                                              int* __restrict__ eord)
{
  const int n = blockIdx.x * 4 + (threadIdx.x >> 6);
  if (n >= N_) return;
  const int lane = threadIdx.x & 63;
  const unsigned long long ltm = (1ull << lane) - 1ull;
  int cnt = roff[n];
  for (int c = 0; c < E_; c += 64) {
    const int e = c + lane;
    const bool m = (e < E_) && (dst[e] == n);
    const unsigned long long mask = __ballot(m);
    if (m) eord[cnt + __popcll(mask & ltm)] = e;
    cnt += __popcll(mask);
  }
}

// ---------------------------------------------------------------------------
// 128x64-tile MFMA bf16 GEMM: C[M,N] = A[M,K](bf16) @ Wt(bf16,[N][K])
// flags: 1 = C += (fp32 C), 2 = relu, 4 = store bf16 C.
// ---------------------------------------------------------------------------
__global__ __launch_bounds__(256) void gemm_bfa_k(
    const unsigned short* __restrict__ A, const unsigned short* __restrict__ Wt,
    const float* __restrict__ bias, void* __restrict__ Cv,
    int M, int N, int K, int lda, int flags)
{
  __shared__ unsigned short Al[128 * 40];
  __shared__ unsigned short Bl[64 * 40];
  const int tid = threadIdx.x;
  const int bm = blockIdx.y * 128;
  const int bn = blockIdx.x * 64;
  const int lane = tid & 63;
  const int wv = tid >> 6;
  const int wm = (wv >> 1) * 64;
  const int wn = (wv & 1) * 32;
  const int s_row = tid >> 1;
  const int s_cb = (tid & 1) * 16;
  const int grow = bm + s_row;
  const unsigned short* Arow = (grow < M) ? A + (size_t)grow * lda : nullptr;
  const int b_col = tid >> 2;
  const int b_ks = (tid & 3) * 8;
  const unsigned short* Wrow = Wt + (size_t)(bn + b_col) * K + b_ks;

  f32x4 acc[4][2] = {};
  const int l15 = lane & 15;
  const int lk = (lane >> 4) * 8;

  for (int k0 = 0; k0 < K; k0 += 32) {
    uint4 a0, a1;
    if (Arow) {
      a0 = *(const uint4*)(Arow + k0 + s_cb);
      a1 = *(const uint4*)(Arow + k0 + s_cb + 8);
    } else {
      a0 = make_uint4(0, 0, 0, 0);
      a1 = a0;
    }
    *(uint4*)&Al[s_row * 40 + s_cb] = a0;
    *(uint4*)&Al[s_row * 40 + s_cb + 8] = a1;
    *(uint4*)&Bl[b_col * 40 + b_ks] = *(const uint4*)(Wrow + k0);
    __syncthreads();
    bf16x8 af[4], bfr[2];
    #pragma unroll
    for (int m = 0; m < 4; ++m)
      af[m] = *(const bf16x8*)&Al[(wm + m * 16 + l15) * 40 + lk];
    #pragma unroll
    for (int n = 0; n < 2; ++n)
      bfr[n] = *(const bf16x8*)&Bl[(wn + n * 16 + l15) * 40 + lk];
    #pragma unroll
    for (int m = 0; m < 4; ++m)
      #pragma unroll
      for (int n = 0; n < 2; ++n)
        acc[m][n] = __builtin_amdgcn_mfma_f32_16x16x32_bf16(af[m], bfr[n], acc[m][n], 0, 0, 0);
    __syncthreads();
  }
  float* Cf = (float*)Cv;
  unsigned short* Cb = (unsigned short*)Cv;
  const int r4 = (lane >> 4) * 4;
  #pragma unroll
  for (int m = 0; m < 4; ++m) {
    #pragma unroll
    for (int n = 0; n < 2; ++n) {
      const int col = bn + wn + n * 16 + l15;
      const float bv = bias ? bias[col] : 0.f;
      #pragma unroll
      for (int r = 0; r < 4; ++r) {
        const int row = bm + wm + m * 16 + r4 + r;
        if (row >= M) continue;
        float v = acc[m][n][r] + bv;
        const size_t ci = (size_t)row * N + col;
        if (flags & 1) v += Cf[ci];
        if (flags & 2) v = fmaxf(v, 0.f);
        if (flags & 4) Cb[ci] = f2bf(v);
        else Cf[ci] = v;
      }
    }
  }
}

// ---------------------------------------------------------------------------
// Stage-A qkv GEMM: A rows are fp32 from 3 interleaved sources
// (row r: slot=r%3, node=nodeBase+r/3). Converts to bf16 in staging.
// ---------------------------------------------------------------------------
__global__ __launch_bounds__(256) void gemm_qkv_k(
    const float* __restrict__ env, const float* __restrict__ infra,
    const float* __restrict__ robot, const unsigned short* __restrict__ Wt,
    const float* __restrict__ bias, unsigned short* __restrict__ Cb,
    int M, int nodeBase)
{
  __shared__ unsigned short Al[128 * 40];
  __shared__ unsigned short Bl[64 * 40];
  const int tid = threadIdx.x;
  const int bm = blockIdx.y * 128;
  const int bn = blockIdx.x * 64;
  const int lane = tid & 63;
  const int wv = tid >> 6;
  const int wm = (wv >> 1) * 64;
  const int wn = (wv & 1) * 32;
  const int s_row = tid >> 1;
  const int s_cb = (tid & 1) * 16;
  const int grow = bm + s_row;
  const float* Arow = nullptr;
  if (grow < M) {
    const int slot = grow % 3;
    const int node = nodeBase + grow / 3;
    const float* srcp = (slot == 0 ? env : (slot == 1 ? infra : robot));
    Arow = srcp + (size_t)node * 256;
  }
  const int b_col = tid >> 2;
  const int b_ks = (tid & 3) * 8;
  const unsigned short* Wrow = Wt + (size_t)(bn + b_col) * 256 + b_ks;

  f32x4 acc[4][2] = {};
  const int l15 = lane & 15;
  const int lk = (lane >> 4) * 8;

  for (int k0 = 0; k0 < 256; k0 += 32) {
    unsigned abuf[8];
    if (Arow) {
      const float* p = Arow + k0 + s_cb;
      #pragma unroll
      for (int i = 0; i < 4; ++i) {
        const float4 v = *(const float4*)(p + i * 4);
        abuf[i * 2 + 0] = f2bf2(v.x, v.y);
        abuf[i * 2 + 1] = f2bf2(v.z, v.w);
      }
    } else {
      #pragma unroll
      for (int i = 0; i < 8; ++i) abuf[i] = 0;
    }
    *(uint4*)&Al[s_row * 40 + s_cb] = *(uint4*)&abuf[0];
    *(uint4*)&Al[s_row * 40 + s_cb + 8] = *(uint4*)&abuf[4];
    *(uint4*)&Bl[b_col * 40 + b_ks] = *(const uint4*)(Wrow + k0);
    __syncthreads();
    bf16x8 af[4], bfr[2];
    #pragma unroll
    for (int m = 0; m < 4; ++m)
      af[m] = *(const bf16x8*)&Al[(wm + m * 16 + l15) * 40 + lk];
    #pragma unroll
    for (int n = 0; n < 2; ++n)
      bfr[n] = *(const bf16x8*)&Bl[(wn + n * 16 + l15) * 40 + lk];
    #pragma unroll
    for (int m = 0; m < 4; ++m)
      #pragma unroll
      for (int n = 0; n < 2; ++n)
        acc[m][n] = __builtin_amdgcn_mfma_f32_16x16x32_bf16(af[m], bfr[n], acc[m][n], 0, 0, 0);
    __syncthreads();
  }
  const int r4 = (lane >> 4) * 4;
  #pragma unroll
  for (int m = 0; m < 4; ++m) {
    #pragma unroll
    for (int n = 0; n < 2; ++n) {
      const int col = bn + wn + n * 16 + l15;
      const float bv = bias[col];
      #pragma unroll
      for (int r = 0; r < 4; ++r) {
        const int row = bm + wm + m * 16 + r4 + r;
        if (row >= M) continue;
        Cb[(size_t)row * 768 + col] = f2bf(acc[m][n][r] + bv);
      }
    }
  }
}

// ---------------------------------------------------------------------------
// Fused LSTM step: gates = [gat_t | h] @ Wt_perm (kEnd=512; kEnd=256 at t=0
// since h==0), newcol = d*4+gate; LSTM pointwise in epilogue via LDS transpose.
// Writes c, h (fp32), hbOut. hbIn/hbOut MUST differ (cross-block race).
// ---------------------------------------------------------------------------
__global__ __launch_bounds__(256) void gemm_lstm_k(
    const unsigned short* __restrict__ gatall, const unsigned short* __restrict__ hbIn,
    const unsigned short* __restrict__ Wt, const float* __restrict__ b_lstm,
    float* __restrict__ h, float* __restrict__ c, unsigned short* __restrict__ hbOut,
    int t, int kEnd)
{
  __shared__ float Gl[128][65];
  unsigned short* Al = (unsigned short*)&Gl[0][0];
  unsigned short* Bl = Al + 128 * 40;
  const int tid = threadIdx.x;
  const int bm = blockIdx.y * 128;
  const int bn = blockIdx.x * 64;
  const int lane = tid & 63;
  const int wv = tid >> 6;
  const int wm = (wv >> 1) * 64;
  const int wn = (wv & 1) * 32;
  const int s_row = tid >> 1;
  const int s_cb = (tid & 1) * 16;
  const int grow = bm + s_row;
  const unsigned short* Arow1 = nullptr;
  const unsigned short* Arow2 = nullptr;
  if (grow < 12000) {
    const int phys = (grow / N_) * (T_ * N_) + t * N_ + (grow % N_);
    Arow1 = gatall + (size_t)phys * 256;
    Arow2 = hbIn + (size_t)grow * 256;
  }
  const int b_col = tid >> 2;
  const int b_ks = (tid & 3) * 8;
  const unsigned short* Wrow = Wt + (size_t)(bn + b_col) * 512 + b_ks;

  f32x4 acc[4][2] = {};
  const int l15 = lane & 15;
  const int lk = (lane >> 4) * 8;

  for (int k0 = 0; k0 < kEnd; k0 += 32) {
    uint4 a0, a1;
    if (Arow1) {
      const unsigned short* p = (k0 < 256) ? (Arow1 + k0 + s_cb)
                                           : (Arow2 + (k0 - 256) + s_cb);
      a0 = *(const uint4*)p;
      a1 = *(const uint4*)(p + 8);
    } else {
      a0 = make_uint4(0, 0, 0, 0);
      a1 = a0;
    }
    *(uint4*)&Al[s_row * 40 + s_cb] = a0;
    *(uint4*)&Al[s_row * 40 + s_cb + 8] = a1;
    *(uint4*)&Bl[b_col * 40 + b_ks] = *(const uint4*)(Wrow + k0);
    __syncthreads();
    bf16x8 af[4], bfr[2];
    #pragma unroll
    for (int m = 0; m < 4; ++m)
      af[m] = *(const bf16x8*)&Al[(wm + m * 16 + l15) * 40 + lk];
    #pragma unroll
    for (int n = 0; n < 2; ++n)
      bfr[n] = *(const bf16x8*)&Bl[(wn + n * 16 + l15) * 40 + lk];
    #pragma unroll
    for (int m = 0; m < 4; ++m)
      #pragma unroll
      for (int n = 0; n < 2; ++n)
        acc[m][n] = __builtin_amdgcn_mfma_f32_16x16x32_bf16(af[m], bfr[n], acc[m][n], 0, 0, 0);
    __syncthreads();
  }
  const int r4 = (lane >> 4) * 4;
  #pragma unroll
  for (int m = 0; m < 4; ++m)
    #pragma unroll
    for (int n = 0; n < 2; ++n) {
      const int col = wn + n * 16 + l15;
      #pragma unroll
      for (int r = 0; r < 4; ++r)
        Gl[wm + m * 16 + r4 + r][col] = acc[m][n][r];
    }
  __syncthreads();
  const int fl = lane & 7;
  const int rg = lane >> 3;
  const int dg = ((bn + wn) >> 2) + fl;
  const float bi = b_lstm[dg];
  const float bff = b_lstm[256 + dg];
  const float bg = b_lstm[512 + dg];
  const float bo = b_lstm[768 + dg];
  const int colb = wn + fl * 4;
  #pragma unroll
  for (int i = 0; i < 8; ++i) {
    const int rl = rg + i * 8;
    const int row = bm + wm + rl;
    if (row >= 12000) continue;
    const float g0 = Gl[wm + rl][colb + 0] + bi;
    const float g1 = Gl[wm + rl][colb + 1] + bff;
    const float g2 = Gl[wm + rl][colb + 2] + bg;
    const float g3 = Gl[wm + rl][colb + 3] + bo;
    const size_t idx = (size_t)row * 256 + dg;
    const float cn = sigm_(g1) * c[idx] + sigm_(g0) * tanhf(g2);
    c[idx] = cn;
    const float hn = sigm_(g3) * tanhf(cn);
    h[idx] = hn;
    hbOut[idx] = f2bf(hn);
  }
}

// ---------------------------------------------------------------------------
// Edge-head GEMM with fused ef gather: A row r (of 48000) = concat(
// hb[b,src[e]], hb[b,dst[e]]), b=r/E, e=r%E. K=512, N=128, relu, fp32 out.
// ---------------------------------------------------------------------------
__global__ __launch_bounds__(256) void gemm_ef_k(
    const unsigned short* __restrict__ hb, const int* __restrict__ srcA,
    const int* __restrict__ dstA, const unsigned short* __restrict__ Wt,
    const float* __restrict__ bias, float* __restrict__ Cf)
{
  __shared__ unsigned short Al[128 * 40];
  __shared__ unsigned short Bl[64 * 40];
  const int tid = threadIdx.x;
  const int bm = blockIdx.y * 128;
  const int bn = blockIdx.x * 64;
  const int lane = tid & 63;
  const int wv = tid >> 6;
  const int wm = (wv >> 1) * 64;
  const int wn = (wv & 1) * 32;
  const int s_row = tid >> 1;
  const int s_cb = (tid & 1) * 16;
  const int grow = bm + s_row;
  const unsigned short* Arow1 = nullptr;
  const unsigned short* Arow2 = nullptr;
  if (grow < 48000) {
    const int b = grow / E_;
    const int e = grow - b * E_;
    Arow1 = hb + ((size_t)(b * N_ + srcA[e])) * 256;
    Arow2 = hb + ((size_t)(b * N_ + dstA[e])) * 256;
  }
  const int b_col = tid >> 2;
  const int b_ks = (tid & 3) * 8;
  const unsigned short* Wrow = Wt + (size_t)(bn + b_col) * 512 + b_ks;

  f32x4 acc[4][2] = {};
  const int l15 = lane & 15;
  const int lk = (lane >> 4) * 8;

  for (int k0 = 0; k0 < 512; k0 += 32) {
    uint4 a0, a1;
    if (Arow1) {
      const unsigned short* p = (k0 < 256) ? (Arow1 + k0 + s_cb)
                                           : (Arow2 + (k0 - 256) + s_cb);
      a0 = *(const uint4*)p;
      a1 = *(const uint4*)(p + 8);
    } else {
      a0 = make_uint4(0, 0, 0, 0);
      a1 = a0;
    }
    *(uint4*)&Al[s_row * 40 + s_cb] = a0;
    *(uint4*)&Al[s_row * 40 + s_cb + 8] = a1;
    *(uint4*)&Bl[b_col * 40 + b_ks] = *(const uint4*)(Wrow + k0);
    __syncthreads();
    bf16x8 af[4], bfr[2];
    #pragma unroll
    for (int m = 0; m < 4; ++m)
      af[m] = *(const bf16x8*)&Al[(wm + m * 16 + l15) * 40 + lk];
    #pragma unroll
    for (int n = 0; n < 2; ++n)
      bfr[n] = *(const bf16x8*)&Bl[(wn + n * 16 + l15) * 40 + lk];
    #pragma unroll
    for (int m = 0; m < 4; ++m)
      #pragma unroll
      for (int n = 0; n < 2; ++n)
        acc[m][n] = __builtin_amdgcn_mfma_f32_16x16x32_bf16(af[m], bfr[n], acc[m][n], 0, 0, 0);
    __syncthreads();
  }
  const int r4 = (lane >> 4) * 4;
  #pragma unroll
  for (int m = 0; m < 4; ++m) {
    #pragma unroll
    for (int n = 0; n < 2; ++n) {
      const int col = bn + wn + n * 16 + l15;
      const float bv = bias[col];
      #pragma unroll
      for (int r = 0; r < 4; ++r) {
        const int row = bm + wm + m * 16 + r4 + r;
        if (row >= 48000) continue;
        Cf[(size_t)row * 128 + col] = fmaxf(acc[m][n][r] + bv, 0.f);
      }
    }
  }
}

// ---------------------------------------------------------------------------
// fp32 fallback GEMM (only the K=8 edge-emb GEMM); flags&4 -> bf16 C store
// ---------------------------------------------------------------------------
__global__ __launch_bounds__(256) void gemm_k(
    const float* __restrict__ A, const float* __restrict__ W,
    const float* __restrict__ bias, void* __restrict__ Cv,
    int M, int N, int K, int lda, int flags)
{
  __shared__ float As[16][68];
  __shared__ float Ws[16][64];
  const int tid = threadIdx.x;
  const int bm = blockIdx.y * 64;
  const int bn = blockIdx.x * 64;
  const int tx = tid & 15;
  const int ty = tid >> 4;
  const int ar = tid >> 2;
  const int ac = (tid & 3) << 2;
  const int wr = tid >> 4;
  const int wc = (tid & 15) << 2;
  const int grow = bm + ar;
  const float* Arow = (grow < M) ? A + (size_t)grow * lda : nullptr;
  float acc[4][4] = {};
  for (int k0 = 0; k0 < K; k0 += 16) {
    float4 av = make_float4(0.f, 0.f, 0.f, 0.f);
    if (Arow) {
      av.x = (k0 + ac + 0 < K) ? Arow[k0 + ac + 0] : 0.f;
      av.y = (k0 + ac + 1 < K) ? Arow[k0 + ac + 1] : 0.f;
      av.z = (k0 + ac + 2 < K) ? Arow[k0 + ac + 2] : 0.f;
      av.w = (k0 + ac + 3 < K) ? Arow[k0 + ac + 3] : 0.f;
    }
    As[ac + 0][ar] = av.x;
    As[ac + 1][ar] = av.y;
    As[ac + 2][ar] = av.z;
    As[ac + 3][ar] = av.w;
    float4 wv = make_float4(0.f, 0.f, 0.f, 0.f);
    if (k0 + wr < K) {
      const int gc = bn + wc;
      const float* wp = W + (size_t)(k0 + wr) * N + gc;
      wv.x = (gc + 0 < N) ? wp[0] : 0.f;
      wv.y = (gc + 1 < N) ? wp[1] : 0.f;
      wv.z = (gc + 2 < N) ? wp[2] : 0.f;
      wv.w = (gc + 3 < N) ? wp[3] : 0.f;
    }
    *(float4*)&Ws[wr][wc] = wv;
    __syncthreads();
    #pragma unroll
    for (int kk = 0; kk < 16; ++kk) {
      const float4 a = *(const float4*)&As[kk][ty << 2];
      const float4 b = *(const float4*)&Ws[kk][tx << 2];
      acc[0][0] += a.x * b.x; acc[0][1] += a.x * b.y; acc[0][2] += a.x * b.z; acc[0][3] += a.x * b.w;
      acc[1][0] += a.y * b.x; acc[1][1] += a.y * b.y; acc[1][2] += a.y * b.z; acc[1][3] += a.y * b.w;
      acc[2][0] += a.z * b.x; acc[2][1] += a.z * b.y; acc[2][2] += a.z * b.z; acc[2][3] += a.z * b.w;
      acc[3][0] += a.w * b.x; acc[3][1] += a.w * b.y; acc[3][2] += a.w * b.z; acc[3][3] += a.w * b.w;
    }
    __syncthreads();
  }
  float* Cf = (float*)Cv;
  unsigned short* Cb = (unsigned short*)Cv;
  #pragma unroll
  for (int i = 0; i < 4; ++i) {
    const int row = bm + (ty << 2) + i;
    if (row >= M) continue;
    #pragma unroll
    for (int j = 0; j < 4; ++j) {
      const int col = bn + (tx << 2) + j;
      if (col >= N) continue;
      float v = acc[i][j];
      if (bias) v += bias[col];
      if (flags & 2) v = fmaxf(v, 0.f);
      const size_t ci = (size_t)row * N + col;
      if (flags & 4) Cb[ci] = f2bf(v);
      else Cf[ci] = v;
    }
  }
}

// ---------------------------------------------------------------------------
// Stage A attention: ONE WAVE PER NODE (coalesced). Lane l -> head l>>3,
// elems (l&7)*4; qkv offset = node*2304 + 4*l. 9 dots reduce over the 8-lane
// subgroup via shfl_xor(1,2,4). 4 waves/block.
// ---------------------------------------------------------------------------
__global__ __launch_bounds__(256) void attn_avg_k(
    const unsigned short* __restrict__ qkv,
    unsigned short* __restrict__ obar, int nodes)
{
  const int node = blockIdx.x * 4 + (threadIdx.x >> 6);
  if (node >= nodes) return;
  const int lane = threadIdx.x & 63;
  const unsigned short* base = qkv + (size_t)node * 2304 + lane * 4;
  float qv[3][4], kv[3][4], vv[3][4];
  #pragma unroll
  for (int s = 0; s < 3; ++s) {
    const uint2 uq = *(const uint2*)(base + s * 768);
    const uint2 uk = *(const uint2*)(base + s * 768 + 256);
    const uint2 uv = *(const uint2*)(base + s * 768 + 512);
    qv[s][0] = bfl(uq.x); qv[s][1] = bfh(uq.x); qv[s][2] = bfl(uq.y); qv[s][3] = bfh(uq.y);
    kv[s][0] = bfl(uk.x); kv[s][1] = bfh(uk.x); kv[s][2] = bfl(uk.y); kv[s][3] = bfh(uk.y);
    vv[s][0] = bfl(uv.x); vv[s][1] = bfh(uv.x); vv[s][2] = bfl(uv.y); vv[s][3] = bfh(uv.y);
  }
  float att[3][3];
  #pragma unroll
  for (int s = 0; s < 3; ++s) {
    #pragma unroll
    for (int t = 0; t < 3; ++t) {
      float d = qv[s][0] * kv[t][0] + qv[s][1] * kv[t][1]
              + qv[s][2] * kv[t][2] + qv[s][3] * kv[t][3];
      d += __shfl_xor(d, 1, 64);
      d += __shfl_xor(d, 2, 64);
      d += __shfl_xor(d, 4, 64);
      att[s][t] = d * 0.17677669529663687f;
    }
  }
  float cs[3] = {0.f, 0.f, 0.f};
  #pragma unroll
  for (int s = 0; s < 3; ++s) {
    const float m = fmaxf(att[s][0], fmaxf(att[s][1], att[s][2]));
    const float e0 = expf(att[s][0] - m);
    const float e1 = expf(att[s][1] - m);
    const float e2 = expf(att[s][2] - m);
    const float inv = (1.f / 3.f) / (e0 + e1 + e2);
    cs[0] += e0 * inv; cs[1] += e1 * inv; cs[2] += e2 * inv;
  }
  float o0 = cs[0] * vv[0][0] + cs[1] * vv[1][0] + cs[2] * vv[2][0];
  float o1 = cs[0] * vv[0][1] + cs[1] * vv[1][1] + cs[2] * vv[2][1];
  float o2 = cs[0] * vv[0][2] + cs[1] * vv[1][2] + cs[2] * vv[2][2];
  float o3 = cs[0] * vv[0][3] + cs[1] * vv[1][3] + cs[2] * vv[2][3];
  uint2 ob;
  ob.x = f2bf2(o0, o1);
  ob.y = f2bf2(o2, o3);
  *(uint2*)(obar + (size_t)node * 256 + lane * 4) = ob;
}

// LayerNorm per row; bf16 in, bf16 out. 1 wave per row.
__global__ __launch_bounds__(64) void ln_k(
    const unsigned short* __restrict__ in, const float* __restrict__ g,
    const float* __restrict__ bta, unsigned short* __restrict__ outp)
{
  const int row = blockIdx.x;
  const int d0 = threadIdx.x << 2;
  const uint2 a = *(const uint2*)(in + (size_t)row * 256 + d0);
  float x[4] = { bfl(a.x), bfh(a.x), bfl(a.y), bfh(a.y) };
  float s = x[0] + x[1] + x[2] + x[3];
  s = wred_(s);
  const float mean = s * (1.f / 256.f);
  float vs = 0.f;
  #pragma unroll
  for (int i = 0; i < 4; ++i) { const float dd = x[i] - mean; vs += dd * dd; }
  vs = wred_(vs);
  const float inv = 1.0f / sqrtf(vs * (1.f / 256.f) + 1e-5f);
  const float4 gv = *(const float4*)(g + d0);
  const float4 bv = *(const float4*)(bta + d0);
  uint2 o;
  o.x = f2bf2((x[0] - mean) * inv * gv.x + bv.x, (x[1] - mean) * inv * gv.y + bv.y);
  o.y = f2bf2((x[2] - mean) * inv * gv.z + bv.z, (x[3] - mean) * inv * gv.w + bv.w);
  *(uint2*)(outp + (size_t)row * 256 + d0) = o;
}

// ---------------------------------------------------------------------------
// GAT kernels (bf16 feature inputs)
// ---------------------------------------------------------------------------
__global__ void alphas_k(const unsigned short* __restrict__ xw, const float* __restrict__ as,
                         const float* __restrict__ ad, float* __restrict__ sal,
                         float* __restrict__ dal, int rows)
{
  const int idx = blockIdx.x * blockDim.x + threadIdx.x;
  if (idx >= rows * 8) return;
  const int row = idx >> 3, h = idx & 7;
  const unsigned short* x = xw + (size_t)row * 256 + h * 32;
  const float* a1 = as + h * 32;
  const float* a2 = ad + h * 32;
  float s = 0.f, d = 0.f;
  #pragma unroll
  for (int i = 0; i < 4; ++i) {
    const uint4 ux = *(const uint4*)(x + i * 8);
    const unsigned* p = &ux.x;
    #pragma unroll
    for (int j = 0; j < 4; ++j) {
      const float lo = bfl(p[j]), hi = bfh(p[j]);
      s += lo * a1[i * 8 + 2 * j] + hi * a1[i * 8 + 2 * j + 1];
      d += lo * a2[i * 8 + 2 * j] + hi * a2[i * 8 + 2 * j + 1];
    }
  }
  sal[idx] = s; dal[idx] = d;
}

// all 4 edge-logit sets in one launch; ew is [48000][1024] (4 x 256 packed)
__global__ void elog4_k(const unsigned short* __restrict__ ew,
                        const float* __restrict__ tg_ae, const float* __restrict__ g_ae,
                        float* __restrict__ el)
{
  const int idx = blockIdx.x * blockDim.x + threadIdx.x;
  if (idx >= 4 * 48000 * 8) return;
  const int l = idx / (48000 * 8);
  const int r = idx - l * (48000 * 8);
  const int row = r >> 3, h = r & 7;
  const unsigned short* x = ew + (size_t)row * 1024 + l * 256 + h * 32;
  const float* a1 = (l == 0 ? tg_ae : g_ae + (l - 1) * 256) + h * 32;
  float s = 0.f;
  #pragma unroll
  for (int i = 0; i < 4; ++i) {
    const uint4 ux = *(const uint4*)(x + i * 8);
    const unsigned* p = &ux.x;
    #pragma unroll
    for (int j = 0; j < 4; ++j) {
      s += bfl(p[j]) * a1[i * 8 + 2 * j] + bfh(p[j]) * a1[i * 8 + 2 * j + 1];
    }
  }
  el[l * 384000 + r] = s;
}

// Fused GAT aggregation: one wave per (beta,node). Online softmax over incoming
// edges (CSR). bf16 gathers. OUTBF: 1 -> bf16 out, 0 -> fp32 out.
template<int OUTBF>
__global__ __launch_bounds__(256) void gat_k(
    const unsigned short* __restrict__ xw, const unsigned short* __restrict__ ew,
    const float* __restrict__ sal, const float* __restrict__ dal,
    const float* __restrict__ el, const int* __restrict__ roff,
    const int* __restrict__ eord, const int* __restrict__ srcArr,
    void* __restrict__ outp, int nwaves, int tshift, int ewStride, int ewOff)
{
  const int wid = blockIdx.x * 4 + (threadIdx.x >> 6);
  if (wid >= nwaves) return;
  const int beta = wid / N_;
  const int n = wid - beta * N_;
  const int b = beta >> tshift;
  const int lane = threadIdx.x & 63;
  const int h = lane >> 3;
  const int d0 = lane << 2;
  const float dal_h = dal[(size_t)wid * 8 + h];
  const int p0 = roff[n], p1 = roff[n + 1];
  float m = -1e30f, s = 0.f;
  float4 acc = make_float4(0.f, 0.f, 0.f, 0.f);
  for (int p = p0; p < p1; ++p) {
    const int e = eord[p];
    const int sc = srcArr[e];
    float lg = sal[((size_t)beta * N_ + sc) * 8 + h] + dal_h + el[((size_t)b * E_ + e) * 8 + h];
    lg = lg > 0.f ? lg : 0.2f * lg;
    const float mn = fmaxf(m, lg);
    const float scale = expf(m - mn);
    const float w = expf(lg - mn);
    s = s * scale + w;
    const uint2 ux = *(const uint2*)(xw + ((size_t)beta * N_ + sc) * 256 + d0);
    const uint2 ue = *(const uint2*)(ew + ((size_t)(b * E_ + e)) * ewStride + ewOff + d0);
    acc.x = acc.x * scale + w * (bfl(ux.x) + bfl(ue.x));
    acc.y = acc.y * scale + w * (bfh(ux.x) + bfh(ue.x));
    acc.z = acc.z * scale + w * (bfl(ux.y) + bfl(ue.y));
    acc.w = acc.w * scale + w * (bfh(ux.y) + bfh(ue.y));
    m = mn;
  }
  const float inv = 1.0f / (s + 1e-16f);
  if (OUTBF) {
    uint2 o;
    o.x = f2bf2(acc.x * inv, acc.y * inv);
    o.y = f2bf2(acc.z * inv, acc.w * inv);
    *(uint2*)((unsigned short*)outp + (size_t)wid * 256 + d0) = o;
  } else {
    *(float4*)((float*)outp + (size_t)wid * 256 + d0) =
        make_float4(acc.x * inv, acc.y * inv, acc.z * inv, acc.w * inv);
  }
}

// h = LN(h + add); writes fp32 h and bf16 hb
__global__ __launch_bounds__(64) void resln_k(float* __restrict__ h,
                                              const float* __restrict__ add,
                                              const float* __restrict__ g,
                                              const float* __restrict__ bta,
                                              unsigned short* __restrict__ hb)
{
  const int row = blockIdx.x;
  const int d0 = threadIdx.x << 2;
  float* hp = h + (size_t)row * 256;
  const float4 hv = *(const float4*)(hp + d0);
  const float4 av = *(const float4*)(add + (size_t)row * 256 + d0);
  float x[4] = { hv.x + av.x, hv.y + av.y, hv.z + av.z, hv.w + av.w };
  float s = x[0] + x[1] + x[2] + x[3];
  s = wred_(s);
  const float mean = s * (1.f / 256.f);
  float vs = 0.f;
  #pragma unroll
  for (int i = 0; i < 4; ++i) { const float dd = x[i] - mean; vs += dd * dd; }
  vs = wred_(vs);
  const float inv = 1.0f / sqrtf(vs * (1.f / 256.f) + 1e-5f);
  const float4 gv = *(const float4*)(g + d0);
  const float4 bv = *(const float4*)(bta + d0);
  float o0 = (x[0] - mean) * inv * gv.x + bv.x;
  float o1 = (x[1] - mean) * inv * gv.y + bv.y;
  float o2 = (x[2] - mean) * inv * gv.z + bv.z;
  float o3 = (x[3] - mean) * inv * gv.w + bv.w;
  *(float4*)(hp + d0) = make_float4(o0, o1, o2, o3);
  uint2 ob;
  ob.x = f2bf2(o0, o1);
  ob.y = f2bf2(o2, o3);
  *(uint2*)(hb + (size_t)row * 256 + d0) = ob;
}

// ---------------------------------------------------------------------------
// Head kernels
// ---------------------------------------------------------------------------
__global__ void nh2_k(const float* __restrict__ hidden, const float* __restrict__ w2,
                      const float* __restrict__ b2, float* __restrict__ outp)
{
  const int idx = blockIdx.x * blockDim.x + threadIdx.x;
  if (idx >= B_ * N_ * 7) return;
  const int row = idx / 7, j = idx % 7;
  const float* hp = hidden + (size_t)row * 448 + j * 64;
  const float* wp = w2 + j * 64;
  float a = 0.f;
  #pragma unroll
  for (int u = 0; u < 64; ++u) a += hp[u] * wp[u];
  a += b2[j];
  if (j == 0 || j == 6) a = sigm_(a);
  else if (j == 1) a = softplus_(a);
  const int b = row / N_, n = row % N_;
  outp[(size_t)b * OUTS_ + n * 7 + j] = a;
}

// two-stage deterministic h_global mean
__global__ __launch_bounds__(256) void hglob1_k(const float* __restrict__ h,
                                                float* __restrict__ hgp)
{
  const int b = blockIdx.x;
  const int seg = blockIdx.y;
  const int d = threadIdx.x;
  float s = 0.f;
  const int n0 = seg * 120;
  for (int n = n0; n < n0 + 120; ++n)
    s += h[((size_t)(b * N_ + n)) * 256 + d];
  hgp[((size_t)(b * 25 + seg)) * 256 + d] = s;
}

__global__ __launch_bounds__(256) void hglob2_k(const float* __restrict__ hgp,
                                                float* __restrict__ hg)
{
  const int b = blockIdx.x;
  const int d = threadIdx.x;
  float s = 0.f;
  for (int i = 0; i < 25; ++i) s += hgp[((size_t)(b * 25 + i)) * 256 + d];
  hg[b * 256 + d] = s * (1.f / (float)N_);
}

__global__ __launch_bounds__(64) void freq_k(const float* __restrict__ hg,
                                             const float* __restrict__ w1, const float* __restrict__ b1,
                                             const float* __restrict__ w2, const float* __restrict__ b2,
                                             float* __restrict__ outp)
{
  const int b = blockIdx.x;
  const int u = threadIdx.x;
  float a = b1[u];
  for (int k = 0; k < 256; ++k) a += hg[b * 256 + k] * w1[k * 64 + u];
  a = fmaxf(a, 0.f) * w2[u];
  a = wred_(a);
  if (u == 0) outp[(size_t)b * OUTS_ + 45000] = a + b2[0];
}

__global__ void eh2_k(const float* __restrict__ hidden, const float* __restrict__ w2,
                      const float* __restrict__ b2, float* __restrict__ outp)
{
  const int idx = blockIdx.x * blockDim.x + threadIdx.x;
  if (idx >= 2 * B_ * E_) return;
  const int jj = idx / (B_ * E_);
  const int r = idx - jj * (B_ * E_);
  const int b = r / E_, e = r % E_;
  const float* hp = hidden + (size_t)r * 128 + jj * 64;
  const float* wp = w2 + jj * 64;
  float a = 0.f;
  #pragma unroll
  for (int u = 0; u < 64; ++u) a += hp[u] * wp[u];
  a += b2[jj];
  outp[(size_t)b * OUTS_ + 21000 + jj * 12000 + e] = a;
}

// ---------------------------------------------------------------------------
extern "C" void kernel_launch(void* const* d_in, const int* in_sizes, int n_in,
                              void* d_out, int out_size, void* d_ws, size_t ws_size,
                              hipStream_t stream)
{
  const float* env      = (const float*)d_in[0];
  const float* infra    = (const float*)d_in[1];
  const float* robot    = (const float*)d_in[2];
  const float* edgeattr = (const float*)d_in[3];
  const int*   eidx     = (const int*)d_in[4];
  const float* wqkv     = (const float*)d_in[5];
  const float* bqkv     = (const float*)d_in[6];
  const float* wo       = (const float*)d_in[7];
  const float* bo       = (const float*)d_in[8];
  const float* lnf_g    = (const float*)d_in[9];
  const float* lnf_b    = (const float*)d_in[10];
  const float* we_emb   = (const float*)d_in[11];
  const float* be_emb   = (const float*)d_in[12];
  const float* tg_W     = (const float*)d_in[13];
  const float* tg_We    = (const float*)d_in[14];
  const float* tg_asrc  = (const float*)d_in[15];
  const float* tg_adst  = (const float*)d_in[16];
  const float* tg_aedge = (const float*)d_in[17];
  const float* w_ih     = (const float*)d_in[18];
  const float* w_hh     = (const float*)d_in[19];
  const float* b_lstm   = (const float*)d_in[20];
  const float* g_W      = (const float*)d_in[21];
  const float* g_We     = (const float*)d_in[22];
  const float* g_asrc   = (const float*)d_in[23];
  const float* g_adst   = (const float*)d_in[24];
  const float* g_aedge  = (const float*)d_in[25];
  const float* g_lng    = (const float*)d_in[26];
  const float* g_lnb    = (const float*)d_in[27];
  const float* hn_w1    = (const float*)d_in[28];
  const float* hn_b1    = (const float*)d_in[29];
  const float* hn_w2    = (const float*)d_in[30];
  const float* hn_b2    = (const float*)d_in[31];
  const float* he_w1    = (const float*)d_in[32];
  const float* he_b1    = (const float*)d_in[33];
  const float* he_w2    = (const float*)d_in[34];
  const float* he_b2    = (const float*)d_in[35];

  const int* src = eidx;
  const int* dst = eidx + E_;
  float* outp = (float*)d_out;
  float* ws = (float*)d_ws;

  // ---- bf16 transposed weights at ws start (short offsets) ----
  unsigned short* wtb0 = (unsigned short*)ws;
  unsigned short* wt_qkv  = wtb0;               // 196,608
  unsigned short* wt_wo   = wtb0 + 196608;      //  65,536
  unsigned short* wt_tgW  = wtb0 + 262144;      //  65,536
  unsigned short* wt_tgWe = wtb0 + 327680;      //  65,536  (rows 0..255 of edge-cat)
  unsigned short* wt_gWe  = wtb0 + 393216;      // 196,608  (rows 256..1023, contiguous)
  unsigned short* wt_lstm = wtb0 + 589824;      // 524,288  permuted [1024][512]
  unsigned short* wt_gW   = wtb0 + 1114112;     // 196,608
  unsigned short* wt_hn   = wtb0 + 1310720;     // 114,688
  unsigned short* wt_he   = wtb0 + 1425408;     //  65,536

  // ---- dynamic regions (float-unit offsets from D0) ----
  const size_t D0 = 1600000;
  // stage A (4 chunks of 24000 nodes):
  unsigned short* qkvb  = (unsigned short*)(ws + D0);              // 27.648M f (72000x768)
  unsigned short* tmpAb = qkvb;                                    // aliases dead qkvb
  unsigned short* obarb = (unsigned short*)(ws + D0 + 27648000);   // 12.288M f
  unsigned short* fseqb = (unsigned short*)(ws + D0 + 39936000);   // 12.288M f -> 52.224M
  // stage B (qkvb/obarb dead; fseqb live until xwall GEMM):
  unsigned short* xwallb  = (unsigned short*)(ws + D0);            // 12.288M f
  unsigned short* gatallb = (unsigned short*)(ws + D0 + 12288000); // 12.288M f
  unsigned short* eembb   = (unsigned short*)(ws + D0 + 24576000); //  6.144M f
  float* h  = ws + D0 + 30720000;                                  //  3.072M
  float* c  = ws + D0 + 33792000;                                  //  3.072M
  unsigned short* hb0 = (unsigned short*)(ws + D0 + 36864000);     //  1.536M f
  unsigned short* hb1 = (unsigned short*)(ws + D0 + 38400000);     //  1.536M f -> 39.936M
  unsigned short* ewall = (unsigned short*)(ws + D0 + 62976000);   // 24.576M f
  float* elogall = ws + D0 + 87552000;         //  1.536M (4 x 384000)
  float* sal     = ws + D0 + 89088000;         //    768,000
  float* dal     = ws + D0 + 89856000;         //    768,000
  int* ideg  = (int*)(ws + D0 + 90624000);
  int* iroff = ideg + 3008;
  int* ieord = iroff + 3008;
  float* hg  = ws + D0 + 90650000;
  float* hgp = ws + D0 + 90652048;
  // GAT-layers phase (fseqb dead by then):
  unsigned short* xw_sb = (unsigned short*)(ws + D0 + 40000000);   // 1.536M f
  float* gat_s = ws + D0 + 41600000;           //  3.072M
  // heads (xwallb/gatallb dead):
  float* hidn = ws + D0;                       //  5.376M
  float* hide = ws + D0 + 17664000;            //  6.144M

  auto mgemm = [&](const unsigned short* A, const unsigned short* Wt, const float* bias,
                   void* C, int M, int N, int K, int lda, int flags) {
    dim3 grid(N / 64, (M + 127) / 128);
    gemm_bfa_k<<<grid, dim3(256), 0, stream>>>(A, Wt, bias, C, M, N, K, lda, flags);
  };
  auto cvtb = [&](const float* W, unsigned short* Wt, int K, int N, int L) {
    const int total = K * N * L;
    wtb_k<<<(total + 255) / 256, 256, 0, stream>>>(W, Wt, K, N, total);
  };

  // ---- weight convert/transpose/permute ----
  cvtb(wqkv, wt_qkv, 256, 768, 1);
  cvtb(wo, wt_wo, 256, 256, 1);
  cvtb(tg_W, wt_tgW, 256, 256, 1);
  cvtb(tg_We, wt_tgWe, 256, 256, 1);
  cvtb(g_We, wt_gWe, 256, 256, 3);
  wtp_k<<<1024, 256, 0, stream>>>(w_ih, wt_lstm, 0);
  wtp_k<<<1024, 256, 0, stream>>>(w_hh, wt_lstm, 256);
  cvtb(g_W, wt_gW, 256, 256, 3);
  cvtb(hn_w1, wt_hn, 256, 64, 7);
  cvtb(he_w1, wt_he, 512, 64, 2);

  // ---- CSR build (deterministic) ----
  hipMemsetAsync(ideg, 0, 3000 * sizeof(int), stream);
  hist_k<<<(E_ + 255) / 256, 256, 0, stream>>>(dst, ideg);
  scan_k<<<1, 256, 0, stream>>>(ideg, iroff);
  fill_k<<<750, 256, 0, stream>>>(dst, iroff, ieord);

  // ---------------- Stage A: 4 chunks of 24000 nodes ----------------
  for (int chunk = 0; chunk < 4; ++chunk) {
    dim3 grid(768 / 64, (72000 + 127) / 128);
    gemm_qkv_k<<<grid, dim3(256), 0, stream>>>(env, infra, robot, wt_qkv, bqkv,
                                               qkvb, 72000, chunk * 24000);
    attn_avg_k<<<6000, 256, 0, stream>>>(qkvb, obarb + (size_t)chunk * 24000 * 256, 24000);
  }
  // tmpAb (aliases qkvb, dead) = obar @ wo + bo (bf16), then fseq = LN(tmpAb)
  mgemm(obarb, wt_wo, bo, tmpAb, 96000, 256, 256, 256, 4);
  ln_k<<<96000, 64, 0, stream>>>(tmpAb, lnf_g, lnf_b, fseqb);

  // ---------------- Stage B prep ----------------
  {  // edge_emb = relu(edge_attr @ we_emb + be_emb) -> bf16
    dim3 grid(4, 750);
    gemm_k<<<grid, dim3(256), 0, stream>>>(edgeattr, we_emb, be_emb, eembb,
                                           48000, 256, 8, 8, 2 | 4);
  }
  // one batched edge-transform GEMM: [tgWe | gWe0 | gWe1 | gWe2], N=1024
  mgemm(eembb, wt_tgWe, nullptr, ewall, 48000, 1024, 256, 256, 4);
  elog4_k<<<6000, 256, 0, stream>>>(ewall, tg_aedge, g_aedge, elogall);

  mgemm(fseqb, wt_tgW, nullptr, xwallb, 96000, 256, 256, 256, 4);
  alphas_k<<<3000, 256, 0, stream>>>(xwallb, tg_asrc, tg_adst, sal, dal, 96000);
  gat_k<1><<<24000, 256, 0, stream>>>(xwallb, ewall, sal, dal, elogall, iroff, ieord,
                                      src, gatallb, 96000, 3, 1024, 0);

  // ---------------- LSTM over T (fused GEMM + pointwise) ----------------
  hipMemsetAsync(c, 0, 12288000, stream);
  unsigned short* hbq[2] = { hb0, hb1 };
  for (int t = 0; t < T_; ++t) {
    dim3 grid(16, 94);
    // t=0: h==0, so only the K=256 ih half contributes (exact)
    gemm_lstm_k<<<grid, dim3(256), 0, stream>>>(gatallb, hbq[t & 1], wt_lstm, b_lstm,
                                                h, c, hbq[(t + 1) & 1], t,
                                                t == 0 ? 256 : 512);
  }
  unsigned short* hbf = hbq[0];  // T=8 even -> final h in hb0

  // ---------------- 3 GAT layers with residual LN ----------------
  for (int l = 0; l < 3; ++l) {
    mgemm(hbf, wt_gW + (size_t)l * 65536, nullptr, xw_sb, 12000, 256, 256, 256, 4);
    alphas_k<<<375, 256, 0, stream>>>(xw_sb, g_asrc + l * 256, g_adst + l * 256, sal, dal, 12000);
    gat_k<0><<<3000, 256, 0, stream>>>(xw_sb, ewall, sal, dal, elogall + 384000 * (l + 1),
                                       iroff, ieord, src, gat_s, 12000, 0,
                                       1024, 256 * (l + 1));
    resln_k<<<12000, 64, 0, stream>>>(h, gat_s, g_lng + l * 256, g_lnb + l * 256, hbf);
  }

  // ---------------- Heads ----------------
  mgemm(hbf, wt_hn, hn_b1, hidn, 12000, 448, 256, 256, 2);
  nh2_k<<<(84000 + 255) / 256, 256, 0, stream>>>(hidn, hn_w2, hn_b2, outp);

  hglob1_k<<<dim3(4, 25), 256, 0, stream>>>(h, hgp);
  hglob2_k<<<4, 256, 0, stream>>>(hgp, hg);
  freq_k<<<4, 64, 0, stream>>>(hg, hn_w1 + 7 * 16384, hn_b1 + 7 * 64,
                               hn_w2 + 7 * 64, hn_b2 + 7, outp);

  // edge heads: fused gather GEMM (no ef buffer)
  {
    dim3 grid(2, 375);
    gemm_ef_k<<<grid, dim3(256), 0, stream>>>(hbf, src, dst, wt_he, he_b1, hide);
  }
  eh2_k<<<(96000 + 255) / 256, 256, 0, stream>>>(hide, he_w2, he_b2, outp);
}

// Round 14
// 1573.365 us; speedup vs baseline: 1.1255x; 1.0338x over previous
//
#include <hip/hip_runtime.h>
#include <hip/hip_bf16.h>
#include <math.h>

#define DEV __device__ __forceinline__

namespace {
constexpr int B_ = 4, T_ = 8, N_ = 3000, E_ = 12000;
constexpr int OUTS_ = 45001;  // per-batch output stride: N*7 + E + E + 1
}

using f32x4 = __attribute__((ext_vector_type(4))) float;
using bf16x8 = __attribute__((ext_vector_type(8))) short;

DEV float sigm_(float x) { return 1.0f / (1.0f + expf(-x)); }
DEV float softplus_(float x) { return fmaxf(x, 0.0f) + log1pf(expf(-fabsf(x))); }
DEV float wred_(float v) {
  #pragma unroll
  for (int o = 32; o > 0; o >>= 1) v += __shfl_xor(v, o, 64);
  return v;
}
DEV unsigned short f2bf(float x) {  // RNE fp32->bf16
  unsigned u = __float_as_uint(x);
  return (unsigned short)((u + 0x7FFFu + ((u >> 16) & 1u)) >> 16);
}
DEV unsigned f2bf2(float a, float b) {
  return (unsigned)f2bf(a) | ((unsigned)f2bf(b) << 16);
}
DEV float bfl(unsigned u) { return __uint_as_float(u << 16); }
DEV float bfh(unsigned u) { return __uint_as_float(u & 0xffff0000u); }

// ---------------------------------------------------------------------------
// Batched weight transpose+convert: L matrices [K][N] -> per-matrix [N][K] bf16
// ---------------------------------------------------------------------------
__global__ void wtb_k(const float* __restrict__ W, unsigned short* __restrict__ Wt,
                      int K, int N, int total)
{
  const int idx = blockIdx.x * blockDim.x + threadIdx.x;
  if (idx >= total) return;
  const int kn = K * N;
  const int l = idx / kn;
  const int r = idx - l * kn;
  const int k = r / N, n = r - k * N;
  Wt[(size_t)l * kn + (size_t)n * K + k] = f2bf(W[idx]);
}

// LSTM weight permute: orig col n = gate*256+d -> newcol = d*4+gate; dense [1024][512]
__global__ void wtp_k(const float* __restrict__ W, unsigned short* __restrict__ Wt,
                      int kOff)
{
  const int idx = blockIdx.x * blockDim.x + threadIdx.x;
  if (idx >= 256 * 1024) return;
  const int k = idx >> 10;
  const int n = idx & 1023;
  const int newcol = (n & 255) * 4 + (n >> 8);
  Wt[(size_t)newcol * 512 + kOff + k] = f2bf(W[idx]);
}

// ---------------------------------------------------------------------------
// CSR build (deterministic)
// ---------------------------------------------------------------------------
__global__ void hist_k(const int* __restrict__ dst, int* __restrict__ deg)
{
  const int e = blockIdx.x * blockDim.x + threadIdx.x;
  if (e < E_) atomicAdd(&deg[dst[e]], 1);
}

__global__ __launch_bounds__(256) void scan_k(const int* __restrict__ deg,
                                              int* __restrict__ roff)
{
  __shared__ int part[256];
  const int t = threadIdx.x;
  int loc[12];
  int s = 0;
  #pragma unroll
  for (int i = 0; i < 12; ++i) {
    const int n = t * 12 + i;
    loc[i] = s;
    s += (n < N_) ? deg[n] : 0;
  }
  part[t] = s;
  __syncthreads();
  if (t == 0) {
    int run = 0;
    for (int i = 0; i < 256; ++i) { const int v = part[i]; part[i] = run; run += v; }
  }
  __syncthreads();
  const int base = part[t];
  #pragma unroll
  for (int i = 0; i < 12; ++i) {
    const int n = t * 12 + i;
    if (n < N_) roff[n] = base + loc[i];
  }
  if (t == 0) roff[N_] = E_;
}

__global__ __launch_bounds__(256) void fill_k(const int* __restrict__ dst,
                                              const int* __restrict__ roff,
                                              int* __restrict__ eord)
{
  const int n = blockIdx.x * 4 + (threadIdx.x >> 6);
  if (n >= N_) return;
  const int lane = threadIdx.x & 63;
  const unsigned long long ltm = (1ull << lane) - 1ull;
  int cnt = roff[n];
  for (int c = 0; c < E_; c += 64) {
    const int e = c + lane;
    const bool m = (e < E_) && (dst[e] == n);
    const unsigned long long mask = __ballot(m);
    if (m) eord[cnt + __popcll(mask & ltm)] = e;
    cnt += __popcll(mask);
  }
}

// ---------------------------------------------------------------------------
// 128x64-tile MFMA bf16 GEMM: C[M,N] = A[M,K](bf16) @ Wt(bf16,[N][K])
// flags: 1 = C += (fp32 C), 2 = relu, 4 = store bf16 C.
// ---------------------------------------------------------------------------
__global__ __launch_bounds__(256) void gemm_bfa_k(
    const unsigned short* __restrict__ A, const unsigned short* __restrict__ Wt,
    const float* __restrict__ bias, void* __restrict__ Cv,
    int M, int N, int K, int lda, int flags)
{
  __shared__ unsigned short Al[128 * 40];
  __shared__ unsigned short Bl[64 * 40];
  const int tid = threadIdx.x;
  const int bm = blockIdx.y * 128;
  const int bn = blockIdx.x * 64;
  const int lane = tid & 63;
  const int wv = tid >> 6;
  const int wm = (wv >> 1) * 64;
  const int wn = (wv & 1) * 32;
  const int s_row = tid >> 1;
  const int s_cb = (tid & 1) * 16;
  const int grow = bm + s_row;
  const unsigned short* Arow = (grow < M) ? A + (size_t)grow * lda : nullptr;
  const int b_col = tid >> 2;
  const int b_ks = (tid & 3) * 8;
  const unsigned short* Wrow = Wt + (size_t)(bn + b_col) * K + b_ks;

  f32x4 acc[4][2] = {};
  const int l15 = lane & 15;
  const int lk = (lane >> 4) * 8;

  for (int k0 = 0; k0 < K; k0 += 32) {
    uint4 a0, a1;
    if (Arow) {
      a0 = *(const uint4*)(Arow + k0 + s_cb);
      a1 = *(const uint4*)(Arow + k0 + s_cb + 8);
    } else {
      a0 = make_uint4(0, 0, 0, 0);
      a1 = a0;
    }
    *(uint4*)&Al[s_row * 40 + s_cb] = a0;
    *(uint4*)&Al[s_row * 40 + s_cb + 8] = a1;
    *(uint4*)&Bl[b_col * 40 + b_ks] = *(const uint4*)(Wrow + k0);
    __syncthreads();
    bf16x8 af[4], bfr[2];
    #pragma unroll
    for (int m = 0; m < 4; ++m)
      af[m] = *(const bf16x8*)&Al[(wm + m * 16 + l15) * 40 + lk];
    #pragma unroll
    for (int n = 0; n < 2; ++n)
      bfr[n] = *(const bf16x8*)&Bl[(wn + n * 16 + l15) * 40 + lk];
    #pragma unroll
    for (int m = 0; m < 4; ++m)
      #pragma unroll
      for (int n = 0; n < 2; ++n)
        acc[m][n] = __builtin_amdgcn_mfma_f32_16x16x32_bf16(af[m], bfr[n], acc[m][n], 0, 0, 0);
    __syncthreads();
  }
  float* Cf = (float*)Cv;
  unsigned short* Cb = (unsigned short*)Cv;
  const int r4 = (lane >> 4) * 4;
  #pragma unroll
  for (int m = 0; m < 4; ++m) {
    #pragma unroll
    for (int n = 0; n < 2; ++n) {
      const int col = bn + wn + n * 16 + l15;
      const float bv = bias ? bias[col] : 0.f;
      #pragma unroll
      for (int r = 0; r < 4; ++r) {
        const int row = bm + wm + m * 16 + r4 + r;
        if (row >= M) continue;
        float v = acc[m][n][r] + bv;
        const size_t ci = (size_t)row * N + col;
        if (flags & 1) v += Cf[ci];
        if (flags & 2) v = fmaxf(v, 0.f);
        if (flags & 4) Cb[ci] = f2bf(v);
        else Cf[ci] = v;
      }
    }
  }
}

// ---------------------------------------------------------------------------
// Stage-A qkv GEMM, 128x128 tile (BK=32): A rows are fp32 from 3 interleaved
// sources (row r: slot=r%3, node=nodeBase+r/3), bf16-converted in staging.
// N=768 fixed -> 6 column blocks (half the A re-reads of the 64-wide tile).
// 4 waves 2x2, each 64x64 (4x4 frags). LDS 20.5 KB.
// ---------------------------------------------------------------------------
__global__ __launch_bounds__(256) void gemm_qkv_k(
    const float* __restrict__ env, const float* __restrict__ infra,
    const float* __restrict__ robot, const unsigned short* __restrict__ Wt,
    const float* __restrict__ bias, unsigned short* __restrict__ Cb,
    int M, int nodeBase)
{
  __shared__ unsigned short Al[128 * 40];
  __shared__ unsigned short Bl[128 * 40];
  const int tid = threadIdx.x;
  const int bm = blockIdx.y * 128;
  const int bn = blockIdx.x * 128;
  const int lane = tid & 63;
  const int wv = tid >> 6;
  const int wm = (wv >> 1) * 64;
  const int wn = (wv & 1) * 64;
  const int s_row = tid >> 1;
  const int s_cb = (tid & 1) * 16;
  const int grow = bm + s_row;
  const float* Arow = nullptr;
  if (grow < M) {
    const int slot = grow % 3;
    const int node = nodeBase + grow / 3;
    const float* srcp = (slot == 0 ? env : (slot == 1 ? infra : robot));
    Arow = srcp + (size_t)node * 256;
  }

  f32x4 acc[4][4] = {};
  const int l15 = lane & 15;
  const int lk = (lane >> 4) * 8;

  for (int k0 = 0; k0 < 256; k0 += 32) {
    unsigned abuf[8];
    if (Arow) {
      const float* p = Arow + k0 + s_cb;
      #pragma unroll
      for (int i = 0; i < 4; ++i) {
        const float4 v = *(const float4*)(p + i * 4);
        abuf[i * 2 + 0] = f2bf2(v.x, v.y);
        abuf[i * 2 + 1] = f2bf2(v.z, v.w);
      }
    } else {
      #pragma unroll
      for (int i = 0; i < 8; ++i) abuf[i] = 0;
    }
    *(uint4*)&Al[s_row * 40 + s_cb] = *(uint4*)&abuf[0];
    *(uint4*)&Al[s_row * 40 + s_cb + 8] = *(uint4*)&abuf[4];
    #pragma unroll
    for (int i = 0; i < 2; ++i) {
      const int task = tid + i * 256;     // 0..511
      const int col = task >> 2;
      const int ks = (task & 3) * 8;
      *(uint4*)&Bl[col * 40 + ks] = *(const uint4*)(Wt + (size_t)(bn + col) * 256 + k0 + ks);
    }
    __syncthreads();
    bf16x8 af[4], bfr[4];
    #pragma unroll
    for (int m = 0; m < 4; ++m)
      af[m] = *(const bf16x8*)&Al[(wm + m * 16 + l15) * 40 + lk];
    #pragma unroll
    for (int n = 0; n < 4; ++n)
      bfr[n] = *(const bf16x8*)&Bl[(wn + n * 16 + l15) * 40 + lk];
    #pragma unroll
    for (int m = 0; m < 4; ++m)
      #pragma unroll
      for (int n = 0; n < 4; ++n)
        acc[m][n] = __builtin_amdgcn_mfma_f32_16x16x32_bf16(af[m], bfr[n], acc[m][n], 0, 0, 0);
    __syncthreads();
  }
  const int r4 = (lane >> 4) * 4;
  #pragma unroll
  for (int m = 0; m < 4; ++m) {
    #pragma unroll
    for (int n = 0; n < 4; ++n) {
      const int col = bn + wn + n * 16 + l15;
      const float bv = bias[col];
      #pragma unroll
      for (int r = 0; r < 4; ++r) {
        const int row = bm + wm + m * 16 + r4 + r;
        if (row >= M) continue;
        Cb[(size_t)row * 768 + col] = f2bf(acc[m][n][r] + bv);
      }
    }
  }
}

// ---------------------------------------------------------------------------
// Fused LSTM step: gates = [gat_t | h] @ Wt_perm (kEnd=512; kEnd=256 at t=0
// since h==0), newcol = d*4+gate; LSTM pointwise in epilogue via LDS transpose.
// Writes c, h (fp32), hbOut. hbIn/hbOut MUST differ (cross-block race).
// ---------------------------------------------------------------------------
__global__ __launch_bounds__(256) void gemm_lstm_k(
    const unsigned short* __restrict__ gatall, const unsigned short* __restrict__ hbIn,
    const unsigned short* __restrict__ Wt, const float* __restrict__ b_lstm,
    float* __restrict__ h, float* __restrict__ c, unsigned short* __restrict__ hbOut,
    int t, int kEnd)
{
  __shared__ float Gl[128][65];
  unsigned short* Al = (unsigned short*)&Gl[0][0];
  unsigned short* Bl = Al + 128 * 40;
  const int tid = threadIdx.x;
  const int bm = blockIdx.y * 128;
  const int bn = blockIdx.x * 64;
  const int lane = tid & 63;
  const int wv = tid >> 6;
  const int wm = (wv >> 1) * 64;
  const int wn = (wv & 1) * 32;
  const int s_row = tid >> 1;
  const int s_cb = (tid & 1) * 16;
  const int grow = bm + s_row;
  const unsigned short* Arow1 = nullptr;
  const unsigned short* Arow2 = nullptr;
  if (grow < 12000) {
    const int phys = (grow / N_) * (T_ * N_) + t * N_ + (grow % N_);
    Arow1 = gatall + (size_t)phys * 256;
    Arow2 = hbIn + (size_t)grow * 256;
  }
  const int b_col = tid >> 2;
  const int b_ks = (tid & 3) * 8;
  const unsigned short* Wrow = Wt + (size_t)(bn + b_col) * 512 + b_ks;

  f32x4 acc[4][2] = {};
  const int l15 = lane & 15;
  const int lk = (lane >> 4) * 8;

  for (int k0 = 0; k0 < kEnd; k0 += 32) {
    uint4 a0, a1;
    if (Arow1) {
      const unsigned short* p = (k0 < 256) ? (Arow1 + k0 + s_cb)
                                           : (Arow2 + (k0 - 256) + s_cb);
      a0 = *(const uint4*)p;
      a1 = *(const uint4*)(p + 8);
    } else {
      a0 = make_uint4(0, 0, 0, 0);
      a1 = a0;
    }
    *(uint4*)&Al[s_row * 40 + s_cb] = a0;
    *(uint4*)&Al[s_row * 40 + s_cb + 8] = a1;
    *(uint4*)&Bl[b_col * 40 + b_ks] = *(const uint4*)(Wrow + k0);
    __syncthreads();
    bf16x8 af[4], bfr[2];
    #pragma unroll
    for (int m = 0; m < 4; ++m)
      af[m] = *(const bf16x8*)&Al[(wm + m * 16 + l15) * 40 + lk];
    #pragma unroll
    for (int n = 0; n < 2; ++n)
      bfr[n] = *(const bf16x8*)&Bl[(wn + n * 16 + l15) * 40 + lk];
    #pragma unroll
    for (int m = 0; m < 4; ++m)
      #pragma unroll
      for (int n = 0; n < 2; ++n)
        acc[m][n] = __builtin_amdgcn_mfma_f32_16x16x32_bf16(af[m], bfr[n], acc[m][n], 0, 0, 0);
    __syncthreads();
  }
  const int r4 = (lane >> 4) * 4;
  #pragma unroll
  for (int m = 0; m < 4; ++m)
    #pragma unroll
    for (int n = 0; n < 2; ++n) {
      const int col = wn + n * 16 + l15;
      #pragma unroll
      for (int r = 0; r < 4; ++r)
        Gl[wm + m * 16 + r4 + r][col] = acc[m][n][r];
    }
  __syncthreads();
  const int fl = lane & 7;
  const int rg = lane >> 3;
  const int dg = ((bn + wn) >> 2) + fl;
  const float bi = b_lstm[dg];
  const float bff = b_lstm[256 + dg];
  const float bg = b_lstm[512 + dg];
  const float bo = b_lstm[768 + dg];
  const int colb = wn + fl * 4;
  #pragma unroll
  for (int i = 0; i < 8; ++i) {
    const int rl = rg + i * 8;
    const int row = bm + wm + rl;
    if (row >= 12000) continue;
    const float g0 = Gl[wm + rl][colb + 0] + bi;
    const float g1 = Gl[wm + rl][colb + 1] + bff;
    const float g2 = Gl[wm + rl][colb + 2] + bg;
    const float g3 = Gl[wm + rl][colb + 3] + bo;
    const size_t idx = (size_t)row * 256 + dg;
    const float cn = sigm_(g1) * c[idx] + sigm_(g0) * tanhf(g2);
    c[idx] = cn;
    const float hn = sigm_(g3) * tanhf(cn);
    h[idx] = hn;
    hbOut[idx] = f2bf(hn);
  }
}

// ---------------------------------------------------------------------------
// Edge-head GEMM with fused ef gather: A row r (of 48000) = concat(
// hb[b,src[e]], hb[b,dst[e]]), b=r/E, e=r%E. K=512, N=128, relu, fp32 out.
// ---------------------------------------------------------------------------
__global__ __launch_bounds__(256) void gemm_ef_k(
    const unsigned short* __restrict__ hb, const int* __restrict__ srcA,
    const int* __restrict__ dstA, const unsigned short* __restrict__ Wt,
    const float* __restrict__ bias, float* __restrict__ Cf)
{
  __shared__ unsigned short Al[128 * 40];
  __shared__ unsigned short Bl[64 * 40];
  const int tid = threadIdx.x;
  const int bm = blockIdx.y * 128;
  const int bn = blockIdx.x * 64;
  const int lane = tid & 63;
  const int wv = tid >> 6;
  const int wm = (wv >> 1) * 64;
  const int wn = (wv & 1) * 32;
  const int s_row = tid >> 1;
  const int s_cb = (tid & 1) * 16;
  const int grow = bm + s_row;
  const unsigned short* Arow1 = nullptr;
  const unsigned short* Arow2 = nullptr;
  if (grow < 48000) {
    const int b = grow / E_;
    const int e = grow - b * E_;
    Arow1 = hb + ((size_t)(b * N_ + srcA[e])) * 256;
    Arow2 = hb + ((size_t)(b * N_ + dstA[e])) * 256;
  }
  const int b_col = tid >> 2;
  const int b_ks = (tid & 3) * 8;
  const unsigned short* Wrow = Wt + (size_t)(bn + b_col) * 512 + b_ks;

  f32x4 acc[4][2] = {};
  const int l15 = lane & 15;
  const int lk = (lane >> 4) * 8;

  for (int k0 = 0; k0 < 512; k0 += 32) {
    uint4 a0, a1;
    if (Arow1) {
      const unsigned short* p = (k0 < 256) ? (Arow1 + k0 + s_cb)
                                           : (Arow2 + (k0 - 256) + s_cb);
      a0 = *(const uint4*)p;
      a1 = *(const uint4*)(p + 8);
    } else {
      a0 = make_uint4(0, 0, 0, 0);
      a1 = a0;
    }
    *(uint4*)&Al[s_row * 40 + s_cb] = a0;
    *(uint4*)&Al[s_row * 40 + s_cb + 8] = a1;
    *(uint4*)&Bl[b_col * 40 + b_ks] = *(const uint4*)(Wrow + k0);
    __syncthreads();
    bf16x8 af[4], bfr[2];
    #pragma unroll
    for (int m = 0; m < 4; ++m)
      af[m] = *(const bf16x8*)&Al[(wm + m * 16 + l15) * 40 + lk];
    #pragma unroll
    for (int n = 0; n < 2; ++n)
      bfr[n] = *(const bf16x8*)&Bl[(wn + n * 16 + l15) * 40 + lk];
    #pragma unroll
    for (int m = 0; m < 4; ++m)
      #pragma unroll
      for (int n = 0; n < 2; ++n)
        acc[m][n] = __builtin_amdgcn_mfma_f32_16x16x32_bf16(af[m], bfr[n], acc[m][n], 0, 0, 0);
    __syncthreads();
  }
  const int r4 = (lane >> 4) * 4;
  #pragma unroll
  for (int m = 0; m < 4; ++m) {
    #pragma unroll
    for (int n = 0; n < 2; ++n) {
      const int col = bn + wn + n * 16 + l15;
      const float bv = bias[col];
      #pragma unroll
      for (int r = 0; r < 4; ++r) {
        const int row = bm + wm + m * 16 + r4 + r;
        if (row >= 48000) continue;
        Cf[(size_t)row * 128 + col] = fmaxf(acc[m][n][r] + bv, 0.f);
      }
    }
  }
}

// ---------------------------------------------------------------------------
// fp32 fallback GEMM (only the K=8 edge-emb GEMM); flags&4 -> bf16 C store
// ---------------------------------------------------------------------------
__global__ __launch_bounds__(256) void gemm_k(
    const float* __restrict__ A, const float* __restrict__ W,
    const float* __restrict__ bias, void* __restrict__ Cv,
    int M, int N, int K, int lda, int flags)
{
  __shared__ float As[16][68];
  __shared__ float Ws[16][64];
  const int tid = threadIdx.x;
  const int bm = blockIdx.y * 64;
  const int bn = blockIdx.x * 64;
  const int tx = tid & 15;
  const int ty = tid >> 4;
  const int ar = tid >> 2;
  const int ac = (tid & 3) << 2;
  const int wr = tid >> 4;
  const int wc = (tid & 15) << 2;
  const int grow = bm + ar;
  const float* Arow = (grow < M) ? A + (size_t)grow * lda : nullptr;
  float acc[4][4] = {};
  for (int k0 = 0; k0 < K; k0 += 16) {
    float4 av = make_float4(0.f, 0.f, 0.f, 0.f);
    if (Arow) {
      av.x = (k0 + ac + 0 < K) ? Arow[k0 + ac + 0] : 0.f;
      av.y = (k0 + ac + 1 < K) ? Arow[k0 + ac + 1] : 0.f;
      av.z = (k0 + ac + 2 < K) ? Arow[k0 + ac + 2] : 0.f;
      av.w = (k0 + ac + 3 < K) ? Arow[k0 + ac + 3] : 0.f;
    }
    As[ac + 0][ar] = av.x;
    As[ac + 1][ar] = av.y;
    As[ac + 2][ar] = av.z;
    As[ac + 3][ar] = av.w;
    float4 wv = make_float4(0.f, 0.f, 0.f, 0.f);
    if (k0 + wr < K) {
      const int gc = bn + wc;
      const float* wp = W + (size_t)(k0 + wr) * N + gc;
      wv.x = (gc + 0 < N) ? wp[0] : 0.f;
      wv.y = (gc + 1 < N) ? wp[1] : 0.f;
      wv.z = (gc + 2 < N) ? wp[2] : 0.f;
      wv.w = (gc + 3 < N) ? wp[3] : 0.f;
    }
    *(float4*)&Ws[wr][wc] = wv;
    __syncthreads();
    #pragma unroll
    for (int kk = 0; kk < 16; ++kk) {
      const float4 a = *(const float4*)&As[kk][ty << 2];
      const float4 b = *(const float4*)&Ws[kk][tx << 2];
      acc[0][0] += a.x * b.x; acc[0][1] += a.x * b.y; acc[0][2] += a.x * b.z; acc[0][3] += a.x * b.w;
      acc[1][0] += a.y * b.x; acc[1][1] += a.y * b.y; acc[1][2] += a.y * b.z; acc[1][3] += a.y * b.w;
      acc[2][0] += a.z * b.x; acc[2][1] += a.z * b.y; acc[2][2] += a.z * b.z; acc[2][3] += a.z * b.w;
      acc[3][0] += a.w * b.x; acc[3][1] += a.w * b.y; acc[3][2] += a.w * b.z; acc[3][3] += a.w * b.w;
    }
    __syncthreads();
  }
  float* Cf = (float*)Cv;
  unsigned short* Cb = (unsigned short*)Cv;
  #pragma unroll
  for (int i = 0; i < 4; ++i) {
    const int row = bm + (ty << 2) + i;
    if (row >= M) continue;
    #pragma unroll
    for (int j = 0; j < 4; ++j) {
      const int col = bn + (tx << 2) + j;
      if (col >= N) continue;
      float v = acc[i][j];
      if (bias) v += bias[col];
      if (flags & 2) v = fmaxf(v, 0.f);
      const size_t ci = (size_t)row * N + col;
      if (flags & 4) Cb[ci] = f2bf(v);
      else Cf[ci] = v;
    }
  }
}

// ---------------------------------------------------------------------------
// Stage A attention: ONE WAVE PER NODE (coalesced). Lane l -> head l>>3,
// elems (l&7)*4; qkv offset = node*2304 + 4*l. 9 dots reduce over the 8-lane
// subgroup via shfl_xor(1,2,4). 4 waves/block.
// ---------------------------------------------------------------------------
__global__ __launch_bounds__(256) void attn_avg_k(
    const unsigned short* __restrict__ qkv,
    unsigned short* __restrict__ obar, int nodes)
{
  const int node = blockIdx.x * 4 + (threadIdx.x >> 6);
  if (node >= nodes) return;
  const int lane = threadIdx.x & 63;
  const unsigned short* base = qkv + (size_t)node * 2304 + lane * 4;
  float qv[3][4], kv[3][4], vv[3][4];
  #pragma unroll
  for (int s = 0; s < 3; ++s) {
    const uint2 uq = *(const uint2*)(base + s * 768);
    const uint2 uk = *(const uint2*)(base + s * 768 + 256);
    const uint2 uv = *(const uint2*)(base + s * 768 + 512);
    qv[s][0] = bfl(uq.x); qv[s][1] = bfh(uq.x); qv[s][2] = bfl(uq.y); qv[s][3] = bfh(uq.y);
    kv[s][0] = bfl(uk.x); kv[s][1] = bfh(uk.x); kv[s][2] = bfl(uk.y); kv[s][3] = bfh(uk.y);
    vv[s][0] = bfl(uv.x); vv[s][1] = bfh(uv.x); vv[s][2] = bfl(uv.y); vv[s][3] = bfh(uv.y);
  }
  float att[3][3];
  #pragma unroll
  for (int s = 0; s < 3; ++s) {
    #pragma unroll
    for (int t = 0; t < 3; ++t) {
      float d = qv[s][0] * kv[t][0] + qv[s][1] * kv[t][1]
              + qv[s][2] * kv[t][2] + qv[s][3] * kv[t][3];
      d += __shfl_xor(d, 1, 64);
      d += __shfl_xor(d, 2, 64);
      d += __shfl_xor(d, 4, 64);
      att[s][t] = d * 0.17677669529663687f;
    }
  }
  float cs[3] = {0.f, 0.f, 0.f};
  #pragma unroll
  for (int s = 0; s < 3; ++s) {
    const float m = fmaxf(att[s][0], fmaxf(att[s][1], att[s][2]));
    const float e0 = expf(att[s][0] - m);
    const float e1 = expf(att[s][1] - m);
    const float e2 = expf(att[s][2] - m);
    const float inv = (1.f / 3.f) / (e0 + e1 + e2);
    cs[0] += e0 * inv; cs[1] += e1 * inv; cs[2] += e2 * inv;
  }
  float o0 = cs[0] * vv[0][0] + cs[1] * vv[1][0] + cs[2] * vv[2][0];
  float o1 = cs[0] * vv[0][1] + cs[1] * vv[1][1] + cs[2] * vv[2][1];
  float o2 = cs[0] * vv[0][2] + cs[1] * vv[1][2] + cs[2] * vv[2][2];
  float o3 = cs[0] * vv[0][3] + cs[1] * vv[1][3] + cs[2] * vv[2][3];
  uint2 ob;
  ob.x = f2bf2(o0, o1);
  ob.y = f2bf2(o2, o3);
  *(uint2*)(obar + (size_t)node * 256 + lane * 4) = ob;
}

// LayerNorm per row; bf16 in, bf16 out. 1 wave per row.
__global__ __launch_bounds__(64) void ln_k(
    const unsigned short* __restrict__ in, const float* __restrict__ g,
    const float* __restrict__ bta, unsigned short* __restrict__ outp)
{
  const int row = blockIdx.x;
  const int d0 = threadIdx.x << 2;
  const uint2 a = *(const uint2*)(in + (size_t)row * 256 + d0);
  float x[4] = { bfl(a.x), bfh(a.x), bfl(a.y), bfh(a.y) };
  float s = x[0] + x[1] + x[2] + x[3];
  s = wred_(s);
  const float mean = s * (1.f / 256.f);
  float vs = 0.f;
  #pragma unroll
  for (int i = 0; i < 4; ++i) { const float dd = x[i] - mean; vs += dd * dd; }
  vs = wred_(vs);
  const float inv = 1.0f / sqrtf(vs * (1.f / 256.f) + 1e-5f);
  const float4 gv = *(const float4*)(g + d0);
  const float4 bv = *(const float4*)(bta + d0);
  uint2 o;
  o.x = f2bf2((x[0] - mean) * inv * gv.x + bv.x, (x[1] - mean) * inv * gv.y + bv.y);
  o.y = f2bf2((x[2] - mean) * inv * gv.z + bv.z, (x[3] - mean) * inv * gv.w + bv.w);
  *(uint2*)(outp + (size_t)row * 256 + d0) = o;
}

// ---------------------------------------------------------------------------
// GAT kernels (bf16 feature inputs)
// ---------------------------------------------------------------------------
__global__ void alphas_k(const unsigned short* __restrict__ xw, const float* __restrict__ as,
                         const float* __restrict__ ad, float* __restrict__ sal,
                         float* __restrict__ dal, int rows)
{
  const int idx = blockIdx.x * blockDim.x + threadIdx.x;
  if (idx >= rows * 8) return;
  const int row = idx >> 3, h = idx & 7;
  const unsigned short* x = xw + (size_t)row * 256 + h * 32;
  const float* a1 = as + h * 32;
  const float* a2 = ad + h * 32;
  float s = 0.f, d = 0.f;
  #pragma unroll
  for (int i = 0; i < 4; ++i) {
    const uint4 ux = *(const uint4*)(x + i * 8);
    const unsigned* p = &ux.x;
    #pragma unroll
    for (int j = 0; j < 4; ++j) {
      const float lo = bfl(p[j]), hi = bfh(p[j]);
      s += lo * a1[i * 8 + 2 * j] + hi * a1[i * 8 + 2 * j + 1];
      d += lo * a2[i * 8 + 2 * j] + hi * a2[i * 8 + 2 * j + 1];
    }
  }
  sal[idx] = s; dal[idx] = d;
}

// all 4 edge-logit sets in one launch; ew is [48000][1024] (4 x 256 packed)
__global__ void elog4_k(const unsigned short* __restrict__ ew,
                        const float* __restrict__ tg_ae, const float* __restrict__ g_ae,
                        float* __restrict__ el)
{
  const int idx = blockIdx.x * blockDim.x + threadIdx.x;
  if (idx >= 4 * 48000 * 8) return;
  const int l = idx / (48000 * 8);
  const int r = idx - l * (48000 * 8);
  const int row = r >> 3, h = r & 7;
  const unsigned short* x = ew + (size_t)row * 1024 + l * 256 + h * 32;
  const float* a1 = (l == 0 ? tg_ae : g_ae + (l - 1) * 256) + h * 32;
  float s = 0.f;
  #pragma unroll
  for (int i = 0; i < 4; ++i) {
    const uint4 ux = *(const uint4*)(x + i * 8);
    const unsigned* p = &ux.x;
    #pragma unroll
    for (int j = 0; j < 4; ++j) {
      s += bfl(p[j]) * a1[i * 8 + 2 * j] + bfh(p[j]) * a1[i * 8 + 2 * j + 1];
    }
  }
  el[l * 384000 + r] = s;
}

// Fused GAT aggregation: one wave per (beta,node). Online softmax over incoming
// edges (CSR). bf16 gathers. OUTBF: 1 -> bf16 out, 0 -> fp32 out.
template<int OUTBF>
__global__ __launch_bounds__(256) void gat_k(
    const unsigned short* __restrict__ xw, const unsigned short* __restrict__ ew,
    const float* __restrict__ sal, const float* __restrict__ dal,
    const float* __restrict__ el, const int* __restrict__ roff,
    const int* __restrict__ eord, const int* __restrict__ srcArr,
    void* __restrict__ outp, int nwaves, int tshift, int ewStride, int ewOff)
{
  const int wid = blockIdx.x * 4 + (threadIdx.x >> 6);
  if (wid >= nwaves) return;
  const int beta = wid / N_;
  const int n = wid - beta * N_;
  const int b = beta >> tshift;
  const int lane = threadIdx.x & 63;
  const int h = lane >> 3;
  const int d0 = lane << 2;
  const float dal_h = dal[(size_t)wid * 8 + h];
  const int p0 = roff[n], p1 = roff[n + 1];
  float m = -1e30f, s = 0.f;
  float4 acc = make_float4(0.f, 0.f, 0.f, 0.f);
  for (int p = p0; p < p1; ++p) {
    const int e = eord[p];
    const int sc = srcArr[e];
    float lg = sal[((size_t)beta * N_ + sc) * 8 + h] + dal_h + el[((size_t)b * E_ + e) * 8 + h];
    lg = lg > 0.f ? lg : 0.2f * lg;
    const float mn = fmaxf(m, lg);
    const float scale = expf(m - mn);
    const float w = expf(lg - mn);
    s = s * scale + w;
    const uint2 ux = *(const uint2*)(xw + ((size_t)beta * N_ + sc) * 256 + d0);
    const uint2 ue = *(const uint2*)(ew + ((size_t)(b * E_ + e)) * ewStride + ewOff + d0);
    acc.x = acc.x * scale + w * (bfl(ux.x) + bfl(ue.x));
    acc.y = acc.y * scale + w * (bfh(ux.x) + bfh(ue.x));
    acc.z = acc.z * scale + w * (bfl(ux.y) + bfl(ue.y));
    acc.w = acc.w * scale + w * (bfh(ux.y) + bfh(ue.y));
    m = mn;
  }
  const float inv = 1.0f / (s + 1e-16f);
  if (OUTBF) {
    uint2 o;
    o.x = f2bf2(acc.x * inv, acc.y * inv);
    o.y = f2bf2(acc.z * inv, acc.w * inv);
    *(uint2*)((unsigned short*)outp + (size_t)wid * 256 + d0) = o;
  } else {
    *(float4*)((float*)outp + (size_t)wid * 256 + d0) =
        make_float4(acc.x * inv, acc.y * inv, acc.z * inv, acc.w * inv);
  }
}

// h = LN(h + add); writes fp32 h and bf16 hb
__global__ __launch_bounds__(64) void resln_k(float* __restrict__ h,
                                              const float* __restrict__ add,
                                              const float* __restrict__ g,
                                              const float* __restrict__ bta,
                                              unsigned short* __restrict__ hb)
{
  const int row = blockIdx.x;
  const int d0 = threadIdx.x << 2;
  float* hp = h + (size_t)row * 256;
  const float4 hv = *(const float4*)(hp + d0);
  const float4 av = *(const float4*)(add + (size_t)row * 256 + d0);
  float x[4] = { hv.x + av.x, hv.y + av.y, hv.z + av.z, hv.w + av.w };
  float s = x[0] + x[1] + x[2] + x[3];
  s = wred_(s);
  const float mean = s * (1.f / 256.f);
  float vs = 0.f;
  #pragma unroll
  for (int i = 0; i < 4; ++i) { const float dd = x[i] - mean; vs += dd * dd; }
  vs = wred_(vs);
  const float inv = 1.0f / sqrtf(vs * (1.f / 256.f) + 1e-5f);
  const float4 gv = *(const float4*)(g + d0);
  const float4 bv = *(const float4*)(bta + d0);
  float o0 = (x[0] - mean) * inv * gv.x + bv.x;
  float o1 = (x[1] - mean) * inv * gv.y + bv.y;
  float o2 = (x[2] - mean) * inv * gv.z + bv.z;
  float o3 = (x[3] - mean) * inv * gv.w + bv.w;
  *(float4*)(hp + d0) = make_float4(o0, o1, o2, o3);
  uint2 ob;
  ob.x = f2bf2(o0, o1);
  ob.y = f2bf2(o2, o3);
  *(uint2*)(hb + (size_t)row * 256 + d0) = ob;
}

// ---------------------------------------------------------------------------
// Head kernels
// ---------------------------------------------------------------------------
__global__ void nh2_k(const float* __restrict__ hidden, const float* __restrict__ w2,
                      const float* __restrict__ b2, float* __restrict__ outp)
{
  const int idx = blockIdx.x * blockDim.x + threadIdx.x;
  if (idx >= B_ * N_ * 7) return;
  const int row = idx / 7, j = idx % 7;
  const float* hp = hidden + (size_t)row * 448 + j * 64;
  const float* wp = w2 + j * 64;
  float a = 0.f;
  #pragma unroll
  for (int u = 0; u < 64; ++u) a += hp[u] * wp[u];
  a += b2[j];
  if (j == 0 || j == 6) a = sigm_(a);
  else if (j == 1) a = softplus_(a);
  const int b = row / N_, n = row % N_;
  outp[(size_t)b * OUTS_ + n * 7 + j] = a;
}

// two-stage deterministic h_global mean
__global__ __launch_bounds__(256) void hglob1_k(const float* __restrict__ h,
                                                float* __restrict__ hgp)
{
  const int b = blockIdx.x;
  const int seg = blockIdx.y;
  const int d = threadIdx.x;
  float s = 0.f;
  const int n0 = seg * 120;
  for (int n = n0; n < n0 + 120; ++n)
    s += h[((size_t)(b * N_ + n)) * 256 + d];
  hgp[((size_t)(b * 25 + seg)) * 256 + d] = s;
}

__global__ __launch_bounds__(256) void hglob2_k(const float* __restrict__ hgp,
                                                float* __restrict__ hg)
{
  const int b = blockIdx.x;
  const int d = threadIdx.x;
  float s = 0.f;
  for (int i = 0; i < 25; ++i) s += hgp[((size_t)(b * 25 + i)) * 256 + d];
  hg[b * 256 + d] = s * (1.f / (float)N_);
}

__global__ __launch_bounds__(64) void freq_k(const float* __restrict__ hg,
                                             const float* __restrict__ w1, const float* __restrict__ b1,
                                             const float* __restrict__ w2, const float* __restrict__ b2,
                                             float* __restrict__ outp)
{
  const int b = blockIdx.x;
  const int u = threadIdx.x;
  float a = b1[u];
  for (int k = 0; k < 256; ++k) a += hg[b * 256 + k] * w1[k * 64 + u];
  a = fmaxf(a, 0.f) * w2[u];
  a = wred_(a);
  if (u == 0) outp[(size_t)b * OUTS_ + 45000] = a + b2[0];
}

__global__ void eh2_k(const float* __restrict__ hidden, const float* __restrict__ w2,
                      const float* __restrict__ b2, float* __restrict__ outp)
{
  const int idx = blockIdx.x * blockDim.x + threadIdx.x;
  if (idx >= 2 * B_ * E_) return;
  const int jj = idx / (B_ * E_);
  const int r = idx - jj * (B_ * E_);
  const int b = r / E_, e = r % E_;
  const float* hp = hidden + (size_t)r * 128 + jj * 64;
  const float* wp = w2 + jj * 64;
  float a = 0.f;
  #pragma unroll
  for (int u = 0; u < 64; ++u) a += hp[u] * wp[u];
  a += b2[jj];
  outp[(size_t)b * OUTS_ + 21000 + jj * 12000 + e] = a;
}

// ---------------------------------------------------------------------------
extern "C" void kernel_launch(void* const* d_in, const int* in_sizes, int n_in,
                              void* d_out, int out_size, void* d_ws, size_t ws_size,
                              hipStream_t stream)
{
  const float* env      = (const float*)d_in[0];
  const float* infra    = (const float*)d_in[1];
  const float* robot    = (const float*)d_in[2];
  const float* edgeattr = (const float*)d_in[3];
  const int*   eidx     = (const int*)d_in[4];
  const float* wqkv     = (const float*)d_in[5];
  const float* bqkv     = (const float*)d_in[6];
  const float* wo       = (const float*)d_in[7];
  const float* bo       = (const float*)d_in[8];
  const float* lnf_g    = (const float*)d_in[9];
  const float* lnf_b    = (const float*)d_in[10];
  const float* we_emb   = (const float*)d_in[11];
  const float* be_emb   = (const float*)d_in[12];
  const float* tg_W     = (const float*)d_in[13];
  const float* tg_We    = (const float*)d_in[14];
  const float* tg_asrc  = (const float*)d_in[15];
  const float* tg_adst  = (const float*)d_in[16];
  const float* tg_aedge = (const float*)d_in[17];
  const float* w_ih     = (const float*)d_in[18];
  const float* w_hh     = (const float*)d_in[19];
  const float* b_lstm   = (const float*)d_in[20];
  const float* g_W      = (const float*)d_in[21];
  const float* g_We     = (const float*)d_in[22];
  const float* g_asrc   = (const float*)d_in[23];
  const float* g_adst   = (const float*)d_in[24];
  const float* g_aedge  = (const float*)d_in[25];
  const float* g_lng    = (const float*)d_in[26];
  const float* g_lnb    = (const float*)d_in[27];
  const float* hn_w1    = (const float*)d_in[28];
  const float* hn_b1    = (const float*)d_in[29];
  const float* hn_w2    = (const float*)d_in[30];
  const float* hn_b2    = (const float*)d_in[31];
  const float* he_w1    = (const float*)d_in[32];
  const float* he_b1    = (const float*)d_in[33];
  const float* he_w2    = (const float*)d_in[34];
  const float* he_b2    = (const float*)d_in[35];

  const int* src = eidx;
  const int* dst = eidx + E_;
  float* outp = (float*)d_out;
  float* ws = (float*)d_ws;

  // ---- bf16 transposed weights at ws start (short offsets) ----
  unsigned short* wtb0 = (unsigned short*)ws;
  unsigned short* wt_qkv  = wtb0;               // 196,608
  unsigned short* wt_wo   = wtb0 + 196608;      //  65,536
  unsigned short* wt_tgW  = wtb0 + 262144;      //  65,536
  unsigned short* wt_tgWe = wtb0 + 327680;      //  65,536  (rows 0..255 of edge-cat)
  unsigned short* wt_gWe  = wtb0 + 393216;      // 196,608  (rows 256..1023, contiguous)
  unsigned short* wt_lstm = wtb0 + 589824;      // 524,288  permuted [1024][512]
  unsigned short* wt_gW   = wtb0 + 1114112;     // 196,608
  unsigned short* wt_hn   = wtb0 + 1310720;     // 114,688
  unsigned short* wt_he   = wtb0 + 1425408;     //  65,536

  // ---- dynamic regions (float-unit offsets from D0) ----
  const size_t D0 = 1600000;
  // stage A (4 chunks of 24000 nodes):
  unsigned short* qkvb  = (unsigned short*)(ws + D0);              // 27.648M f (72000x768)
  unsigned short* tmpAb = qkvb;                                    // aliases dead qkvb
  unsigned short* obarb = (unsigned short*)(ws + D0 + 27648000);   // 12.288M f
  unsigned short* fseqb = (unsigned short*)(ws + D0 + 39936000);   // 12.288M f -> 52.224M
  // stage B (qkvb/obarb dead; fseqb live until xwall GEMM):
  unsigned short* xwallb  = (unsigned short*)(ws + D0);            // 12.288M f
  unsigned short* gatallb = (unsigned short*)(ws + D0 + 12288000); // 12.288M f
  unsigned short* eembb   = (unsigned short*)(ws + D0 + 24576000); //  6.144M f
  float* h  = ws + D0 + 30720000;                                  //  3.072M
  float* c  = ws + D0 + 33792000;                                  //  3.072M
  unsigned short* hb0 = (unsigned short*)(ws + D0 + 36864000);     //  1.536M f
  unsigned short* hb1 = (unsigned short*)(ws + D0 + 38400000);     //  1.536M f -> 39.936M
  unsigned short* ewall = (unsigned short*)(ws + D0 + 62976000);   // 24.576M f
  float* elogall = ws + D0 + 87552000;         //  1.536M (4 x 384000)
  float* sal     = ws + D0 + 89088000;         //    768,000
  float* dal     = ws + D0 + 89856000;         //    768,000
  int* ideg  = (int*)(ws + D0 + 90624000);
  int* iroff = ideg + 3008;
  int* ieord = iroff + 3008;
  float* hg  = ws + D0 + 90650000;
  float* hgp = ws + D0 + 90652048;
  // GAT-layers phase (fseqb dead by then):
  unsigned short* xw_sb = (unsigned short*)(ws + D0 + 40000000);   // 1.536M f
  float* gat_s = ws + D0 + 41600000;           //  3.072M
  // heads (xwallb/gatallb dead):
  float* hidn = ws + D0;                       //  5.376M
  float* hide = ws + D0 + 17664000;            //  6.144M

  auto mgemm = [&](const unsigned short* A, const unsigned short* Wt, const float* bias,
                   void* C, int M, int N, int K, int lda, int flags) {
    dim3 grid(N / 64, (M + 127) / 128);
    gemm_bfa_k<<<grid, dim3(256), 0, stream>>>(A, Wt, bias, C, M, N, K, lda, flags);
  };
  auto cvtb = [&](const float* W, unsigned short* Wt, int K, int N, int L) {
    const int total = K * N * L;
    wtb_k<<<(total + 255) / 256, 256, 0, stream>>>(W, Wt, K, N, total);
  };

  // ---- weight convert/transpose/permute ----
  cvtb(wqkv, wt_qkv, 256, 768, 1);
  cvtb(wo, wt_wo, 256, 256, 1);
  cvtb(tg_W, wt_tgW, 256, 256, 1);
  cvtb(tg_We, wt_tgWe, 256, 256, 1);
  cvtb(g_We, wt_gWe, 256, 256, 3);
  wtp_k<<<1024, 256, 0, stream>>>(w_ih, wt_lstm, 0);
  wtp_k<<<1024, 256, 0, stream>>>(w_hh, wt_lstm, 256);
  cvtb(g_W, wt_gW, 256, 256, 3);
  cvtb(hn_w1, wt_hn, 256, 64, 7);
  cvtb(he_w1, wt_he, 512, 64, 2);

  // ---- CSR build (deterministic) ----
  hipMemsetAsync(ideg, 0, 3000 * sizeof(int), stream);
  hist_k<<<(E_ + 255) / 256, 256, 0, stream>>>(dst, ideg);
  scan_k<<<1, 256, 0, stream>>>(ideg, iroff);
  fill_k<<<750, 256, 0, stream>>>(dst, iroff, ieord);

  // ---------------- Stage A: 4 chunks of 24000 nodes ----------------
  for (int chunk = 0; chunk < 4; ++chunk) {
    dim3 grid(768 / 128, (72000 + 127) / 128);
    gemm_qkv_k<<<grid, dim3(256), 0, stream>>>(env, infra, robot, wt_qkv, bqkv,
                                               qkvb, 72000, chunk * 24000);
    attn_avg_k<<<6000, 256, 0, stream>>>(qkvb, obarb + (size_t)chunk * 24000 * 256, 24000);
  }
  // tmpAb (aliases qkvb, dead) = obar @ wo + bo (bf16), then fseq = LN(tmpAb)
  mgemm(obarb, wt_wo, bo, tmpAb, 96000, 256, 256, 256, 4);
  ln_k<<<96000, 64, 0, stream>>>(tmpAb, lnf_g, lnf_b, fseqb);

  // ---------------- Stage B prep ----------------
  {  // edge_emb = relu(edge_attr @ we_emb + be_emb) -> bf16
    dim3 grid(4, 750);
    gemm_k<<<grid, dim3(256), 0, stream>>>(edgeattr, we_emb, be_emb, eembb,
                                           48000, 256, 8, 8, 2 | 4);
  }
  // one batched edge-transform GEMM: [tgWe | gWe0 | gWe1 | gWe2], N=1024
  mgemm(eembb, wt_tgWe, nullptr, ewall, 48000, 1024, 256, 256, 4);
  elog4_k<<<6000, 256, 0, stream>>>(ewall, tg_aedge, g_aedge, elogall);

  mgemm(fseqb, wt_tgW, nullptr, xwallb, 96000, 256, 256, 256, 4);
  alphas_k<<<3000, 256, 0, stream>>>(xwallb, tg_asrc, tg_adst, sal, dal, 96000);
  gat_k<1><<<24000, 256, 0, stream>>>(xwallb, ewall, sal, dal, elogall, iroff, ieord,
                                      src, gatallb, 96000, 3, 1024, 0);

  // ---------------- LSTM over T (fused GEMM + pointwise) ----------------
  hipMemsetAsync(c, 0, 12288000, stream);
  unsigned short* hbq[2] = { hb0, hb1 };
  for (int t = 0; t < T_; ++t) {
    dim3 grid(16, 94);
    // t=0: h==0, so only the K=256 ih half contributes (exact)
    gemm_lstm_k<<<grid, dim3(256), 0, stream>>>(gatallb, hbq[t & 1], wt_lstm, b_lstm,
                                                h, c, hbq[(t + 1) & 1], t,
                                                t == 0 ? 256 : 512);
  }
  unsigned short* hbf = hbq[0];  // T=8 even -> final h in hb0

  // ---------------- 3 GAT layers with residual LN ----------------
  for (int l = 0; l < 3; ++l) {
    mgemm(hbf, wt_gW + (size_t)l * 65536, nullptr, xw_sb, 12000, 256, 256, 256, 4);
    alphas_k<<<375, 256, 0, stream>>>(xw_sb, g_asrc + l * 256, g_adst + l * 256, sal, dal, 12000);
    gat_k<0><<<3000, 256, 0, stream>>>(xw_sb, ewall, sal, dal, elogall + 384000 * (l + 1),
                                       iroff, ieord, src, gat_s, 12000, 0,
                                       1024, 256 * (l + 1));
    resln_k<<<12000, 64, 0, stream>>>(h, gat_s, g_lng + l * 256, g_lnb + l * 256, hbf);
  }

  // ---------------- Heads ----------------
  mgemm(hbf, wt_hn, hn_b1, hidn, 12000, 448, 256, 256, 2);
  nh2_k<<<(84000 + 255) / 256, 256, 0, stream>>>(hidn, hn_w2, hn_b2, outp);

  hglob1_k<<<dim3(4, 25), 256, 0, stream>>>(h, hgp);
  hglob2_k<<<4, 256, 0, stream>>>(hgp, hg);
  freq_k<<<4, 64, 0, stream>>>(hg, hn_w1 + 7 * 16384, hn_b1 + 7 * 64,
                               hn_w2 + 7 * 64, hn_b2 + 7, outp);

  // edge heads: fused gather GEMM (no ef buffer)
  {
    dim3 grid(2, 375);
    gemm_ef_k<<<grid, dim3(256), 0, stream>>>(hbf, src, dst, wt_he, he_b1, hide);
  }
  eh2_k<<<(96000 + 255) / 256, 256, 0, stream>>>(hide, he_w2, he_b2, outp);
}

// Round 15
// 1517.707 us; speedup vs baseline: 1.1668x; 1.0367x over previous
//
#include <hip/hip_runtime.h>
#include <hip/hip_bf16.h>
#include <math.h>

#define DEV __device__ __forceinline__

namespace {
constexpr int B_ = 4, T_ = 8, N_ = 3000, E_ = 12000;
constexpr int OUTS_ = 45001;  // per-batch output stride: N*7 + E + E + 1
}

using f32x4 = __attribute__((ext_vector_type(4))) float;
using bf16x8 = __attribute__((ext_vector_type(8))) short;

DEV float sigm_(float x) { return 1.0f / (1.0f + expf(-x)); }
DEV float softplus_(float x) { return fmaxf(x, 0.0f) + log1pf(expf(-fabsf(x))); }
DEV float wred_(float v) {
  #pragma unroll
  for (int o = 32; o > 0; o >>= 1) v += __shfl_xor(v, o, 64);
  return v;
}
DEV unsigned short f2bf(float x) {  // RNE fp32->bf16
  unsigned u = __float_as_uint(x);
  return (unsigned short)((u + 0x7FFFu + ((u >> 16) & 1u)) >> 16);
}
DEV unsigned f2bf2(float a, float b) {
  return (unsigned)f2bf(a) | ((unsigned)f2bf(b) << 16);
}
DEV float bfl(unsigned u) { return __uint_as_float(u << 16); }
DEV float bfh(unsigned u) { return __uint_as_float(u & 0xffff0000u); }

// ---------------------------------------------------------------------------
// Batched weight transpose+convert: L matrices [K][N] -> per-matrix [N][K] bf16
// ---------------------------------------------------------------------------
__global__ void wtb_k(const float* __restrict__ W, unsigned short* __restrict__ Wt,
                      int K, int N, int total)
{
  const int idx = blockIdx.x * blockDim.x + threadIdx.x;
  if (idx >= total) return;
  const int kn = K * N;
  const int l = idx / kn;
  const int r = idx - l * kn;
  const int k = r / N, n = r - k * N;
  Wt[(size_t)l * kn + (size_t)n * K + k] = f2bf(W[idx]);
}

// LSTM weight permute: orig col n = gate*256+d -> newcol = d*4+gate; dense [1024][512]
__global__ void wtp_k(const float* __restrict__ W, unsigned short* __restrict__ Wt,
                      int kOff)
{
  const int idx = blockIdx.x * blockDim.x + threadIdx.x;
  if (idx >= 256 * 1024) return;
  const int k = idx >> 10;
  const int n = idx & 1023;
  const int newcol = (n & 255) * 4 + (n >> 8);
  Wt[(size_t)newcol * 512 + kOff + k] = f2bf(W[idx]);
}

// ---------------------------------------------------------------------------
// CSR build (deterministic)
// ---------------------------------------------------------------------------
__global__ void hist_k(const int* __restrict__ dst, int* __restrict__ deg)
{
  const int e = blockIdx.x * blockDim.x + threadIdx.x;
  if (e < E_) atomicAdd(&deg[dst[e]], 1);
}

__global__ __launch_bounds__(256) void scan_k(const int* __restrict__ deg,
                                              int* __restrict__ roff)
{
  __shared__ int part[256];
  const int t = threadIdx.x;
  int loc[12];
  int s = 0;
  #pragma unroll
  for (int i = 0; i < 12; ++i) {
    const int n = t * 12 + i;
    loc[i] = s;
    s += (n < N_) ? deg[n] : 0;
  }
  part[t] = s;
  __syncthreads();
  if (t == 0) {
    int run = 0;
    for (int i = 0; i < 256; ++i) { const int v = part[i]; part[i] = run; run += v; }
  }
  __syncthreads();
  const int base = part[t];
  #pragma unroll
  for (int i = 0; i < 12; ++i) {
    const int n = t * 12 + i;
    if (n < N_) roff[n] = base + loc[i];
  }
  if (t == 0) roff[N_] = E_;
}

__global__ __launch_bounds__(256) void fill_k(const int* __restrict__ dst,
                                              const int* __restrict__ roff,
                                              int* __restrict__ eord)
{
  const int n = blockIdx.x * 4 + (threadIdx.x >> 6);
  if (n >= N_) return;
  const int lane = threadIdx.x & 63;
  const unsigned long long ltm = (1ull << lane) - 1ull;
  int cnt = roff[n];
  for (int c = 0; c < E_; c += 64) {
    const int e = c + lane;
    const bool m = (e < E_) && (dst[e] == n);
    const unsigned long long mask = __ballot(m);
    if (m) eord[cnt + __popcll(mask & ltm)] = e;
    cnt += __popcll(mask);
  }
}

// ---------------------------------------------------------------------------
// 128x64-tile MFMA bf16 GEMM: C[M,N] = A[M,K](bf16) @ Wt(bf16,[N][K])
// flags: 1 = C += (fp32 C), 2 = relu, 4 = store bf16 C.
// ---------------------------------------------------------------------------
__global__ __launch_bounds__(256) void gemm_bfa_k(
    const unsigned short* __restrict__ A, const unsigned short* __restrict__ Wt,
    const float* __restrict__ bias, void* __restrict__ Cv,
    int M, int N, int K, int lda, int flags)
{
  __shared__ unsigned short Al[128 * 40];
  __shared__ unsigned short Bl[64 * 40];
  const int tid = threadIdx.x;
  const int bm = blockIdx.y * 128;
  const int bn = blockIdx.x * 64;
  const int lane = tid & 63;
  const int wv = tid >> 6;
  const int wm = (wv >> 1) * 64;
  const int wn = (wv & 1) * 32;
  const int s_row = tid >> 1;
  const int s_cb = (tid & 1) * 16;
  const int grow = bm + s_row;
  const unsigned short* Arow = (grow < M) ? A + (size_t)grow * lda : nullptr;
  const int b_col = tid >> 2;
  const int b_ks = (tid & 3) * 8;
  const unsigned short* Wrow = Wt + (size_t)(bn + b_col) * K + b_ks;

  f32x4 acc[4][2] = {};
  const int l15 = lane & 15;
  const int lk = (lane >> 4) * 8;

  for (int k0 = 0; k0 < K; k0 += 32) {
    uint4 a0, a1;
    if (Arow) {
      a0 = *(const uint4*)(Arow + k0 + s_cb);
      a1 = *(const uint4*)(Arow + k0 + s_cb + 8);
    } else {
      a0 = make_uint4(0, 0, 0, 0);
      a1 = a0;
    }
    *(uint4*)&Al[s_row * 40 + s_cb] = a0;
    *(uint4*)&Al[s_row * 40 + s_cb + 8] = a1;
    *(uint4*)&Bl[b_col * 40 + b_ks] = *(const uint4*)(Wrow + k0);
    __syncthreads();
    bf16x8 af[4], bfr[2];
    #pragma unroll
    for (int m = 0; m < 4; ++m)
      af[m] = *(const bf16x8*)&Al[(wm + m * 16 + l15) * 40 + lk];
    #pragma unroll
    for (int n = 0; n < 2; ++n)
      bfr[n] = *(const bf16x8*)&Bl[(wn + n * 16 + l15) * 40 + lk];
    #pragma unroll
    for (int m = 0; m < 4; ++m)
      #pragma unroll
      for (int n = 0; n < 2; ++n)
        acc[m][n] = __builtin_amdgcn_mfma_f32_16x16x32_bf16(af[m], bfr[n], acc[m][n], 0, 0, 0);
    __syncthreads();
  }
  float* Cf = (float*)Cv;
  unsigned short* Cb = (unsigned short*)Cv;
  const int r4 = (lane >> 4) * 4;
  #pragma unroll
  for (int m = 0; m < 4; ++m) {
    #pragma unroll
    for (int n = 0; n < 2; ++n) {
      const int col = bn + wn + n * 16 + l15;
      const float bv = bias ? bias[col] : 0.f;
      #pragma unroll
      for (int r = 0; r < 4; ++r) {
        const int row = bm + wm + m * 16 + r4 + r;
        if (row >= M) continue;
        float v = acc[m][n][r] + bv;
        const size_t ci = (size_t)row * N + col;
        if (flags & 1) v += Cf[ci];
        if (flags & 2) v = fmaxf(v, 0.f);
        if (flags & 4) Cb[ci] = f2bf(v);
        else Cf[ci] = v;
      }
    }
  }
}

// ---------------------------------------------------------------------------
// Stage-A qkv GEMM, 128x128 tile (BK=32), 1-D grid with bijective XCD swizzle:
// consecutive LOGICAL tiles (6 col-blocks of one A row-panel) land on the SAME
// XCD so the A panel stays L2-resident across its 6 reads. A rows are fp32
// from 3 interleaved sources (row r: slot=r%3, node=nodeBase+r/3).
// ---------------------------------------------------------------------------
__global__ __launch_bounds__(256) void gemm_qkv_k(
    const float* __restrict__ env, const float* __restrict__ infra,
    const float* __restrict__ robot, const unsigned short* __restrict__ Wt,
    const float* __restrict__ bias, unsigned short* __restrict__ Cb,
    int M, int nodeBase)
{
  __shared__ unsigned short Al[128 * 40];
  __shared__ unsigned short Bl[128 * 40];
  // bijective chunked XCD swizzle (nwg % 8 != 0 safe)
  const int nwg = gridDim.x;
  const int orig = blockIdx.x;
  const int q = nwg >> 3, rr = nwg & 7;
  const int xcd = orig & 7, pos = orig >> 3;
  const int logical = (xcd < rr ? xcd * (q + 1) : rr * (q + 1) + (xcd - rr) * q) + pos;
  const int bm = (logical / 6) * 128;
  const int bn = (logical % 6) * 128;

  const int tid = threadIdx.x;
  const int lane = tid & 63;
  const int wv = tid >> 6;
  const int wm = (wv >> 1) * 64;
  const int wn = (wv & 1) * 64;
  const int s_row = tid >> 1;
  const int s_cb = (tid & 1) * 16;
  const int grow = bm + s_row;
  const float* Arow = nullptr;
  if (grow < M) {
    const int slot = grow % 3;
    const int node = nodeBase + grow / 3;
    const float* srcp = (slot == 0 ? env : (slot == 1 ? infra : robot));
    Arow = srcp + (size_t)node * 256;
  }

  f32x4 acc[4][4] = {};
  const int l15 = lane & 15;
  const int lk = (lane >> 4) * 8;

  for (int k0 = 0; k0 < 256; k0 += 32) {
    unsigned abuf[8];
    if (Arow) {
      const float* p = Arow + k0 + s_cb;
      #pragma unroll
      for (int i = 0; i < 4; ++i) {
        const float4 v = *(const float4*)(p + i * 4);
        abuf[i * 2 + 0] = f2bf2(v.x, v.y);
        abuf[i * 2 + 1] = f2bf2(v.z, v.w);
      }
    } else {
      #pragma unroll
      for (int i = 0; i < 8; ++i) abuf[i] = 0;
    }
    *(uint4*)&Al[s_row * 40 + s_cb] = *(uint4*)&abuf[0];
    *(uint4*)&Al[s_row * 40 + s_cb + 8] = *(uint4*)&abuf[4];
    #pragma unroll
    for (int i = 0; i < 2; ++i) {
      const int task = tid + i * 256;     // 0..511
      const int col = task >> 2;
      const int ks = (task & 3) * 8;
      *(uint4*)&Bl[col * 40 + ks] = *(const uint4*)(Wt + (size_t)(bn + col) * 256 + k0 + ks);
    }
    __syncthreads();
    bf16x8 af[4], bfr[4];
    #pragma unroll
    for (int m = 0; m < 4; ++m)
      af[m] = *(const bf16x8*)&Al[(wm + m * 16 + l15) * 40 + lk];
    #pragma unroll
    for (int n = 0; n < 4; ++n)
      bfr[n] = *(const bf16x8*)&Bl[(wn + n * 16 + l15) * 40 + lk];
    #pragma unroll
    for (int m = 0; m < 4; ++m)
      #pragma unroll
      for (int n = 0; n < 4; ++n)
        acc[m][n] = __builtin_amdgcn_mfma_f32_16x16x32_bf16(af[m], bfr[n], acc[m][n], 0, 0, 0);
    __syncthreads();
  }
  const int r4 = (lane >> 4) * 4;
  #pragma unroll
  for (int m = 0; m < 4; ++m) {
    #pragma unroll
    for (int n = 0; n < 4; ++n) {
      const int col = bn + wn + n * 16 + l15;
      const float bv = bias[col];
      #pragma unroll
      for (int r = 0; r < 4; ++r) {
        const int row = bm + wm + m * 16 + r4 + r;
        if (row >= M) continue;
        Cb[(size_t)row * 768 + col] = f2bf(acc[m][n][r] + bv);
      }
    }
  }
}

// ---------------------------------------------------------------------------
// Fused LSTM step: gates = [gat_t | h] @ Wt_perm (kEnd=512; kEnd=256 at t=0
// since h==0), newcol = d*4+gate; LSTM pointwise in epilogue via LDS transpose.
// Writes c, h (fp32), hbOut. hbIn/hbOut MUST differ (cross-block race).
// ---------------------------------------------------------------------------
__global__ __launch_bounds__(256) void gemm_lstm_k(
    const unsigned short* __restrict__ gatall, const unsigned short* __restrict__ hbIn,
    const unsigned short* __restrict__ Wt, const float* __restrict__ b_lstm,
    float* __restrict__ h, float* __restrict__ c, unsigned short* __restrict__ hbOut,
    int t, int kEnd)
{
  __shared__ float Gl[128][65];
  unsigned short* Al = (unsigned short*)&Gl[0][0];
  unsigned short* Bl = Al + 128 * 40;
  const int tid = threadIdx.x;
  const int bm = blockIdx.y * 128;
  const int bn = blockIdx.x * 64;
  const int lane = tid & 63;
  const int wv = tid >> 6;
  const int wm = (wv >> 1) * 64;
  const int wn = (wv & 1) * 32;
  const int s_row = tid >> 1;
  const int s_cb = (tid & 1) * 16;
  const int grow = bm + s_row;
  const unsigned short* Arow1 = nullptr;
  const unsigned short* Arow2 = nullptr;
  if (grow < 12000) {
    const int phys = (grow / N_) * (T_ * N_) + t * N_ + (grow % N_);
    Arow1 = gatall + (size_t)phys * 256;
    Arow2 = hbIn + (size_t)grow * 256;
  }
  const int b_col = tid >> 2;
  const int b_ks = (tid & 3) * 8;
  const unsigned short* Wrow = Wt + (size_t)(bn + b_col) * 512 + b_ks;

  f32x4 acc[4][2] = {};
  const int l15 = lane & 15;
  const int lk = (lane >> 4) * 8;

  for (int k0 = 0; k0 < kEnd; k0 += 32) {
    uint4 a0, a1;
    if (Arow1) {
      const unsigned short* p = (k0 < 256) ? (Arow1 + k0 + s_cb)
                                           : (Arow2 + (k0 - 256) + s_cb);
      a0 = *(const uint4*)p;
      a1 = *(const uint4*)(p + 8);
    } else {
      a0 = make_uint4(0, 0, 0, 0);
      a1 = a0;
    }
    *(uint4*)&Al[s_row * 40 + s_cb] = a0;
    *(uint4*)&Al[s_row * 40 + s_cb + 8] = a1;
    *(uint4*)&Bl[b_col * 40 + b_ks] = *(const uint4*)(Wrow + k0);
    __syncthreads();
    bf16x8 af[4], bfr[2];
    #pragma unroll
    for (int m = 0; m < 4; ++m)
      af[m] = *(const bf16x8*)&Al[(wm + m * 16 + l15) * 40 + lk];
    #pragma unroll
    for (int n = 0; n < 2; ++n)
      bfr[n] = *(const bf16x8*)&Bl[(wn + n * 16 + l15) * 40 + lk];
    #pragma unroll
    for (int m = 0; m < 4; ++m)
      #pragma unroll
      for (int n = 0; n < 2; ++n)
        acc[m][n] = __builtin_amdgcn_mfma_f32_16x16x32_bf16(af[m], bfr[n], acc[m][n], 0, 0, 0);
    __syncthreads();
  }
  const int r4 = (lane >> 4) * 4;
  #pragma unroll
  for (int m = 0; m < 4; ++m)
    #pragma unroll
    for (int n = 0; n < 2; ++n) {
      const int col = wn + n * 16 + l15;
      #pragma unroll
      for (int r = 0; r < 4; ++r)
        Gl[wm + m * 16 + r4 + r][col] = acc[m][n][r];
    }
  __syncthreads();
  const int fl = lane & 7;
  const int rg = lane >> 3;
  const int dg = ((bn + wn) >> 2) + fl;
  const float bi = b_lstm[dg];
  const float bff = b_lstm[256 + dg];
  const float bg = b_lstm[512 + dg];
  const float bo = b_lstm[768 + dg];
  const int colb = wn + fl * 4;
  #pragma unroll
  for (int i = 0; i < 8; ++i) {
    const int rl = rg + i * 8;
    const int row = bm + wm + rl;
    if (row >= 12000) continue;
    const float g0 = Gl[wm + rl][colb + 0] + bi;
    const float g1 = Gl[wm + rl][colb + 1] + bff;
    const float g2 = Gl[wm + rl][colb + 2] + bg;
    const float g3 = Gl[wm + rl][colb + 3] + bo;
    const size_t idx = (size_t)row * 256 + dg;
    const float cn = sigm_(g1) * c[idx] + sigm_(g0) * tanhf(g2);
    c[idx] = cn;
    const float hn = sigm_(g3) * tanhf(cn);
    h[idx] = hn;
    hbOut[idx] = f2bf(hn);
  }
}

// ---------------------------------------------------------------------------
// Edge-head GEMM with fused ef gather: A row r (of 48000) = concat(
// hb[b,src[e]], hb[b,dst[e]]), b=r/E, e=r%E. K=512, N=128, relu, fp32 out.
// ---------------------------------------------------------------------------
__global__ __launch_bounds__(256) void gemm_ef_k(
    const unsigned short* __restrict__ hb, const int* __restrict__ srcA,
    const int* __restrict__ dstA, const unsigned short* __restrict__ Wt,
    const float* __restrict__ bias, float* __restrict__ Cf)
{
  __shared__ unsigned short Al[128 * 40];
  __shared__ unsigned short Bl[64 * 40];
  const int tid = threadIdx.x;
  const int bm = blockIdx.y * 128;
  const int bn = blockIdx.x * 64;
  const int lane = tid & 63;
  const int wv = tid >> 6;
  const int wm = (wv >> 1) * 64;
  const int wn = (wv & 1) * 32;
  const int s_row = tid >> 1;
  const int s_cb = (tid & 1) * 16;
  const int grow = bm + s_row;
  const unsigned short* Arow1 = nullptr;
  const unsigned short* Arow2 = nullptr;
  if (grow < 48000) {
    const int b = grow / E_;
    const int e = grow - b * E_;
    Arow1 = hb + ((size_t)(b * N_ + srcA[e])) * 256;
    Arow2 = hb + ((size_t)(b * N_ + dstA[e])) * 256;
  }
  const int b_col = tid >> 2;
  const int b_ks = (tid & 3) * 8;
  const unsigned short* Wrow = Wt + (size_t)(bn + b_col) * 512 + b_ks;

  f32x4 acc[4][2] = {};
  const int l15 = lane & 15;
  const int lk = (lane >> 4) * 8;

  for (int k0 = 0; k0 < 512; k0 += 32) {
    uint4 a0, a1;
    if (Arow1) {
      const unsigned short* p = (k0 < 256) ? (Arow1 + k0 + s_cb)
                                           : (Arow2 + (k0 - 256) + s_cb);
      a0 = *(const uint4*)p;
      a1 = *(const uint4*)(p + 8);
    } else {
      a0 = make_uint4(0, 0, 0, 0);
      a1 = a0;
    }
    *(uint4*)&Al[s_row * 40 + s_cb] = a0;
    *(uint4*)&Al[s_row * 40 + s_cb + 8] = a1;
    *(uint4*)&Bl[b_col * 40 + b_ks] = *(const uint4*)(Wrow + k0);
    __syncthreads();
    bf16x8 af[4], bfr[2];
    #pragma unroll
    for (int m = 0; m < 4; ++m)
      af[m] = *(const bf16x8*)&Al[(wm + m * 16 + l15) * 40 + lk];
    #pragma unroll
    for (int n = 0; n < 2; ++n)
      bfr[n] = *(const bf16x8*)&Bl[(wn + n * 16 + l15) * 40 + lk];
    #pragma unroll
    for (int m = 0; m < 4; ++m)
      #pragma unroll
      for (int n = 0; n < 2; ++n)
        acc[m][n] = __builtin_amdgcn_mfma_f32_16x16x32_bf16(af[m], bfr[n], acc[m][n], 0, 0, 0);
    __syncthreads();
  }
  const int r4 = (lane >> 4) * 4;
  #pragma unroll
  for (int m = 0; m < 4; ++m) {
    #pragma unroll
    for (int n = 0; n < 2; ++n) {
      const int col = bn + wn + n * 16 + l15;
      const float bv = bias[col];
      #pragma unroll
      for (int r = 0; r < 4; ++r) {
        const int row = bm + wm + m * 16 + r4 + r;
        if (row >= 48000) continue;
        Cf[(size_t)row * 128 + col] = fmaxf(acc[m][n][r] + bv, 0.f);
      }
    }
  }
}

// ---------------------------------------------------------------------------
// fp32 fallback GEMM (only the K=8 edge-emb GEMM); flags&4 -> bf16 C store
// ---------------------------------------------------------------------------
__global__ __launch_bounds__(256) void gemm_k(
    const float* __restrict__ A, const float* __restrict__ W,
    const float* __restrict__ bias, void* __restrict__ Cv,
    int M, int N, int K, int lda, int flags)
{
  __shared__ float As[16][68];
  __shared__ float Ws[16][64];
  const int tid = threadIdx.x;
  const int bm = blockIdx.y * 64;
  const int bn = blockIdx.x * 64;
  const int tx = tid & 15;
  const int ty = tid >> 4;
  const int ar = tid >> 2;
  const int ac = (tid & 3) << 2;
  const int wr = tid >> 4;
  const int wc = (tid & 15) << 2;
  const int grow = bm + ar;
  const float* Arow = (grow < M) ? A + (size_t)grow * lda : nullptr;
  float acc[4][4] = {};
  for (int k0 = 0; k0 < K; k0 += 16) {
    float4 av = make_float4(0.f, 0.f, 0.f, 0.f);
    if (Arow) {
      av.x = (k0 + ac + 0 < K) ? Arow[k0 + ac + 0] : 0.f;
      av.y = (k0 + ac + 1 < K) ? Arow[k0 + ac + 1] : 0.f;
      av.z = (k0 + ac + 2 < K) ? Arow[k0 + ac + 2] : 0.f;
      av.w = (k0 + ac + 3 < K) ? Arow[k0 + ac + 3] : 0.f;
    }
    As[ac + 0][ar] = av.x;
    As[ac + 1][ar] = av.y;
    As[ac + 2][ar] = av.z;
    As[ac + 3][ar] = av.w;
    float4 wv = make_float4(0.f, 0.f, 0.f, 0.f);
    if (k0 + wr < K) {
      const int gc = bn + wc;
      const float* wp = W + (size_t)(k0 + wr) * N + gc;
      wv.x = (gc + 0 < N) ? wp[0] : 0.f;
      wv.y = (gc + 1 < N) ? wp[1] : 0.f;
      wv.z = (gc + 2 < N) ? wp[2] : 0.f;
      wv.w = (gc + 3 < N) ? wp[3] : 0.f;
    }
    *(float4*)&Ws[wr][wc] = wv;
    __syncthreads();
    #pragma unroll
    for (int kk = 0; kk < 16; ++kk) {
      const float4 a = *(const float4*)&As[kk][ty << 2];
      const float4 b = *(const float4*)&Ws[kk][tx << 2];
      acc[0][0] += a.x * b.x; acc[0][1] += a.x * b.y; acc[0][2] += a.x * b.z; acc[0][3] += a.x * b.w;
      acc[1][0] += a.y * b.x; acc[1][1] += a.y * b.y; acc[1][2] += a.y * b.z; acc[1][3] += a.y * b.w;
      acc[2][0] += a.z * b.x; acc[2][1] += a.z * b.y; acc[2][2] += a.z * b.z; acc[2][3] += a.z * b.w;
      acc[3][0] += a.w * b.x; acc[3][1] += a.w * b.y; acc[3][2] += a.w * b.z; acc[3][3] += a.w * b.w;
    }
    __syncthreads();
  }
  float* Cf = (float*)Cv;
  unsigned short* Cb = (unsigned short*)Cv;
  #pragma unroll
  for (int i = 0; i < 4; ++i) {
    const int row = bm + (ty << 2) + i;
    if (row >= M) continue;
    #pragma unroll
    for (int j = 0; j < 4; ++j) {
      const int col = bn + (tx << 2) + j;
      if (col >= N) continue;
      float v = acc[i][j];
      if (bias) v += bias[col];
      if (flags & 2) v = fmaxf(v, 0.f);
      const size_t ci = (size_t)row * N + col;
      if (flags & 4) Cb[ci] = f2bf(v);
      else Cf[ci] = v;
    }
  }
}

// ---------------------------------------------------------------------------
// Stage A attention: ONE WAVE PER NODE (coalesced). Lane l -> head l>>3,
// elems (l&7)*4; qkv offset = node*2304 + 4*l. 9 dots reduce over the 8-lane
// subgroup via shfl_xor(1,2,4). 4 waves/block.
// ---------------------------------------------------------------------------
__global__ __launch_bounds__(256) void attn_avg_k(
    const unsigned short* __restrict__ qkv,
    unsigned short* __restrict__ obar, int nodes)
{
  const int node = blockIdx.x * 4 + (threadIdx.x >> 6);
  if (node >= nodes) return;
  const int lane = threadIdx.x & 63;
  const unsigned short* base = qkv + (size_t)node * 2304 + lane * 4;
  float qv[3][4], kv[3][4], vv[3][4];
  #pragma unroll
  for (int s = 0; s < 3; ++s) {
    const uint2 uq = *(const uint2*)(base + s * 768);
    const uint2 uk = *(const uint2*)(base + s * 768 + 256);
    const uint2 uv = *(const uint2*)(base + s * 768 + 512);
    qv[s][0] = bfl(uq.x); qv[s][1] = bfh(uq.x); qv[s][2] = bfl(uq.y); qv[s][3] = bfh(uq.y);
    kv[s][0] = bfl(uk.x); kv[s][1] = bfh(uk.x); kv[s][2] = bfl(uk.y); kv[s][3] = bfh(uk.y);
    vv[s][0] = bfl(uv.x); vv[s][1] = bfh(uv.x); vv[s][2] = bfl(uv.y); vv[s][3] = bfh(uv.y);
  }
  float att[3][3];
  #pragma unroll
  for (int s = 0; s < 3; ++s) {
    #pragma unroll
    for (int t = 0; t < 3; ++t) {
      float d = qv[s][0] * kv[t][0] + qv[s][1] * kv[t][1]
              + qv[s][2] * kv[t][2] + qv[s][3] * kv[t][3];
      d += __shfl_xor(d, 1, 64);
      d += __shfl_xor(d, 2, 64);
      d += __shfl_xor(d, 4, 64);
      att[s][t] = d * 0.17677669529663687f;
    }
  }
  float cs[3] = {0.f, 0.f, 0.f};
  #pragma unroll
  for (int s = 0; s < 3; ++s) {
    const float m = fmaxf(att[s][0], fmaxf(att[s][1], att[s][2]));
    const float e0 = expf(att[s][0] - m);
    const float e1 = expf(att[s][1] - m);
    const float e2 = expf(att[s][2] - m);
    const float inv = (1.f / 3.f) / (e0 + e1 + e2);
    cs[0] += e0 * inv; cs[1] += e1 * inv; cs[2] += e2 * inv;
  }
  float o0 = cs[0] * vv[0][0] + cs[1] * vv[1][0] + cs[2] * vv[2][0];
  float o1 = cs[0] * vv[0][1] + cs[1] * vv[1][1] + cs[2] * vv[2][1];
  float o2 = cs[0] * vv[0][2] + cs[1] * vv[1][2] + cs[2] * vv[2][2];
  float o3 = cs[0] * vv[0][3] + cs[1] * vv[1][3] + cs[2] * vv[2][3];
  uint2 ob;
  ob.x = f2bf2(o0, o1);
  ob.y = f2bf2(o2, o3);
  *(uint2*)(obar + (size_t)node * 256 + lane * 4) = ob;
}

// LayerNorm per row; bf16 in, bf16 out. 1 wave per row.
__global__ __launch_bounds__(64) void ln_k(
    const unsigned short* __restrict__ in, const float* __restrict__ g,
    const float* __restrict__ bta, unsigned short* __restrict__ outp)
{
  const int row = blockIdx.x;
  const int d0 = threadIdx.x << 2;
  const uint2 a = *(const uint2*)(in + (size_t)row * 256 + d0);
  float x[4] = { bfl(a.x), bfh(a.x), bfl(a.y), bfh(a.y) };
  float s = x[0] + x[1] + x[2] + x[3];
  s = wred_(s);
  const float mean = s * (1.f / 256.f);
  float vs = 0.f;
  #pragma unroll
  for (int i = 0; i < 4; ++i) { const float dd = x[i] - mean; vs += dd * dd; }
  vs = wred_(vs);
  const float inv = 1.0f / sqrtf(vs * (1.f / 256.f) + 1e-5f);
  const float4 gv = *(const float4*)(g + d0);
  const float4 bv = *(const float4*)(bta + d0);
  uint2 o;
  o.x = f2bf2((x[0] - mean) * inv * gv.x + bv.x, (x[1] - mean) * inv * gv.y + bv.y);
  o.y = f2bf2((x[2] - mean) * inv * gv.z + bv.z, (x[3] - mean) * inv * gv.w + bv.w);
  *(uint2*)(outp + (size_t)row * 256 + d0) = o;
}

// ---------------------------------------------------------------------------
// GAT kernels (bf16 feature inputs)
// ---------------------------------------------------------------------------
__global__ void alphas_k(const unsigned short* __restrict__ xw, const float* __restrict__ as,
                         const float* __restrict__ ad, float* __restrict__ sal,
                         float* __restrict__ dal, int rows)
{
  const int idx = blockIdx.x * blockDim.x + threadIdx.x;
  if (idx >= rows * 8) return;
  const int row = idx >> 3, h = idx & 7;
  const unsigned short* x = xw + (size_t)row * 256 + h * 32;
  const float* a1 = as + h * 32;
  const float* a2 = ad + h * 32;
  float s = 0.f, d = 0.f;
  #pragma unroll
  for (int i = 0; i < 4; ++i) {
    const uint4 ux = *(const uint4*)(x + i * 8);
    const unsigned* p = &ux.x;
    #pragma unroll
    for (int j = 0; j < 4; ++j) {
      const float lo = bfl(p[j]), hi = bfh(p[j]);
      s += lo * a1[i * 8 + 2 * j] + hi * a1[i * 8 + 2 * j + 1];
      d += lo * a2[i * 8 + 2 * j] + hi * a2[i * 8 + 2 * j + 1];
    }
  }
  sal[idx] = s; dal[idx] = d;
}

// all 4 edge-logit sets in one launch; ew is [48000][1024] (4 x 256 packed)
__global__ void elog4_k(const unsigned short* __restrict__ ew,
                        const float* __restrict__ tg_ae, const float* __restrict__ g_ae,
                        float* __restrict__ el)
{
  const int idx = blockIdx.x * blockDim.x + threadIdx.x;
  if (idx >= 4 * 48000 * 8) return;
  const int l = idx / (48000 * 8);
  const int r = idx - l * (48000 * 8);
  const int row = r >> 3, h = r & 7;
  const unsigned short* x = ew + (size_t)row * 1024 + l * 256 + h * 32;
  const float* a1 = (l == 0 ? tg_ae : g_ae + (l - 1) * 256) + h * 32;
  float s = 0.f;
  #pragma unroll
  for (int i = 0; i < 4; ++i) {
    const uint4 ux = *(const uint4*)(x + i * 8);
    const unsigned* p = &ux.x;
    #pragma unroll
    for (int j = 0; j < 4; ++j) {
      s += bfl(p[j]) * a1[i * 8 + 2 * j] + bfh(p[j]) * a1[i * 8 + 2 * j + 1];
    }
  }
  el[l * 384000 + r] = s;
}

// Fused GAT aggregation: one wave per (beta,node). Online softmax over incoming
// edges (CSR). bf16 gathers. OUTBF: 1 -> bf16 out, 0 -> fp32 out.
template<int OUTBF>
__global__ __launch_bounds__(256) void gat_k(
    const unsigned short* __restrict__ xw, const unsigned short* __restrict__ ew,
    const float* __restrict__ sal, const float* __restrict__ dal,
    const float* __restrict__ el, const int* __restrict__ roff,
    const int* __restrict__ eord, const int* __restrict__ srcArr,
    void* __restrict__ outp, int nwaves, int tshift, int ewStride, int ewOff)
{
  const int wid = blockIdx.x * 4 + (threadIdx.x >> 6);
  if (wid >= nwaves) return;
  const int beta = wid / N_;
  const int n = wid - beta * N_;
  const int b = beta >> tshift;
  const int lane = threadIdx.x & 63;
  const int h = lane >> 3;
  const int d0 = lane << 2;
  const float dal_h = dal[(size_t)wid * 8 + h];
  const int p0 = roff[n], p1 = roff[n + 1];
  float m = -1e30f, s = 0.f;
  float4 acc = make_float4(0.f, 0.f, 0.f, 0.f);
  for (int p = p0; p < p1; ++p) {
    const int e = eord[p];
    const int sc = srcArr[e];
    float lg = sal[((size_t)beta * N_ + sc) * 8 + h] + dal_h + el[((size_t)b * E_ + e) * 8 + h];
    lg = lg > 0.f ? lg : 0.2f * lg;
    const float mn = fmaxf(m, lg);
    const float scale = expf(m - mn);
    const float w = expf(lg - mn);
    s = s * scale + w;
    const uint2 ux = *(const uint2*)(xw + ((size_t)beta * N_ + sc) * 256 + d0);
    const uint2 ue = *(const uint2*)(ew + ((size_t)(b * E_ + e)) * ewStride + ewOff + d0);
    acc.x = acc.x * scale + w * (bfl(ux.x) + bfl(ue.x));
    acc.y = acc.y * scale + w * (bfh(ux.x) + bfh(ue.x));
    acc.z = acc.z * scale + w * (bfl(ux.y) + bfl(ue.y));
    acc.w = acc.w * scale + w * (bfh(ux.y) + bfh(ue.y));
    m = mn;
  }
  const float inv = 1.0f / (s + 1e-16f);
  if (OUTBF) {
    uint2 o;
    o.x = f2bf2(acc.x * inv, acc.y * inv);
    o.y = f2bf2(acc.z * inv, acc.w * inv);
    *(uint2*)((unsigned short*)outp + (size_t)wid * 256 + d0) = o;
  } else {
    *(float4*)((float*)outp + (size_t)wid * 256 + d0) =
        make_float4(acc.x * inv, acc.y * inv, acc.z * inv, acc.w * inv);
  }
}

// h = LN(h + add); writes fp32 h and bf16 hb
__global__ __launch_bounds__(64) void resln_k(float* __restrict__ h,
                                              const float* __restrict__ add,
                                              const float* __restrict__ g,
                                              const float* __restrict__ bta,
                                              unsigned short* __restrict__ hb)
{
  const int row = blockIdx.x;
  const int d0 = threadIdx.x << 2;
  float* hp = h + (size_t)row * 256;
  const float4 hv = *(const float4*)(hp + d0);
  const float4 av = *(const float4*)(add + (size_t)row * 256 + d0);
  float x[4] = { hv.x + av.x, hv.y + av.y, hv.z + av.z, hv.w + av.w };
  float s = x[0] + x[1] + x[2] + x[3];
  s = wred_(s);
  const float mean = s * (1.f / 256.f);
  float vs = 0.f;
  #pragma unroll
  for (int i = 0; i < 4; ++i) { const float dd = x[i] - mean; vs += dd * dd; }
  vs = wred_(vs);
  const float inv = 1.0f / sqrtf(vs * (1.f / 256.f) + 1e-5f);
  const float4 gv = *(const float4*)(g + d0);
  const float4 bv = *(const float4*)(bta + d0);
  float o0 = (x[0] - mean) * inv * gv.x + bv.x;
  float o1 = (x[1] - mean) * inv * gv.y + bv.y;
  float o2 = (x[2] - mean) * inv * gv.z + bv.z;
  float o3 = (x[3] - mean) * inv * gv.w + bv.w;
  *(float4*)(hp + d0) = make_float4(o0, o1, o2, o3);
  uint2 ob;
  ob.x = f2bf2(o0, o1);
  ob.y = f2bf2(o2, o3);
  *(uint2*)(hb + (size_t)row * 256 + d0) = ob;
}

// ---------------------------------------------------------------------------
// Head kernels
// ---------------------------------------------------------------------------
__global__ void nh2_k(const float* __restrict__ hidden, const float* __restrict__ w2,
                      const float* __restrict__ b2, float* __restrict__ outp)
{
  const int idx = blockIdx.x * blockDim.x + threadIdx.x;
  if (idx >= B_ * N_ * 7) return;
  const int row = idx / 7, j = idx % 7;
  const float* hp = hidden + (size_t)row * 448 + j * 64;
  const float* wp = w2 + j * 64;
  float a = 0.f;
  #pragma unroll
  for (int u = 0; u < 64; ++u) a += hp[u] * wp[u];
  a += b2[j];
  if (j == 0 || j == 6) a = sigm_(a);
  else if (j == 1) a = softplus_(a);
  const int b = row / N_, n = row % N_;
  outp[(size_t)b * OUTS_ + n * 7 + j] = a;
}

// two-stage deterministic h_global mean
__global__ __launch_bounds__(256) void hglob1_k(const float* __restrict__ h,
                                                float* __restrict__ hgp)
{
  const int b = blockIdx.x;
  const int seg = blockIdx.y;
  const int d = threadIdx.x;
  float s = 0.f;
  const int n0 = seg * 120;
  for (int n = n0; n < n0 + 120; ++n)
    s += h[((size_t)(b * N_ + n)) * 256 + d];
  hgp[((size_t)(b * 25 + seg)) * 256 + d] = s;
}

__global__ __launch_bounds__(256) void hglob2_k(const float* __restrict__ hgp,
                                                float* __restrict__ hg)
{
  const int b = blockIdx.x;
  const int d = threadIdx.x;
  float s = 0.f;
  for (int i = 0; i < 25; ++i) s += hgp[((size_t)(b * 25 + i)) * 256 + d];
  hg[b * 256 + d] = s * (1.f / (float)N_);
}

__global__ __launch_bounds__(64) void freq_k(const float* __restrict__ hg,
                                             const float* __restrict__ w1, const float* __restrict__ b1,
                                             const float* __restrict__ w2, const float* __restrict__ b2,
                                             float* __restrict__ outp)
{
  const int b = blockIdx.x;
  const int u = threadIdx.x;
  float a = b1[u];
  for (int k = 0; k < 256; ++k) a += hg[b * 256 + k] * w1[k * 64 + u];
  a = fmaxf(a, 0.f) * w2[u];
  a = wred_(a);
  if (u == 0) outp[(size_t)b * OUTS_ + 45000] = a + b2[0];
}

__global__ void eh2_k(const float* __restrict__ hidden, const float* __restrict__ w2,
                      const float* __restrict__ b2, float* __restrict__ outp)
{
  const int idx = blockIdx.x * blockDim.x + threadIdx.x;
  if (idx >= 2 * B_ * E_) return;
  const int jj = idx / (B_ * E_);
  const int r = idx - jj * (B_ * E_);
  const int b = r / E_, e = r % E_;
  const float* hp = hidden + (size_t)r * 128 + jj * 64;
  const float* wp = w2 + jj * 64;
  float a = 0.f;
  #pragma unroll
  for (int u = 0; u < 64; ++u) a += hp[u] * wp[u];
  a += b2[jj];
  outp[(size_t)b * OUTS_ + 21000 + jj * 12000 + e] = a;
}

// ---------------------------------------------------------------------------
extern "C" void kernel_launch(void* const* d_in, const int* in_sizes, int n_in,
                              void* d_out, int out_size, void* d_ws, size_t ws_size,
                              hipStream_t stream)
{
  const float* env      = (const float*)d_in[0];
  const float* infra    = (const float*)d_in[1];
  const float* robot    = (const float*)d_in[2];
  const float* edgeattr = (const float*)d_in[3];
  const int*   eidx     = (const int*)d_in[4];
  const float* wqkv     = (const float*)d_in[5];
  const float* bqkv     = (const float*)d_in[6];
  const float* wo       = (const float*)d_in[7];
  const float* bo       = (const float*)d_in[8];
  const float* lnf_g    = (const float*)d_in[9];
  const float* lnf_b    = (const float*)d_in[10];
  const float* we_emb   = (const float*)d_in[11];
  const float* be_emb   = (const float*)d_in[12];
  const float* tg_W     = (const float*)d_in[13];
  const float* tg_We    = (const float*)d_in[14];
  const float* tg_asrc  = (const float*)d_in[15];
  const float* tg_adst  = (const float*)d_in[16];
  const float* tg_aedge = (const float*)d_in[17];
  const float* w_ih     = (const float*)d_in[18];
  const float* w_hh     = (const float*)d_in[19];
  const float* b_lstm   = (const float*)d_in[20];
  const float* g_W      = (const float*)d_in[21];
  const float* g_We     = (const float*)d_in[22];
  const float* g_asrc   = (const float*)d_in[23];
  const float* g_adst   = (const float*)d_in[24];
  const float* g_aedge  = (const float*)d_in[25];
  const float* g_lng    = (const float*)d_in[26];
  const float* g_lnb    = (const float*)d_in[27];
  const float* hn_w1    = (const float*)d_in[28];
  const float* hn_b1    = (const float*)d_in[29];
  const float* hn_w2    = (const float*)d_in[30];
  const float* hn_b2    = (const float*)d_in[31];
  const float* he_w1    = (const float*)d_in[32];
  const float* he_b1    = (const float*)d_in[33];
  const float* he_w2    = (const float*)d_in[34];
  const float* he_b2    = (const float*)d_in[35];

  const int* src = eidx;
  const int* dst = eidx + E_;
  float* outp = (float*)d_out;
  float* ws = (float*)d_ws;

  // ---- bf16 transposed weights at ws start (short offsets) ----
  unsigned short* wtb0 = (unsigned short*)ws;
  unsigned short* wt_qkv  = wtb0;               // 196,608
  unsigned short* wt_wo   = wtb0 + 196608;      //  65,536
  unsigned short* wt_tgW  = wtb0 + 262144;      //  65,536
  unsigned short* wt_tgWe = wtb0 + 327680;      //  65,536  (rows 0..255 of edge-cat)
  unsigned short* wt_gWe  = wtb0 + 393216;      // 196,608  (rows 256..1023, contiguous)
  unsigned short* wt_lstm = wtb0 + 589824;      // 524,288  permuted [1024][512]
  unsigned short* wt_gW   = wtb0 + 1114112;     // 196,608
  unsigned short* wt_hn   = wtb0 + 1310720;     // 114,688
  unsigned short* wt_he   = wtb0 + 1425408;     //  65,536

  // ---- dynamic regions (float-unit offsets from D0) ----
  const size_t D0 = 1600000;
  // stage A (4 chunks of 24000 nodes):
  unsigned short* qkvb  = (unsigned short*)(ws + D0);              // 27.648M f (72000x768)
  unsigned short* tmpAb = qkvb;                                    // aliases dead qkvb
  unsigned short* obarb = (unsigned short*)(ws + D0 + 27648000);   // 12.288M f
  unsigned short* fseqb = (unsigned short*)(ws + D0 + 39936000);   // 12.288M f -> 52.224M
  // stage B (qkvb/obarb dead; fseqb live until xwall GEMM):
  unsigned short* xwallb  = (unsigned short*)(ws + D0);            // 12.288M f
  unsigned short* gatallb = (unsigned short*)(ws + D0 + 12288000); // 12.288M f
  unsigned short* eembb   = (unsigned short*)(ws + D0 + 24576000); //  6.144M f
  float* h  = ws + D0 + 30720000;                                  //  3.072M
  float* c  = ws + D0 + 33792000;                                  //  3.072M
  unsigned short* hb0 = (unsigned short*)(ws + D0 + 36864000);     //  1.536M f
  unsigned short* hb1 = (unsigned short*)(ws + D0 + 38400000);     //  1.536M f -> 39.936M
  unsigned short* ewall = (unsigned short*)(ws + D0 + 62976000);   // 24.576M f
  float* elogall = ws + D0 + 87552000;         //  1.536M (4 x 384000)
  float* sal     = ws + D0 + 89088000;         //    768,000
  float* dal     = ws + D0 + 89856000;         //    768,000
  int* ideg  = (int*)(ws + D0 + 90624000);
  int* iroff = ideg + 3008;
  int* ieord = iroff + 3008;
  float* hg  = ws + D0 + 90650000;
  float* hgp = ws + D0 + 90652048;
  // GAT-layers phase (fseqb dead by then):
  unsigned short* xw_sb = (unsigned short*)(ws + D0 + 40000000);   // 1.536M f
  float* gat_s = ws + D0 + 41600000;           //  3.072M
  // heads (xwallb/gatallb dead):
  float* hidn = ws + D0;                       //  5.376M
  float* hide = ws + D0 + 17664000;            //  6.144M

  auto mgemm = [&](const unsigned short* A, const unsigned short* Wt, const float* bias,
                   void* C, int M, int N, int K, int lda, int flags) {
    dim3 grid(N / 64, (M + 127) / 128);
    gemm_bfa_k<<<grid, dim3(256), 0, stream>>>(A, Wt, bias, C, M, N, K, lda, flags);
  };
  auto cvtb = [&](const float* W, unsigned short* Wt, int K, int N, int L) {
    const int total = K * N * L;
    wtb_k<<<(total + 255) / 256, 256, 0, stream>>>(W, Wt, K, N, total);
  };

  // ---- weight convert/transpose/permute ----
  cvtb(wqkv, wt_qkv, 256, 768, 1);
  cvtb(wo, wt_wo, 256, 256, 1);
  cvtb(tg_W, wt_tgW, 256, 256, 1);
  cvtb(tg_We, wt_tgWe, 256, 256, 1);
  cvtb(g_We, wt_gWe, 256, 256, 3);
  wtp_k<<<1024, 256, 0, stream>>>(w_ih, wt_lstm, 0);
  wtp_k<<<1024, 256, 0, stream>>>(w_hh, wt_lstm, 256);
  cvtb(g_W, wt_gW, 256, 256, 3);
  cvtb(hn_w1, wt_hn, 256, 64, 7);
  cvtb(he_w1, wt_he, 512, 64, 2);

  // ---- CSR build (deterministic) ----
  hipMemsetAsync(ideg, 0, 3000 * sizeof(int), stream);
  hist_k<<<(E_ + 255) / 256, 256, 0, stream>>>(dst, ideg);
  scan_k<<<1, 256, 0, stream>>>(ideg, iroff);
  fill_k<<<750, 256, 0, stream>>>(dst, iroff, ieord);

  // ---------------- Stage A: 4 chunks of 24000 nodes ----------------
  for (int chunk = 0; chunk < 4; ++chunk) {
    // 1-D grid: 563 row-panels x 6 col-blocks, XCD-swizzled in-kernel
    gemm_qkv_k<<<563 * 6, 256, 0, stream>>>(env, infra, robot, wt_qkv, bqkv,
                                            qkvb, 72000, chunk * 24000);
    attn_avg_k<<<6000, 256, 0, stream>>>(qkvb, obarb + (size_t)chunk * 24000 * 256, 24000);
  }
  // tmpAb (aliases qkvb, dead) = obar @ wo + bo (bf16), then fseq = LN(tmpAb)
  mgemm(obarb, wt_wo, bo, tmpAb, 96000, 256, 256, 256, 4);
  ln_k<<<96000, 64, 0, stream>>>(tmpAb, lnf_g, lnf_b, fseqb);

  // ---------------- Stage B prep ----------------
  {  // edge_emb = relu(edge_attr @ we_emb + be_emb) -> bf16
    dim3 grid(4, 750);
    gemm_k<<<grid, dim3(256), 0, stream>>>(edgeattr, we_emb, be_emb, eembb,
                                           48000, 256, 8, 8, 2 | 4);
  }
  // one batched edge-transform GEMM: [tgWe | gWe0 | gWe1 | gWe2], N=1024
  mgemm(eembb, wt_tgWe, nullptr, ewall, 48000, 1024, 256, 256, 4);
  elog4_k<<<6000, 256, 0, stream>>>(ewall, tg_aedge, g_aedge, elogall);

  mgemm(fseqb, wt_tgW, nullptr, xwallb, 96000, 256, 256, 256, 4);
  alphas_k<<<3000, 256, 0, stream>>>(xwallb, tg_asrc, tg_adst, sal, dal, 96000);
  gat_k<1><<<24000, 256, 0, stream>>>(xwallb, ewall, sal, dal, elogall, iroff, ieord,
                                      src, gatallb, 96000, 3, 1024, 0);

  // ---------------- LSTM over T (fused GEMM + pointwise) ----------------
  hipMemsetAsync(c, 0, 12288000, stream);
  unsigned short* hbq[2] = { hb0, hb1 };
  for (int t = 0; t < T_; ++t) {
    dim3 grid(16, 94);
    // t=0: h==0, so only the K=256 ih half contributes (exact)
    gemm_lstm_k<<<grid, dim3(256), 0, stream>>>(gatallb, hbq[t & 1], wt_lstm, b_lstm,
                                                h, c, hbq[(t + 1) & 1], t,
                                                t == 0 ? 256 : 512);
  }
  unsigned short* hbf = hbq[0];  // T=8 even -> final h in hb0

  // ---------------- 3 GAT layers with residual LN ----------------
  for (int l = 0; l < 3; ++l) {
    mgemm(hbf, wt_gW + (size_t)l * 65536, nullptr, xw_sb, 12000, 256, 256, 256, 4);
    alphas_k<<<375, 256, 0, stream>>>(xw_sb, g_asrc + l * 256, g_adst + l * 256, sal, dal, 12000);
    gat_k<0><<<3000, 256, 0, stream>>>(xw_sb, ewall, sal, dal, elogall + 384000 * (l + 1),
                                       iroff, ieord, src, gat_s, 12000, 0,
                                       1024, 256 * (l + 1));
    resln_k<<<12000, 64, 0, stream>>>(h, gat_s, g_lng + l * 256, g_lnb + l * 256, hbf);
  }

  // ---------------- Heads ----------------
  mgemm(hbf, wt_hn, hn_b1, hidn, 12000, 448, 256, 256, 2);
  nh2_k<<<(84000 + 255) / 256, 256, 0, stream>>>(hidn, hn_w2, hn_b2, outp);

  hglob1_k<<<dim3(4, 25), 256, 0, stream>>>(h, hgp);
  hglob2_k<<<4, 256, 0, stream>>>(hgp, hg);
  freq_k<<<4, 64, 0, stream>>>(hg, hn_w1 + 7 * 16384, hn_b1 + 7 * 64,
                               hn_w2 + 7 * 64, hn_b2 + 7, outp);

  // edge heads: fused gather GEMM (no ef buffer)
  {
    dim3 grid(2, 375);
    gemm_ef_k<<<grid, dim3(256), 0, stream>>>(hbf, src, dst, wt_he, he_b1, hide);
  }
  eh2_k<<<(96000 + 255) / 256, 256, 0, stream>>>(hide, he_w2, he_b2, outp);
}

// Round 16
// 1456.054 us; speedup vs baseline: 1.2162x; 1.0423x over previous
//
#include <hip/hip_runtime.h>
#include <hip/hip_bf16.h>
#include <math.h>

#define DEV __device__ __forceinline__

namespace {
constexpr int B_ = 4, T_ = 8, N_ = 3000, E_ = 12000;
constexpr int OUTS_ = 45001;  // per-batch output stride: N*7 + E + E + 1
}

using f32x4 = __attribute__((ext_vector_type(4))) float;
using bf16x8 = __attribute__((ext_vector_type(8))) short;

DEV float sigm_(float x) { return 1.0f / (1.0f + expf(-x)); }
DEV float softplus_(float x) { return fmaxf(x, 0.0f) + log1pf(expf(-fabsf(x))); }
DEV float wred_(float v) {
  #pragma unroll
  for (int o = 32; o > 0; o >>= 1) v += __shfl_xor(v, o, 64);
  return v;
}
DEV unsigned short f2bf(float x) {  // RNE fp32->bf16
  unsigned u = __float_as_uint(x);
  return (unsigned short)((u + 0x7FFFu + ((u >> 16) & 1u)) >> 16);
}
DEV unsigned f2bf2(float a, float b) {
  return (unsigned)f2bf(a) | ((unsigned)f2bf(b) << 16);
}
DEV float bfl(unsigned u) { return __uint_as_float(u << 16); }
DEV float bfh(unsigned u) { return __uint_as_float(u & 0xffff0000u); }

// bijective chunked XCD swizzle: hardware block id -> logical tile id so that
// consecutive logical tiles run on the same XCD (L2 panel reuse). nwg%8 safe.
DEV int xcd_swz(int orig, int nwg) {
  const int q = nwg >> 3, rr = nwg & 7;
  const int xcd = orig & 7, pos = orig >> 3;
  return (xcd < rr ? xcd * (q + 1) : rr * (q + 1) + (xcd - rr) * q) + pos;
}

// ---------------------------------------------------------------------------
// Batched weight transpose+convert: L matrices [K][N] -> per-matrix [N][K] bf16
// ---------------------------------------------------------------------------
__global__ void wtb_k(const float* __restrict__ W, unsigned short* __restrict__ Wt,
                      int K, int N, int total)
{
  const int idx = blockIdx.x * blockDim.x + threadIdx.x;
  if (idx >= total) return;
  const int kn = K * N;
  const int l = idx / kn;
  const int r = idx - l * kn;
  const int k = r / N, n = r - k * N;
  Wt[(size_t)l * kn + (size_t)n * K + k] = f2bf(W[idx]);
}

// LSTM weight permute: orig col n = gate*256+d -> newcol = d*4+gate; dense [1024][512]
__global__ void wtp_k(const float* __restrict__ W, unsigned short* __restrict__ Wt,
                      int kOff)
{
  const int idx = blockIdx.x * blockDim.x + threadIdx.x;
  if (idx >= 256 * 1024) return;
  const int k = idx >> 10;
  const int n = idx & 1023;
  const int newcol = (n & 255) * 4 + (n >> 8);
  Wt[(size_t)newcol * 512 + kOff + k] = f2bf(W[idx]);
}

// ---------------------------------------------------------------------------
// CSR build (deterministic)
// ---------------------------------------------------------------------------
__global__ void hist_k(const int* __restrict__ dst, int* __restrict__ deg)
{
  const int e = blockIdx.x * blockDim.x + threadIdx.x;
  if (e < E_) atomicAdd(&deg[dst[e]], 1);
}

__global__ __launch_bounds__(256) void scan_k(const int* __restrict__ deg,
                                              int* __restrict__ roff)
{
  __shared__ int part[256];
  const int t = threadIdx.x;
  int loc[12];
  int s = 0;
  #pragma unroll
  for (int i = 0; i < 12; ++i) {
    const int n = t * 12 + i;
    loc[i] = s;
    s += (n < N_) ? deg[n] : 0;
  }
  part[t] = s;
  __syncthreads();
  if (t == 0) {
    int run = 0;
    for (int i = 0; i < 256; ++i) { const int v = part[i]; part[i] = run; run += v; }
  }
  __syncthreads();
  const int base = part[t];
  #pragma unroll
  for (int i = 0; i < 12; ++i) {
    const int n = t * 12 + i;
    if (n < N_) roff[n] = base + loc[i];
  }
  if (t == 0) roff[N_] = E_;
}

__global__ __launch_bounds__(256) void fill_k(const int* __restrict__ dst,
                                              const int* __restrict__ roff,
                                              int* __restrict__ eord)
{
  const int n = blockIdx.x * 4 + (threadIdx.x >> 6);
  if (n >= N_) return;
  const int lane = threadIdx.x & 63;
  const unsigned long long ltm = (1ull << lane) - 1ull;
  int cnt = roff[n];
  for (int c = 0; c < E_; c += 64) {
    const int e = c + lane;
    const bool m = (e < E_) && (dst[e] == n);
    const unsigned long long mask = __ballot(m);
    if (m) eord[cnt + __popcll(mask & ltm)] = e;
    cnt += __popcll(mask);
  }
}

// ---------------------------------------------------------------------------
// 128x64-tile MFMA bf16 GEMM, 1-D grid + XCD swizzle:
// C[M,N] = A[M,K](bf16) @ Wt(bf16,[N][K]); flags: 1=C+= (fp32), 2=relu, 4=bf16 C.
// ---------------------------------------------------------------------------
__global__ __launch_bounds__(256) void gemm_bfa_k(
    const unsigned short* __restrict__ A, const unsigned short* __restrict__ Wt,
    const float* __restrict__ bias, void* __restrict__ Cv,
    int M, int N, int K, int lda, int flags)
{
  __shared__ unsigned short Al[128 * 40];
  __shared__ unsigned short Bl[64 * 40];
  const int tid = threadIdx.x;
  const int logical = xcd_swz(blockIdx.x, gridDim.x);
  const int nbx = N >> 6;
  const int bm = (logical / nbx) * 128;
  const int bn = (logical % nbx) * 64;
  const int lane = tid & 63;
  const int wv = tid >> 6;
  const int wm = (wv >> 1) * 64;
  const int wn = (wv & 1) * 32;
  const int s_row = tid >> 1;
  const int s_cb = (tid & 1) * 16;
  const int grow = bm + s_row;
  const unsigned short* Arow = (grow < M) ? A + (size_t)grow * lda : nullptr;
  const int b_col = tid >> 2;
  const int b_ks = (tid & 3) * 8;
  const unsigned short* Wrow = Wt + (size_t)(bn + b_col) * K + b_ks;

  f32x4 acc[4][2] = {};
  const int l15 = lane & 15;
  const int lk = (lane >> 4) * 8;

  for (int k0 = 0; k0 < K; k0 += 32) {
    uint4 a0, a1;
    if (Arow) {
      a0 = *(const uint4*)(Arow + k0 + s_cb);
      a1 = *(const uint4*)(Arow + k0 + s_cb + 8);
    } else {
      a0 = make_uint4(0, 0, 0, 0);
      a1 = a0;
    }
    *(uint4*)&Al[s_row * 40 + s_cb] = a0;
    *(uint4*)&Al[s_row * 40 + s_cb + 8] = a1;
    *(uint4*)&Bl[b_col * 40 + b_ks] = *(const uint4*)(Wrow + k0);
    __syncthreads();
    bf16x8 af[4], bfr[2];
    #pragma unroll
    for (int m = 0; m < 4; ++m)
      af[m] = *(const bf16x8*)&Al[(wm + m * 16 + l15) * 40 + lk];
    #pragma unroll
    for (int n = 0; n < 2; ++n)
      bfr[n] = *(const bf16x8*)&Bl[(wn + n * 16 + l15) * 40 + lk];
    #pragma unroll
    for (int m = 0; m < 4; ++m)
      #pragma unroll
      for (int n = 0; n < 2; ++n)
        acc[m][n] = __builtin_amdgcn_mfma_f32_16x16x32_bf16(af[m], bfr[n], acc[m][n], 0, 0, 0);
    __syncthreads();
  }
  float* Cf = (float*)Cv;
  unsigned short* Cb = (unsigned short*)Cv;
  const int r4 = (lane >> 4) * 4;
  #pragma unroll
  for (int m = 0; m < 4; ++m) {
    #pragma unroll
    for (int n = 0; n < 2; ++n) {
      const int col = bn + wn + n * 16 + l15;
      const float bv = bias ? bias[col] : 0.f;
      #pragma unroll
      for (int r = 0; r < 4; ++r) {
        const int row = bm + wm + m * 16 + r4 + r;
        if (row >= M) continue;
        float v = acc[m][n][r] + bv;
        const size_t ci = (size_t)row * N + col;
        if (flags & 1) v += Cf[ci];
        if (flags & 2) v = fmaxf(v, 0.f);
        if (flags & 4) Cb[ci] = f2bf(v);
        else Cf[ci] = v;
      }
    }
  }
}

// ---------------------------------------------------------------------------
// Stage-A qkv GEMM, 128x128 tile (BK=32), 1-D grid + XCD swizzle.
// A rows fp32 from 3 interleaved sources (row r: slot=r%3, node=nodeBase+r/3).
// ---------------------------------------------------------------------------
__global__ __launch_bounds__(256) void gemm_qkv_k(
    const float* __restrict__ env, const float* __restrict__ infra,
    const float* __restrict__ robot, const unsigned short* __restrict__ Wt,
    const float* __restrict__ bias, unsigned short* __restrict__ Cb,
    int M, int nodeBase)
{
  __shared__ unsigned short Al[128 * 40];
  __shared__ unsigned short Bl[128 * 40];
  const int logical = xcd_swz(blockIdx.x, gridDim.x);
  const int bm = (logical / 6) * 128;
  const int bn = (logical % 6) * 128;

  const int tid = threadIdx.x;
  const int lane = tid & 63;
  const int wv = tid >> 6;
  const int wm = (wv >> 1) * 64;
  const int wn = (wv & 1) * 64;
  const int s_row = tid >> 1;
  const int s_cb = (tid & 1) * 16;
  const int grow = bm + s_row;
  const float* Arow = nullptr;
  if (grow < M) {
    const int slot = grow % 3;
    const int node = nodeBase + grow / 3;
    const float* srcp = (slot == 0 ? env : (slot == 1 ? infra : robot));
    Arow = srcp + (size_t)node * 256;
  }

  f32x4 acc[4][4] = {};
  const int l15 = lane & 15;
  const int lk = (lane >> 4) * 8;

  for (int k0 = 0; k0 < 256; k0 += 32) {
    unsigned abuf[8];
    if (Arow) {
      const float* p = Arow + k0 + s_cb;
      #pragma unroll
      for (int i = 0; i < 4; ++i) {
        const float4 v = *(const float4*)(p + i * 4);
        abuf[i * 2 + 0] = f2bf2(v.x, v.y);
        abuf[i * 2 + 1] = f2bf2(v.z, v.w);
      }
    } else {
      #pragma unroll
      for (int i = 0; i < 8; ++i) abuf[i] = 0;
    }
    *(uint4*)&Al[s_row * 40 + s_cb] = *(uint4*)&abuf[0];
    *(uint4*)&Al[s_row * 40 + s_cb + 8] = *(uint4*)&abuf[4];
    #pragma unroll
    for (int i = 0; i < 2; ++i) {
      const int task = tid + i * 256;     // 0..511
      const int col = task >> 2;
      const int ks = (task & 3) * 8;
      *(uint4*)&Bl[col * 40 + ks] = *(const uint4*)(Wt + (size_t)(bn + col) * 256 + k0 + ks);
    }
    __syncthreads();
    bf16x8 af[4], bfr[4];
    #pragma unroll
    for (int m = 0; m < 4; ++m)
      af[m] = *(const bf16x8*)&Al[(wm + m * 16 + l15) * 40 + lk];
    #pragma unroll
    for (int n = 0; n < 4; ++n)
      bfr[n] = *(const bf16x8*)&Bl[(wn + n * 16 + l15) * 40 + lk];
    #pragma unroll
    for (int m = 0; m < 4; ++m)
      #pragma unroll
      for (int n = 0; n < 4; ++n)
        acc[m][n] = __builtin_amdgcn_mfma_f32_16x16x32_bf16(af[m], bfr[n], acc[m][n], 0, 0, 0);
    __syncthreads();
  }
  const int r4 = (lane >> 4) * 4;
  #pragma unroll
  for (int m = 0; m < 4; ++m) {
    #pragma unroll
    for (int n = 0; n < 4; ++n) {
      const int col = bn + wn + n * 16 + l15;
      const float bv = bias[col];
      #pragma unroll
      for (int r = 0; r < 4; ++r) {
        const int row = bm + wm + m * 16 + r4 + r;
        if (row >= M) continue;
        Cb[(size_t)row * 768 + col] = f2bf(acc[m][n][r] + bv);
      }
    }
  }
}

// ---------------------------------------------------------------------------
// Fused LSTM step (1-D grid + XCD swizzle, nbx=16): gates = [gat_t|h] @ Wt_perm
// (kEnd=512; 256 at t=0), newcol = d*4+gate; LSTM pointwise in epilogue.
// Writes c, h (fp32), hbOut. hbIn/hbOut MUST differ (cross-block race).
// ---------------------------------------------------------------------------
__global__ __launch_bounds__(256) void gemm_lstm_k(
    const unsigned short* __restrict__ gatall, const unsigned short* __restrict__ hbIn,
    const unsigned short* __restrict__ Wt, const float* __restrict__ b_lstm,
    float* __restrict__ h, float* __restrict__ c, unsigned short* __restrict__ hbOut,
    int t, int kEnd)
{
  __shared__ float Gl[128][65];
  unsigned short* Al = (unsigned short*)&Gl[0][0];
  unsigned short* Bl = Al + 128 * 40;
  const int tid = threadIdx.x;
  const int logical = xcd_swz(blockIdx.x, gridDim.x);
  const int bm = (logical / 16) * 128;
  const int bn = (logical % 16) * 64;
  const int lane = tid & 63;
  const int wv = tid >> 6;
  const int wm = (wv >> 1) * 64;
  const int wn = (wv & 1) * 32;
  const int s_row = tid >> 1;
  const int s_cb = (tid & 1) * 16;
  const int grow = bm + s_row;
  const unsigned short* Arow1 = nullptr;
  const unsigned short* Arow2 = nullptr;
  if (grow < 12000) {
    const int phys = (grow / N_) * (T_ * N_) + t * N_ + (grow % N_);
    Arow1 = gatall + (size_t)phys * 256;
    Arow2 = hbIn + (size_t)grow * 256;
  }
  const int b_col = tid >> 2;
  const int b_ks = (tid & 3) * 8;
  const unsigned short* Wrow = Wt + (size_t)(bn + b_col) * 512 + b_ks;

  f32x4 acc[4][2] = {};
  const int l15 = lane & 15;
  const int lk = (lane >> 4) * 8;

  for (int k0 = 0; k0 < kEnd; k0 += 32) {
    uint4 a0, a1;
    if (Arow1) {
      const unsigned short* p = (k0 < 256) ? (Arow1 + k0 + s_cb)
                                           : (Arow2 + (k0 - 256) + s_cb);
      a0 = *(const uint4*)p;
      a1 = *(const uint4*)(p + 8);
    } else {
      a0 = make_uint4(0, 0, 0, 0);
      a1 = a0;
    }
    *(uint4*)&Al[s_row * 40 + s_cb] = a0;
    *(uint4*)&Al[s_row * 40 + s_cb + 8] = a1;
    *(uint4*)&Bl[b_col * 40 + b_ks] = *(const uint4*)(Wrow + k0);
    __syncthreads();
    bf16x8 af[4], bfr[2];
    #pragma unroll
    for (int m = 0; m < 4; ++m)
      af[m] = *(const bf16x8*)&Al[(wm + m * 16 + l15) * 40 + lk];
    #pragma unroll
    for (int n = 0; n < 2; ++n)
      bfr[n] = *(const bf16x8*)&Bl[(wn + n * 16 + l15) * 40 + lk];
    #pragma unroll
    for (int m = 0; m < 4; ++m)
      #pragma unroll
      for (int n = 0; n < 2; ++n)
        acc[m][n] = __builtin_amdgcn_mfma_f32_16x16x32_bf16(af[m], bfr[n], acc[m][n], 0, 0, 0);
    __syncthreads();
  }
  const int r4 = (lane >> 4) * 4;
  #pragma unroll
  for (int m = 0; m < 4; ++m)
    #pragma unroll
    for (int n = 0; n < 2; ++n) {
      const int col = wn + n * 16 + l15;
      #pragma unroll
      for (int r = 0; r < 4; ++r)
        Gl[wm + m * 16 + r4 + r][col] = acc[m][n][r];
    }
  __syncthreads();
  const int fl = lane & 7;
  const int rg = lane >> 3;
  const int dg = ((bn + wn) >> 2) + fl;
  const float bi = b_lstm[dg];
  const float bff = b_lstm[256 + dg];
  const float bg = b_lstm[512 + dg];
  const float bo = b_lstm[768 + dg];
  const int colb = wn + fl * 4;
  #pragma unroll
  for (int i = 0; i < 8; ++i) {
    const int rl = rg + i * 8;
    const int row = bm + wm + rl;
    if (row >= 12000) continue;
    const float g0 = Gl[wm + rl][colb + 0] + bi;
    const float g1 = Gl[wm + rl][colb + 1] + bff;
    const float g2 = Gl[wm + rl][colb + 2] + bg;
    const float g3 = Gl[wm + rl][colb + 3] + bo;
    const size_t idx = (size_t)row * 256 + dg;
    const float cn = sigm_(g1) * c[idx] + sigm_(g0) * tanhf(g2);
    c[idx] = cn;
    const float hn = sigm_(g3) * tanhf(cn);
    h[idx] = hn;
    hbOut[idx] = f2bf(hn);
  }
}

// ---------------------------------------------------------------------------
// Edge-head GEMM with fused ef gather (1-D grid + XCD swizzle, nbx=2):
// A row r = concat(hb[b,src[e]], hb[b,dst[e]]). K=512, N=128, relu, fp32 out.
// ---------------------------------------------------------------------------
__global__ __launch_bounds__(256) void gemm_ef_k(
    const unsigned short* __restrict__ hb, const int* __restrict__ srcA,
    const int* __restrict__ dstA, const unsigned short* __restrict__ Wt,
    const float* __restrict__ bias, float* __restrict__ Cf)
{
  __shared__ unsigned short Al[128 * 40];
  __shared__ unsigned short Bl[64 * 40];
  const int tid = threadIdx.x;
  const int logical = xcd_swz(blockIdx.x, gridDim.x);
  const int bm = (logical >> 1) * 128;
  const int bn = (logical & 1) * 64;
  const int lane = tid & 63;
  const int wv = tid >> 6;
  const int wm = (wv >> 1) * 64;
  const int wn = (wv & 1) * 32;
  const int s_row = tid >> 1;
  const int s_cb = (tid & 1) * 16;
  const int grow = bm + s_row;
  const unsigned short* Arow1 = nullptr;
  const unsigned short* Arow2 = nullptr;
  if (grow < 48000) {
    const int b = grow / E_;
    const int e = grow - b * E_;
    Arow1 = hb + ((size_t)(b * N_ + srcA[e])) * 256;
    Arow2 = hb + ((size_t)(b * N_ + dstA[e])) * 256;
  }
  const int b_col = tid >> 2;
  const int b_ks = (tid & 3) * 8;
  const unsigned short* Wrow = Wt + (size_t)(bn + b_col) * 512 + b_ks;

  f32x4 acc[4][2] = {};
  const int l15 = lane & 15;
  const int lk = (lane >> 4) * 8;

  for (int k0 = 0; k0 < 512; k0 += 32) {
    uint4 a0, a1;
    if (Arow1) {
      const unsigned short* p = (k0 < 256) ? (Arow1 + k0 + s_cb)
                                           : (Arow2 + (k0 - 256) + s_cb);
      a0 = *(const uint4*)p;
      a1 = *(const uint4*)(p + 8);
    } else {
      a0 = make_uint4(0, 0, 0, 0);
      a1 = a0;
    }
    *(uint4*)&Al[s_row * 40 + s_cb] = a0;
    *(uint4*)&Al[s_row * 40 + s_cb + 8] = a1;
    *(uint4*)&Bl[b_col * 40 + b_ks] = *(const uint4*)(Wrow + k0);
    __syncthreads();
    bf16x8 af[4], bfr[2];
    #pragma unroll
    for (int m = 0; m < 4; ++m)
      af[m] = *(const bf16x8*)&Al[(wm + m * 16 + l15) * 40 + lk];
    #pragma unroll
    for (int n = 0; n < 2; ++n)
      bfr[n] = *(const bf16x8*)&Bl[(wn + n * 16 + l15) * 40 + lk];
    #pragma unroll
    for (int m = 0; m < 4; ++m)
      #pragma unroll
      for (int n = 0; n < 2; ++n)
        acc[m][n] = __builtin_amdgcn_mfma_f32_16x16x32_bf16(af[m], bfr[n], acc[m][n], 0, 0, 0);
    __syncthreads();
  }
  const int r4 = (lane >> 4) * 4;
  #pragma unroll
  for (int m = 0; m < 4; ++m) {
    #pragma unroll
    for (int n = 0; n < 2; ++n) {
      const int col = bn + wn + n * 16 + l15;
      const float bv = bias[col];
      #pragma unroll
      for (int r = 0; r < 4; ++r) {
        const int row = bm + wm + m * 16 + r4 + r;
        if (row >= 48000) continue;
        Cf[(size_t)row * 128 + col] = fmaxf(acc[m][n][r] + bv, 0.f);
      }
    }
  }
}

// ---------------------------------------------------------------------------
// fp32 fallback GEMM (only the K=8 edge-emb GEMM); flags&4 -> bf16 C store
// ---------------------------------------------------------------------------
__global__ __launch_bounds__(256) void gemm_k(
    const float* __restrict__ A, const float* __restrict__ W,
    const float* __restrict__ bias, void* __restrict__ Cv,
    int M, int N, int K, int lda, int flags)
{
  __shared__ float As[16][68];
  __shared__ float Ws[16][64];
  const int tid = threadIdx.x;
  const int bm = blockIdx.y * 64;
  const int bn = blockIdx.x * 64;
  const int tx = tid & 15;
  const int ty = tid >> 4;
  const int ar = tid >> 2;
  const int ac = (tid & 3) << 2;
  const int wr = tid >> 4;
  const int wc = (tid & 15) << 2;
  const int grow = bm + ar;
  const float* Arow = (grow < M) ? A + (size_t)grow * lda : nullptr;
  float acc[4][4] = {};
  for (int k0 = 0; k0 < K; k0 += 16) {
    float4 av = make_float4(0.f, 0.f, 0.f, 0.f);
    if (Arow) {
      av.x = (k0 + ac + 0 < K) ? Arow[k0 + ac + 0] : 0.f;
      av.y = (k0 + ac + 1 < K) ? Arow[k0 + ac + 1] : 0.f;
      av.z = (k0 + ac + 2 < K) ? Arow[k0 + ac + 2] : 0.f;
      av.w = (k0 + ac + 3 < K) ? Arow[k0 + ac + 3] : 0.f;
    }
    As[ac + 0][ar] = av.x;
    As[ac + 1][ar] = av.y;
    As[ac + 2][ar] = av.z;
    As[ac + 3][ar] = av.w;
    float4 wv = make_float4(0.f, 0.f, 0.f, 0.f);
    if (k0 + wr < K) {
      const int gc = bn + wc;
      const float* wp = W + (size_t)(k0 + wr) * N + gc;
      wv.x = (gc + 0 < N) ? wp[0] : 0.f;
      wv.y = (gc + 1 < N) ? wp[1] : 0.f;
      wv.z = (gc + 2 < N) ? wp[2] : 0.f;
      wv.w = (gc + 3 < N) ? wp[3] : 0.f;
    }
    *(float4*)&Ws[wr][wc] = wv;
    __syncthreads();
    #pragma unroll
    for (int kk = 0; kk < 16; ++kk) {
      const float4 a = *(const float4*)&As[kk][ty << 2];
      const float4 b = *(const float4*)&Ws[kk][tx << 2];
      acc[0][0] += a.x * b.x; acc[0][1] += a.x * b.y; acc[0][2] += a.x * b.z; acc[0][3] += a.x * b.w;
      acc[1][0] += a.y * b.x; acc[1][1] += a.y * b.y; acc[1][2] += a.y * b.z; acc[1][3] += a.y * b.w;
      acc[2][0] += a.z * b.x; acc[2][1] += a.z * b.y; acc[2][2] += a.z * b.z; acc[2][3] += a.z * b.w;
      acc[3][0] += a.w * b.x; acc[3][1] += a.w * b.y; acc[3][2] += a.w * b.z; acc[3][3] += a.w * b.w;
    }
    __syncthreads();
  }
  float* Cf = (float*)Cv;
  unsigned short* Cb = (unsigned short*)Cv;
  #pragma unroll
  for (int i = 0; i < 4; ++i) {
    const int row = bm + (ty << 2) + i;
    if (row >= M) continue;
    #pragma unroll
    for (int j = 0; j < 4; ++j) {
      const int col = bn + (tx << 2) + j;
      if (col >= N) continue;
      float v = acc[i][j];
      if (bias) v += bias[col];
      if (flags & 2) v = fmaxf(v, 0.f);
      const size_t ci = (size_t)row * N + col;
      if (flags & 4) Cb[ci] = f2bf(v);
      else Cf[ci] = v;
    }
  }
}

// ---------------------------------------------------------------------------
// Stage A attention: ONE WAVE PER NODE (coalesced). Lane l -> head l>>3,
// elems (l&7)*4; qkv offset = node*2304 + 4*l. 9 dots reduce over the 8-lane
// subgroup via shfl_xor(1,2,4). 4 waves/block.
// ---------------------------------------------------------------------------
__global__ __launch_bounds__(256) void attn_avg_k(
    const unsigned short* __restrict__ qkv,
    unsigned short* __restrict__ obar, int nodes)
{
  const int node = blockIdx.x * 4 + (threadIdx.x >> 6);
  if (node >= nodes) return;
  const int lane = threadIdx.x & 63;
  const unsigned short* base = qkv + (size_t)node * 2304 + lane * 4;
  float qv[3][4], kv[3][4], vv[3][4];
  #pragma unroll
  for (int s = 0; s < 3; ++s) {
    const uint2 uq = *(const uint2*)(base + s * 768);
    const uint2 uk = *(const uint2*)(base + s * 768 + 256);
    const uint2 uv = *(const uint2*)(base + s * 768 + 512);
    qv[s][0] = bfl(uq.x); qv[s][1] = bfh(uq.x); qv[s][2] = bfl(uq.y); qv[s][3] = bfh(uq.y);
    kv[s][0] = bfl(uk.x); kv[s][1] = bfh(uk.x); kv[s][2] = bfl(uk.y); kv[s][3] = bfh(uk.y);
    vv[s][0] = bfl(uv.x); vv[s][1] = bfh(uv.x); vv[s][2] = bfl(uv.y); vv[s][3] = bfh(uv.y);
  }
  float att[3][3];
  #pragma unroll
  for (int s = 0; s < 3; ++s) {
    #pragma unroll
    for (int t = 0; t < 3; ++t) {
      float d = qv[s][0] * kv[t][0] + qv[s][1] * kv[t][1]
              + qv[s][2] * kv[t][2] + qv[s][3] * kv[t][3];
      d += __shfl_xor(d, 1, 64);
      d += __shfl_xor(d, 2, 64);
      d += __shfl_xor(d, 4, 64);
      att[s][t] = d * 0.17677669529663687f;
    }
  }
  float cs[3] = {0.f, 0.f, 0.f};
  #pragma unroll
  for (int s = 0; s < 3; ++s) {
    const float m = fmaxf(att[s][0], fmaxf(att[s][1], att[s][2]));
    const float e0 = expf(att[s][0] - m);
    const float e1 = expf(att[s][1] - m);
    const float e2 = expf(att[s][2] - m);
    const float inv = (1.f / 3.f) / (e0 + e1 + e2);
    cs[0] += e0 * inv; cs[1] += e1 * inv; cs[2] += e2 * inv;
  }
  float o0 = cs[0] * vv[0][0] + cs[1] * vv[1][0] + cs[2] * vv[2][0];
  float o1 = cs[0] * vv[0][1] + cs[1] * vv[1][1] + cs[2] * vv[2][1];
  float o2 = cs[0] * vv[0][2] + cs[1] * vv[1][2] + cs[2] * vv[2][2];
  float o3 = cs[0] * vv[0][3] + cs[1] * vv[1][3] + cs[2] * vv[2][3];
  uint2 ob;
  ob.x = f2bf2(o0, o1);
  ob.y = f2bf2(o2, o3);
  *(uint2*)(obar + (size_t)node * 256 + lane * 4) = ob;
}

// LayerNorm per row; bf16 in, bf16 out. 1 wave per row.
__global__ __launch_bounds__(64) void ln_k(
    const unsigned short* __restrict__ in, const float* __restrict__ g,
    const float* __restrict__ bta, unsigned short* __restrict__ outp)
{
  const int row = blockIdx.x;
  const int d0 = threadIdx.x << 2;
  const uint2 a = *(const uint2*)(in + (size_t)row * 256 + d0);
  float x[4] = { bfl(a.x), bfh(a.x), bfl(a.y), bfh(a.y) };
  float s = x[0] + x[1] + x[2] + x[3];
  s = wred_(s);
  const float mean = s * (1.f / 256.f);
  float vs = 0.f;
  #pragma unroll
  for (int i = 0; i < 4; ++i) { const float dd = x[i] - mean; vs += dd * dd; }
  vs = wred_(vs);
  const float inv = 1.0f / sqrtf(vs * (1.f / 256.f) + 1e-5f);
  const float4 gv = *(const float4*)(g + d0);
  const float4 bv = *(const float4*)(bta + d0);
  uint2 o;
  o.x = f2bf2((x[0] - mean) * inv * gv.x + bv.x, (x[1] - mean) * inv * gv.y + bv.y);
  o.y = f2bf2((x[2] - mean) * inv * gv.z + bv.z, (x[3] - mean) * inv * gv.w + bv.w);
  *(uint2*)(outp + (size_t)row * 256 + d0) = o;
}

// ---------------------------------------------------------------------------
// GAT kernels (bf16 feature inputs)
// ---------------------------------------------------------------------------
__global__ void alphas_k(const unsigned short* __restrict__ xw, const float* __restrict__ as,
                         const float* __restrict__ ad, float* __restrict__ sal,
                         float* __restrict__ dal, int rows)
{
  const int idx = blockIdx.x * blockDim.x + threadIdx.x;
  if (idx >= rows * 8) return;
  const int row = idx >> 3, h = idx & 7;
  const unsigned short* x = xw + (size_t)row * 256 + h * 32;
  const float* a1 = as + h * 32;
  const float* a2 = ad + h * 32;
  float s = 0.f, d = 0.f;
  #pragma unroll
  for (int i = 0; i < 4; ++i) {
    const uint4 ux = *(const uint4*)(x + i * 8);
    const unsigned* p = &ux.x;
    #pragma unroll
    for (int j = 0; j < 4; ++j) {
      const float lo = bfl(p[j]), hi = bfh(p[j]);
      s += lo * a1[i * 8 + 2 * j] + hi * a1[i * 8 + 2 * j + 1];
      d += lo * a2[i * 8 + 2 * j] + hi * a2[i * 8 + 2 * j + 1];
    }
  }
  sal[idx] = s; dal[idx] = d;
}

// all 4 edge-logit sets in one launch; ew is [48000][1024] (4 x 256 packed)
__global__ void elog4_k(const unsigned short* __restrict__ ew,
                        const float* __restrict__ tg_ae, const float* __restrict__ g_ae,
                        float* __restrict__ el)
{
  const int idx = blockIdx.x * blockDim.x + threadIdx.x;
  if (idx >= 4 * 48000 * 8) return;
  const int l = idx / (48000 * 8);
  const int r = idx - l * (48000 * 8);
  const int row = r >> 3, h = r & 7;
  const unsigned short* x = ew + (size_t)row * 1024 + l * 256 + h * 32;
  const float* a1 = (l == 0 ? tg_ae : g_ae + (l - 1) * 256) + h * 32;
  float s = 0.f;
  #pragma unroll
  for (int i = 0; i < 4; ++i) {
    const uint4 ux = *(const uint4*)(x + i * 8);
    const unsigned* p = &ux.x;
    #pragma unroll
    for (int j = 0; j < 4; ++j) {
      s += bfl(p[j]) * a1[i * 8 + 2 * j] + bfh(p[j]) * a1[i * 8 + 2 * j + 1];
    }
  }
  el[l * 384000 + r] = s;
}

// Fused GAT aggregation: one wave per (beta,node). Online softmax over incoming
// edges (CSR). bf16 gathers. OUTBF: 1 -> bf16 out, 0 -> fp32 out.
template<int OUTBF>
__global__ __launch_bounds__(256) void gat_k(
    const unsigned short* __restrict__ xw, const unsigned short* __restrict__ ew,
    const float* __restrict__ sal, const float* __restrict__ dal,
    const float* __restrict__ el, const int* __restrict__ roff,
    const int* __restrict__ eord, const int* __restrict__ srcArr,
    void* __restrict__ outp, int nwaves, int tshift, int ewStride, int ewOff)
{
  const int wid = blockIdx.x * 4 + (threadIdx.x >> 6);
  if (wid >= nwaves) return;
  const int beta = wid / N_;
  const int n = wid - beta * N_;
  const int b = beta >> tshift;
  const int lane = threadIdx.x & 63;
  const int h = lane >> 3;
  const int d0 = lane << 2;
  const float dal_h = dal[(size_t)wid * 8 + h];
  const int p0 = roff[n], p1 = roff[n + 1];
  float m = -1e30f, s = 0.f;
  float4 acc = make_float4(0.f, 0.f, 0.f, 0.f);
  for (int p = p0; p < p1; ++p) {
    const int e = eord[p];
    const int sc = srcArr[e];
    float lg = sal[((size_t)beta * N_ + sc) * 8 + h] + dal_h + el[((size_t)b * E_ + e) * 8 + h];
    lg = lg > 0.f ? lg : 0.2f * lg;
    const float mn = fmaxf(m, lg);
    const float scale = expf(m - mn);
    const float w = expf(lg - mn);
    s = s * scale + w;
    const uint2 ux = *(const uint2*)(xw + ((size_t)beta * N_ + sc) * 256 + d0);
    const uint2 ue = *(const uint2*)(ew + ((size_t)(b * E_ + e)) * ewStride + ewOff + d0);
    acc.x = acc.x * scale + w * (bfl(ux.x) + bfl(ue.x));
    acc.y = acc.y * scale + w * (bfh(ux.x) + bfh(ue.x));
    acc.z = acc.z * scale + w * (bfl(ux.y) + bfl(ue.y));
    acc.w = acc.w * scale + w * (bfh(ux.y) + bfh(ue.y));
    m = mn;
  }
  const float inv = 1.0f / (s + 1e-16f);
  if (OUTBF) {
    uint2 o;
    o.x = f2bf2(acc.x * inv, acc.y * inv);
    o.y = f2bf2(acc.z * inv, acc.w * inv);
    *(uint2*)((unsigned short*)outp + (size_t)wid * 256 + d0) = o;
  } else {
    *(float4*)((float*)outp + (size_t)wid * 256 + d0) =
        make_float4(acc.x * inv, acc.y * inv, acc.z * inv, acc.w * inv);
  }
}

// h = LN(h + add); writes fp32 h and bf16 hb
__global__ __launch_bounds__(64) void resln_k(float* __restrict__ h,
                                              const float* __restrict__ add,
                                              const float* __restrict__ g,
                                              const float* __restrict__ bta,
                                              unsigned short* __restrict__ hb)
{
  const int row = blockIdx.x;
  const int d0 = threadIdx.x << 2;
  float* hp = h + (size_t)row * 256;
  const float4 hv = *(const float4*)(hp + d0);
  const float4 av = *(const float4*)(add + (size_t)row * 256 + d0);
  float x[4] = { hv.x + av.x, hv.y + av.y, hv.z + av.z, hv.w + av.w };
  float s = x[0] + x[1] + x[2] + x[3];
  s = wred_(s);
  const float mean = s * (1.f / 256.f);
  float vs = 0.f;
  #pragma unroll
  for (int i = 0; i < 4; ++i) { const float dd = x[i] - mean; vs += dd * dd; }
  vs = wred_(vs);
  const float inv = 1.0f / sqrtf(vs * (1.f / 256.f) + 1e-5f);
  const float4 gv = *(const float4*)(g + d0);
  const float4 bv = *(const float4*)(bta + d0);
  float o0 = (x[0] - mean) * inv * gv.x + bv.x;
  float o1 = (x[1] - mean) * inv * gv.y + bv.y;
  float o2 = (x[2] - mean) * inv * gv.z + bv.z;
  float o3 = (x[3] - mean) * inv * gv.w + bv.w;
  *(float4*)(hp + d0) = make_float4(o0, o1, o2, o3);
  uint2 ob;
  ob.x = f2bf2(o0, o1);
  ob.y = f2bf2(o2, o3);
  *(uint2*)(hb + (size_t)row * 256 + d0) = ob;
}

// ---------------------------------------------------------------------------
// Head kernels
// ---------------------------------------------------------------------------
__global__ void nh2_k(const float* __restrict__ hidden, const float* __restrict__ w2,
                      const float* __restrict__ b2, float* __restrict__ outp)
{
  const int idx = blockIdx.x * blockDim.x + threadIdx.x;
  if (idx >= B_ * N_ * 7) return;
  const int row = idx / 7, j = idx % 7;
  const float* hp = hidden + (size_t)row * 448 + j * 64;
  const float* wp = w2 + j * 64;
  float a = 0.f;
  #pragma unroll
  for (int u = 0; u < 64; ++u) a += hp[u] * wp[u];
  a += b2[j];
  if (j == 0 || j == 6) a = sigm_(a);
  else if (j == 1) a = softplus_(a);
  const int b = row / N_, n = row % N_;
  outp[(size_t)b * OUTS_ + n * 7 + j] = a;
}

// two-stage deterministic h_global mean
__global__ __launch_bounds__(256) void hglob1_k(const float* __restrict__ h,
                                                float* __restrict__ hgp)
{
  const int b = blockIdx.x;
  const int seg = blockIdx.y;
  const int d = threadIdx.x;
  float s = 0.f;
  const int n0 = seg * 120;
  for (int n = n0; n < n0 + 120; ++n)
    s += h[((size_t)(b * N_ + n)) * 256 + d];
  hgp[((size_t)(b * 25 + seg)) * 256 + d] = s;
}

__global__ __launch_bounds__(256) void hglob2_k(const float* __restrict__ hgp,
                                                float* __restrict__ hg)
{
  const int b = blockIdx.x;
  const int d = threadIdx.x;
  float s = 0.f;
  for (int i = 0; i < 25; ++i) s += hgp[((size_t)(b * 25 + i)) * 256 + d];
  hg[b * 256 + d] = s * (1.f / (float)N_);
}

__global__ __launch_bounds__(64) void freq_k(const float* __restrict__ hg,
                                             const float* __restrict__ w1, const float* __restrict__ b1,
                                             const float* __restrict__ w2, const float* __restrict__ b2,
                                             float* __restrict__ outp)
{
  const int b = blockIdx.x;
  const int u = threadIdx.x;
  float a = b1[u];
  for (int k = 0; k < 256; ++k) a += hg[b * 256 + k] * w1[k * 64 + u];
  a = fmaxf(a, 0.f) * w2[u];
  a = wred_(a);
  if (u == 0) outp[(size_t)b * OUTS_ + 45000] = a + b2[0];
}

__global__ void eh2_k(const float* __restrict__ hidden, const float* __restrict__ w2,
                      const float* __restrict__ b2, float* __restrict__ outp)
{
  const int idx = blockIdx.x * blockDim.x + threadIdx.x;
  if (idx >= 2 * B_ * E_) return;
  const int jj = idx / (B_ * E_);
  const int r = idx - jj * (B_ * E_);
  const int b = r / E_, e = r % E_;
  const float* hp = hidden + (size_t)r * 128 + jj * 64;
  const float* wp = w2 + jj * 64;
  float a = 0.f;
  #pragma unroll
  for (int u = 0; u < 64; ++u) a += hp[u] * wp[u];
  a += b2[jj];
  outp[(size_t)b * OUTS_ + 21000 + jj * 12000 + e] = a;
}

// ---------------------------------------------------------------------------
extern "C" void kernel_launch(void* const* d_in, const int* in_sizes, int n_in,
                              void* d_out, int out_size, void* d_ws, size_t ws_size,
                              hipStream_t stream)
{
  const float* env      = (const float*)d_in[0];
  const float* infra    = (const float*)d_in[1];
  const float* robot    = (const float*)d_in[2];
  const float* edgeattr = (const float*)d_in[3];
  const int*   eidx     = (const int*)d_in[4];
  const float* wqkv     = (const float*)d_in[5];
  const float* bqkv     = (const float*)d_in[6];
  const float* wo       = (const float*)d_in[7];
  const float* bo       = (const float*)d_in[8];
  const float* lnf_g    = (const float*)d_in[9];
  const float* lnf_b    = (const float*)d_in[10];
  const float* we_emb   = (const float*)d_in[11];
  const float* be_emb   = (const float*)d_in[12];
  const float* tg_W     = (const float*)d_in[13];
  const float* tg_We    = (const float*)d_in[14];
  const float* tg_asrc  = (const float*)d_in[15];
  const float* tg_adst  = (const float*)d_in[16];
  const float* tg_aedge = (const float*)d_in[17];
  const float* w_ih     = (const float*)d_in[18];
  const float* w_hh     = (const float*)d_in[19];
  const float* b_lstm   = (const float*)d_in[20];
  const float* g_W      = (const float*)d_in[21];
  const float* g_We     = (const float*)d_in[22];
  const float* g_asrc   = (const float*)d_in[23];
  const float* g_adst   = (const float*)d_in[24];
  const float* g_aedge  = (const float*)d_in[25];
  const float* g_lng    = (const float*)d_in[26];
  const float* g_lnb    = (const float*)d_in[27];
  const float* hn_w1    = (const float*)d_in[28];
  const float* hn_b1    = (const float*)d_in[29];
  const float* hn_w2    = (const float*)d_in[30];
  const float* hn_b2    = (const float*)d_in[31];
  const float* he_w1    = (const float*)d_in[32];
  const float* he_b1    = (const float*)d_in[33];
  const float* he_w2    = (const float*)d_in[34];
  const float* he_b2    = (const float*)d_in[35];

  const int* src = eidx;
  const int* dst = eidx + E_;
  float* outp = (float*)d_out;
  float* ws = (float*)d_ws;

  // ---- bf16 transposed weights at ws start (short offsets) ----
  unsigned short* wtb0 = (unsigned short*)ws;
  unsigned short* wt_qkv  = wtb0;               // 196,608
  unsigned short* wt_wo   = wtb0 + 196608;      //  65,536
  unsigned short* wt_tgW  = wtb0 + 262144;      //  65,536
  unsigned short* wt_tgWe = wtb0 + 327680;      //  65,536  (rows 0..255 of edge-cat)
  unsigned short* wt_gWe  = wtb0 + 393216;      // 196,608  (rows 256..1023, contiguous)
  unsigned short* wt_lstm = wtb0 + 589824;      // 524,288  permuted [1024][512]
  unsigned short* wt_gW   = wtb0 + 1114112;     // 196,608
  unsigned short* wt_hn   = wtb0 + 1310720;     // 114,688
  unsigned short* wt_he   = wtb0 + 1425408;     //  65,536

  // ---- dynamic regions (float-unit offsets from D0) ----
  const size_t D0 = 1600000;
  // stage A (4 chunks of 24000 nodes):
  unsigned short* qkvb  = (unsigned short*)(ws + D0);              // 27.648M f (72000x768)
  unsigned short* tmpAb = qkvb;                                    // aliases dead qkvb
  unsigned short* obarb = (unsigned short*)(ws + D0 + 27648000);   // 12.288M f
  unsigned short* fseqb = (unsigned short*)(ws + D0 + 39936000);   // 12.288M f -> 52.224M
  // stage B (qkvb/obarb dead; fseqb live until xwall GEMM):
  unsigned short* xwallb  = (unsigned short*)(ws + D0);            // 12.288M f
  unsigned short* gatallb = (unsigned short*)(ws + D0 + 12288000); // 12.288M f
  unsigned short* eembb   = (unsigned short*)(ws + D0 + 24576000); //  6.144M f
  float* h  = ws + D0 + 30720000;                                  //  3.072M
  float* c  = ws + D0 + 33792000;                                  //  3.072M
  unsigned short* hb0 = (unsigned short*)(ws + D0 + 36864000);     //  1.536M f
  unsigned short* hb1 = (unsigned short*)(ws + D0 + 38400000);     //  1.536M f -> 39.936M
  unsigned short* ewall = (unsigned short*)(ws + D0 + 62976000);   // 24.576M f
  float* elogall = ws + D0 + 87552000;         //  1.536M (4 x 384000)
  float* sal     = ws + D0 + 89088000;         //    768,000
  float* dal     = ws + D0 + 89856000;         //    768,000
  int* ideg  = (int*)(ws + D0 + 90624000);
  int* iroff = ideg + 3008;
  int* ieord = iroff + 3008;
  float* hg  = ws + D0 + 90650000;
  float* hgp = ws + D0 + 90652048;
  // GAT-layers phase (fseqb dead by then):
  unsigned short* xw_sb = (unsigned short*)(ws + D0 + 40000000);   // 1.536M f
  float* gat_s = ws + D0 + 41600000;           //  3.072M
  // heads (xwallb/gatallb dead):
  float* hidn = ws + D0;                       //  5.376M
  float* hide = ws + D0 + 17664000;            //  6.144M

  auto mgemm = [&](const unsigned short* A, const unsigned short* Wt, const float* bias,
                   void* C, int M, int N, int K, int lda, int flags) {
    const int nwg = (N / 64) * ((M + 127) / 128);
    gemm_bfa_k<<<nwg, 256, 0, stream>>>(A, Wt, bias, C, M, N, K, lda, flags);
  };
  auto cvtb = [&](const float* W, unsigned short* Wt, int K, int N, int L) {
    const int total = K * N * L;
    wtb_k<<<(total + 255) / 256, 256, 0, stream>>>(W, Wt, K, N, total);
  };

  // ---- weight convert/transpose/permute ----
  cvtb(wqkv, wt_qkv, 256, 768, 1);
  cvtb(wo, wt_wo, 256, 256, 1);
  cvtb(tg_W, wt_tgW, 256, 256, 1);
  cvtb(tg_We, wt_tgWe, 256, 256, 1);
  cvtb(g_We, wt_gWe, 256, 256, 3);
  wtp_k<<<1024, 256, 0, stream>>>(w_ih, wt_lstm, 0);
  wtp_k<<<1024, 256, 0, stream>>>(w_hh, wt_lstm, 256);
  cvtb(g_W, wt_gW, 256, 256, 3);
  cvtb(hn_w1, wt_hn, 256, 64, 7);
  cvtb(he_w1, wt_he, 512, 64, 2);

  // ---- CSR build (deterministic) ----
  hipMemsetAsync(ideg, 0, 3000 * sizeof(int), stream);
  hist_k<<<(E_ + 255) / 256, 256, 0, stream>>>(dst, ideg);
  scan_k<<<1, 256, 0, stream>>>(ideg, iroff);
  fill_k<<<750, 256, 0, stream>>>(dst, iroff, ieord);

  // ---------------- Stage A: 4 chunks of 24000 nodes ----------------
  for (int chunk = 0; chunk < 4; ++chunk) {
    gemm_qkv_k<<<563 * 6, 256, 0, stream>>>(env, infra, robot, wt_qkv, bqkv,
                                            qkvb, 72000, chunk * 24000);
    attn_avg_k<<<6000, 256, 0, stream>>>(qkvb, obarb + (size_t)chunk * 24000 * 256, 24000);
  }
  // tmpAb (aliases qkvb, dead) = obar @ wo + bo (bf16), then fseq = LN(tmpAb)
  mgemm(obarb, wt_wo, bo, tmpAb, 96000, 256, 256, 256, 4);
  ln_k<<<96000, 64, 0, stream>>>(tmpAb, lnf_g, lnf_b, fseqb);

  // ---------------- Stage B prep ----------------
  {  // edge_emb = relu(edge_attr @ we_emb + be_emb) -> bf16
    dim3 grid(4, 750);
    gemm_k<<<grid, dim3(256), 0, stream>>>(edgeattr, we_emb, be_emb, eembb,
                                           48000, 256, 8, 8, 2 | 4);
  }
  // one batched edge-transform GEMM: [tgWe | gWe0 | gWe1 | gWe2], N=1024
  mgemm(eembb, wt_tgWe, nullptr, ewall, 48000, 1024, 256, 256, 4);
  elog4_k<<<6000, 256, 0, stream>>>(ewall, tg_aedge, g_aedge, elogall);

  mgemm(fseqb, wt_tgW, nullptr, xwallb, 96000, 256, 256, 256, 4);
  alphas_k<<<3000, 256, 0, stream>>>(xwallb, tg_asrc, tg_adst, sal, dal, 96000);
  gat_k<1><<<24000, 256, 0, stream>>>(xwallb, ewall, sal, dal, elogall, iroff, ieord,
                                      src, gatallb, 96000, 3, 1024, 0);

  // ---------------- LSTM over T (fused GEMM + pointwise) ----------------
  hipMemsetAsync(c, 0, 12288000, stream);
  unsigned short* hbq[2] = { hb0, hb1 };
  for (int t = 0; t < T_; ++t) {
    // t=0: h==0, so only the K=256 ih half contributes (exact)
    gemm_lstm_k<<<16 * 94, 256, 0, stream>>>(gatallb, hbq[t & 1], wt_lstm, b_lstm,
                                             h, c, hbq[(t + 1) & 1], t,
                                             t == 0 ? 256 : 512);
  }
  unsigned short* hbf = hbq[0];  // T=8 even -> final h in hb0

  // ---------------- 3 GAT layers with residual LN ----------------
  for (int l = 0; l < 3; ++l) {
    mgemm(hbf, wt_gW + (size_t)l * 65536, nullptr, xw_sb, 12000, 256, 256, 256, 4);
    alphas_k<<<375, 256, 0, stream>>>(xw_sb, g_asrc + l * 256, g_adst + l * 256, sal, dal, 12000);
    gat_k<0><<<3000, 256, 0, stream>>>(xw_sb, ewall, sal, dal, elogall + 384000 * (l + 1),
                                       iroff, ieord, src, gat_s, 12000, 0,
                                       1024, 256 * (l + 1));
    resln_k<<<12000, 64, 0, stream>>>(h, gat_s, g_lng + l * 256, g_lnb + l * 256, hbf);
  }

  // ---------------- Heads ----------------
  mgemm(hbf, wt_hn, hn_b1, hidn, 12000, 448, 256, 256, 2);
  nh2_k<<<(84000 + 255) / 256, 256, 0, stream>>>(hidn, hn_w2, hn_b2, outp);

  hglob1_k<<<dim3(4, 25), 256, 0, stream>>>(h, hgp);
  hglob2_k<<<4, 256, 0, stream>>>(hgp, hg);
  freq_k<<<4, 64, 0, stream>>>(hg, hn_w1 + 7 * 16384, hn_b1 + 7 * 64,
                               hn_w2 + 7 * 64, hn_b2 + 7, outp);

  // edge heads: fused gather GEMM (no ef buffer)
  gemm_ef_k<<<750, 256, 0, stream>>>(hbf, src, dst, wt_he, he_b1, hide);
  eh2_k<<<(96000 + 255) / 256, 256, 0, stream>>>(hide, he_w2, he_b2, outp);
}

// Round 17
// 1430.706 us; speedup vs baseline: 1.2378x; 1.0177x over previous
//
#include <hip/hip_runtime.h>
#include <hip/hip_bf16.h>
#include <math.h>

#define DEV __device__ __forceinline__

namespace {
constexpr int B_ = 4, T_ = 8, N_ = 3000, E_ = 12000;
constexpr int OUTS_ = 45001;  // per-batch output stride: N*7 + E + E + 1
}

using f32x4 = __attribute__((ext_vector_type(4))) float;
using bf16x8 = __attribute__((ext_vector_type(8))) short;

DEV float sigm_(float x) { return 1.0f / (1.0f + expf(-x)); }
DEV float softplus_(float x) { return fmaxf(x, 0.0f) + log1pf(expf(-fabsf(x))); }
DEV float wred_(float v) {
  #pragma unroll
  for (int o = 32; o > 0; o >>= 1) v += __shfl_xor(v, o, 64);
  return v;
}
DEV unsigned short f2bf(float x) {  // RNE fp32->bf16
  unsigned u = __float_as_uint(x);
  return (unsigned short)((u + 0x7FFFu + ((u >> 16) & 1u)) >> 16);
}
DEV unsigned f2bf2(float a, float b) {
  return (unsigned)f2bf(a) | ((unsigned)f2bf(b) << 16);
}
DEV float bfl(unsigned u) { return __uint_as_float(u << 16); }
DEV float bfh(unsigned u) { return __uint_as_float(u & 0xffff0000u); }

// bijective chunked XCD swizzle: hardware block id -> logical tile id so that
// consecutive logical tiles run on the same XCD (L2 panel reuse). nwg%8 safe.
DEV int xcd_swz(int orig, int nwg) {
  const int q = nwg >> 3, rr = nwg & 7;
  const int xcd = orig & 7, pos = orig >> 3;
  return (xcd < rr ? xcd * (q + 1) : rr * (q + 1) + (xcd - rr) * q) + pos;
}

// ---------------------------------------------------------------------------
// ONE weight-prep kernel: all transposes/converts/permutes in a single launch.
// Segment boundaries == packed dst offsets in the bf16 weight arena.
// ---------------------------------------------------------------------------
__global__ void wtall_k(const float* __restrict__ wqkv, const float* __restrict__ wo,
                        const float* __restrict__ tgW, const float* __restrict__ tgWe,
                        const float* __restrict__ gWe, const float* __restrict__ w_ih,
                        const float* __restrict__ w_hh, const float* __restrict__ gW,
                        const float* __restrict__ hn_w1, const float* __restrict__ he_w1,
                        unsigned short* __restrict__ Wt)
{
  const int idx = blockIdx.x * blockDim.x + threadIdx.x;
  if (idx >= 1490944) return;
  const float* src;
  int local, K, N, dst;
  int lstmOff = -1;
  if (idx < 196608)      { src = wqkv;  local = idx;            K = 256; N = 768; dst = 0; }
  else if (idx < 262144) { src = wo;    local = idx - 196608;   K = 256; N = 256; dst = 196608; }
  else if (idx < 327680) { src = tgW;   local = idx - 262144;   K = 256; N = 256; dst = 262144; }
  else if (idx < 393216) { src = tgWe;  local = idx - 327680;   K = 256; N = 256; dst = 327680; }
  else if (idx < 589824) { src = gWe;   local = idx - 393216;   K = 256; N = 256; dst = 393216; }
  else if (idx < 851968) { src = w_ih;  local = idx - 589824;   lstmOff = 0; }
  else if (idx < 1114112){ src = w_hh;  local = idx - 851968;   lstmOff = 256; }
  else if (idx < 1310720){ src = gW;    local = idx - 1114112;  K = 256; N = 256; dst = 1114112; }
  else if (idx < 1425408){ src = hn_w1; local = idx - 1310720;  K = 256; N = 64;  dst = 1310720; }
  else                   { src = he_w1; local = idx - 1425408;  K = 512; N = 64;  dst = 1425408; }
  if (lstmOff >= 0) {
    // LSTM permute: src is [256][1024]; col n=gate*256+d -> newcol=d*4+gate
    const int k = local >> 10;
    const int n = local & 1023;
    const int newcol = (n & 255) * 4 + (n >> 8);
    Wt[589824 + (size_t)newcol * 512 + lstmOff + k] = f2bf(src[local]);
  } else {
    const int kn = K * N;
    const int l = local / kn;
    const int r = local - l * kn;
    const int k = r / N, n = r - k * N;
    Wt[dst + (size_t)l * kn + (size_t)n * K + k] = f2bf(src[local]);
  }
}

// ---------------------------------------------------------------------------
// CSR build (deterministic)
// ---------------------------------------------------------------------------
__global__ void hist_k(const int* __restrict__ dst, int* __restrict__ deg)
{
  const int e = blockIdx.x * blockDim.x + threadIdx.x;
  if (e < E_) atomicAdd(&deg[dst[e]], 1);
}

__global__ __launch_bounds__(256) void scan_k(const int* __restrict__ deg,
                                              int* __restrict__ roff)
{
  __shared__ int part[256];
  const int t = threadIdx.x;
  int loc[12];
  int s = 0;
  #pragma unroll
  for (int i = 0; i < 12; ++i) {
    const int n = t * 12 + i;
    loc[i] = s;
    s += (n < N_) ? deg[n] : 0;
  }
  part[t] = s;
  __syncthreads();
  if (t == 0) {
    int run = 0;
    for (int i = 0; i < 256; ++i) { const int v = part[i]; part[i] = run; run += v; }
  }
  __syncthreads();
  const int base = part[t];
  #pragma unroll
  for (int i = 0; i < 12; ++i) {
    const int n = t * 12 + i;
    if (n < N_) roff[n] = base + loc[i];
  }
  if (t == 0) roff[N_] = E_;
}

__global__ __launch_bounds__(256) void fill_k(const int* __restrict__ dst,
                                              const int* __restrict__ roff,
                                              int* __restrict__ eord)
{
  const int n = blockIdx.x * 4 + (threadIdx.x >> 6);
  if (n >= N_) return;
  const int lane = threadIdx.x & 63;
  const unsigned long long ltm = (1ull << lane) - 1ull;
  int cnt = roff[n];
  for (int c = 0; c < E_; c += 64) {
    const int e = c + lane;
    const bool m = (e < E_) && (dst[e] == n);
    const unsigned long long mask = __ballot(m);
    if (m) eord[cnt + __popcll(mask & ltm)] = e;
    cnt += __popcll(mask);
  }
}

// ---------------------------------------------------------------------------
// 128x64-tile MFMA bf16 GEMM, 1-D grid + XCD swizzle:
// C[M,N] = A[M,K](bf16) @ Wt(bf16,[N][K]); flags: 1=C+= (fp32), 2=relu, 4=bf16 C.
// ---------------------------------------------------------------------------
__global__ __launch_bounds__(256) void gemm_bfa_k(
    const unsigned short* __restrict__ A, const unsigned short* __restrict__ Wt,
    const float* __restrict__ bias, void* __restrict__ Cv,
    int M, int N, int K, int lda, int flags)
{
  __shared__ unsigned short Al[128 * 40];
  __shared__ unsigned short Bl[64 * 40];
  const int tid = threadIdx.x;
  const int logical = xcd_swz(blockIdx.x, gridDim.x);
  const int nbx = N >> 6;
  const int bm = (logical / nbx) * 128;
  const int bn = (logical % nbx) * 64;
  const int lane = tid & 63;
  const int wv = tid >> 6;
  const int wm = (wv >> 1) * 64;
  const int wn = (wv & 1) * 32;
  const int s_row = tid >> 1;
  const int s_cb = (tid & 1) * 16;
  const int grow = bm + s_row;
  const unsigned short* Arow = (grow < M) ? A + (size_t)grow * lda : nullptr;
  const int b_col = tid >> 2;
  const int b_ks = (tid & 3) * 8;
  const unsigned short* Wrow = Wt + (size_t)(bn + b_col) * K + b_ks;

  f32x4 acc[4][2] = {};
  const int l15 = lane & 15;
  const int lk = (lane >> 4) * 8;

  for (int k0 = 0; k0 < K; k0 += 32) {
    uint4 a0, a1;
    if (Arow) {
      a0 = *(const uint4*)(Arow + k0 + s_cb);
      a1 = *(const uint4*)(Arow + k0 + s_cb + 8);
    } else {
      a0 = make_uint4(0, 0, 0, 0);
      a1 = a0;
    }
    *(uint4*)&Al[s_row * 40 + s_cb] = a0;
    *(uint4*)&Al[s_row * 40 + s_cb + 8] = a1;
    *(uint4*)&Bl[b_col * 40 + b_ks] = *(const uint4*)(Wrow + k0);
    __syncthreads();
    bf16x8 af[4], bfr[2];
    #pragma unroll
    for (int m = 0; m < 4; ++m)
      af[m] = *(const bf16x8*)&Al[(wm + m * 16 + l15) * 40 + lk];
    #pragma unroll
    for (int n = 0; n < 2; ++n)
      bfr[n] = *(const bf16x8*)&Bl[(wn + n * 16 + l15) * 40 + lk];
    #pragma unroll
    for (int m = 0; m < 4; ++m)
      #pragma unroll
      for (int n = 0; n < 2; ++n)
        acc[m][n] = __builtin_amdgcn_mfma_f32_16x16x32_bf16(af[m], bfr[n], acc[m][n], 0, 0, 0);
    __syncthreads();
  }
  float* Cf = (float*)Cv;
  unsigned short* Cb = (unsigned short*)Cv;
  const int r4 = (lane >> 4) * 4;
  #pragma unroll
  for (int m = 0; m < 4; ++m) {
    #pragma unroll
    for (int n = 0; n < 2; ++n) {
      const int col = bn + wn + n * 16 + l15;
      const float bv = bias ? bias[col] : 0.f;
      #pragma unroll
      for (int r = 0; r < 4; ++r) {
        const int row = bm + wm + m * 16 + r4 + r;
        if (row >= M) continue;
        float v = acc[m][n][r] + bv;
        const size_t ci = (size_t)row * N + col;
        if (flags & 1) v += Cf[ci];
        if (flags & 2) v = fmaxf(v, 0.f);
        if (flags & 4) Cb[ci] = f2bf(v);
        else Cf[ci] = v;
      }
    }
  }
}

// ---------------------------------------------------------------------------
// Stage-A qkv GEMM, 128x128 tile (BK=32), 1-D grid + XCD swizzle.
// A rows fp32 from 3 interleaved sources (row r: slot=r%3, node=nodeBase+r/3).
// ---------------------------------------------------------------------------
__global__ __launch_bounds__(256) void gemm_qkv_k(
    const float* __restrict__ env, const float* __restrict__ infra,
    const float* __restrict__ robot, const unsigned short* __restrict__ Wt,
    const float* __restrict__ bias, unsigned short* __restrict__ Cb,
    int M, int nodeBase)
{
  __shared__ unsigned short Al[128 * 40];
  __shared__ unsigned short Bl[128 * 40];
  const int logical = xcd_swz(blockIdx.x, gridDim.x);
  const int bm = (logical / 6) * 128;
  const int bn = (logical % 6) * 128;

  const int tid = threadIdx.x;
  const int lane = tid & 63;
  const int wv = tid >> 6;
  const int wm = (wv >> 1) * 64;
  const int wn = (wv & 1) * 64;
  const int s_row = tid >> 1;
  const int s_cb = (tid & 1) * 16;
  const int grow = bm + s_row;
  const float* Arow = nullptr;
  if (grow < M) {
    const int slot = grow % 3;
    const int node = nodeBase + grow / 3;
    const float* srcp = (slot == 0 ? env : (slot == 1 ? infra : robot));
    Arow = srcp + (size_t)node * 256;
  }

  f32x4 acc[4][4] = {};
  const int l15 = lane & 15;
  const int lk = (lane >> 4) * 8;

  for (int k0 = 0; k0 < 256; k0 += 32) {
    unsigned abuf[8];
    if (Arow) {
      const float* p = Arow + k0 + s_cb;
      #pragma unroll
      for (int i = 0; i < 4; ++i) {
        const float4 v = *(const float4*)(p + i * 4);
        abuf[i * 2 + 0] = f2bf2(v.x, v.y);
        abuf[i * 2 + 1] = f2bf2(v.z, v.w);
      }
    } else {
      #pragma unroll
      for (int i = 0; i < 8; ++i) abuf[i] = 0;
    }
    *(uint4*)&Al[s_row * 40 + s_cb] = *(uint4*)&abuf[0];
    *(uint4*)&Al[s_row * 40 + s_cb + 8] = *(uint4*)&abuf[4];
    #pragma unroll
    for (int i = 0; i < 2; ++i) {
      const int task = tid + i * 256;     // 0..511
      const int col = task >> 2;
      const int ks = (task & 3) * 8;
      *(uint4*)&Bl[col * 40 + ks] = *(const uint4*)(Wt + (size_t)(bn + col) * 256 + k0 + ks);
    }
    __syncthreads();
    bf16x8 af[4], bfr[4];
    #pragma unroll
    for (int m = 0; m < 4; ++m)
      af[m] = *(const bf16x8*)&Al[(wm + m * 16 + l15) * 40 + lk];
    #pragma unroll
    for (int n = 0; n < 4; ++n)
      bfr[n] = *(const bf16x8*)&Bl[(wn + n * 16 + l15) * 40 + lk];
    #pragma unroll
    for (int m = 0; m < 4; ++m)
      #pragma unroll
      for (int n = 0; n < 4; ++n)
        acc[m][n] = __builtin_amdgcn_mfma_f32_16x16x32_bf16(af[m], bfr[n], acc[m][n], 0, 0, 0);
    __syncthreads();
  }
  const int r4 = (lane >> 4) * 4;
  #pragma unroll
  for (int m = 0; m < 4; ++m) {
    #pragma unroll
    for (int n = 0; n < 4; ++n) {
      const int col = bn + wn + n * 16 + l15;
      const float bv = bias[col];
      #pragma unroll
      for (int r = 0; r < 4; ++r) {
        const int row = bm + wm + m * 16 + r4 + r;
        if (row >= M) continue;
        Cb[(size_t)row * 768 + col] = f2bf(acc[m][n][r] + bv);
      }
    }
  }
}

// ---------------------------------------------------------------------------
// Fused LSTM step (1-D grid + XCD swizzle, nbx=16): gates = [gat_t|h] @ Wt_perm
// (kEnd=512; 256 at t=0), newcol = d*4+gate; LSTM pointwise in epilogue.
// hcMask: bit0 = store fp32 h (only needed at final t), bit1 = store c (not
// needed at final t). hb always written. hbIn/hbOut MUST differ.
// ---------------------------------------------------------------------------
__global__ __launch_bounds__(256) void gemm_lstm_k(
    const unsigned short* __restrict__ gatall, const unsigned short* __restrict__ hbIn,
    const unsigned short* __restrict__ Wt, const float* __restrict__ b_lstm,
    float* __restrict__ h, float* __restrict__ c, unsigned short* __restrict__ hbOut,
    int t, int kEnd, int hcMask)
{
  __shared__ float Gl[128][65];
  unsigned short* Al = (unsigned short*)&Gl[0][0];
  unsigned short* Bl = Al + 128 * 40;
  const int tid = threadIdx.x;
  const int logical = xcd_swz(blockIdx.x, gridDim.x);
  const int bm = (logical / 16) * 128;
  const int bn = (logical % 16) * 64;
  const int lane = tid & 63;
  const int wv = tid >> 6;
  const int wm = (wv >> 1) * 64;
  const int wn = (wv & 1) * 32;
  const int s_row = tid >> 1;
  const int s_cb = (tid & 1) * 16;
  const int grow = bm + s_row;
  const unsigned short* Arow1 = nullptr;
  const unsigned short* Arow2 = nullptr;
  if (grow < 12000) {
    const int phys = (grow / N_) * (T_ * N_) + t * N_ + (grow % N_);
    Arow1 = gatall + (size_t)phys * 256;
    Arow2 = hbIn + (size_t)grow * 256;
  }
  const int b_col = tid >> 2;
  const int b_ks = (tid & 3) * 8;
  const unsigned short* Wrow = Wt + (size_t)(bn + b_col) * 512 + b_ks;

  f32x4 acc[4][2] = {};
  const int l15 = lane & 15;
  const int lk = (lane >> 4) * 8;

  for (int k0 = 0; k0 < kEnd; k0 += 32) {
    uint4 a0, a1;
    if (Arow1) {
      const unsigned short* p = (k0 < 256) ? (Arow1 + k0 + s_cb)
                                           : (Arow2 + (k0 - 256) + s_cb);
      a0 = *(const uint4*)p;
      a1 = *(const uint4*)(p + 8);
    } else {
      a0 = make_uint4(0, 0, 0, 0);
      a1 = a0;
    }
    *(uint4*)&Al[s_row * 40 + s_cb] = a0;
    *(uint4*)&Al[s_row * 40 + s_cb + 8] = a1;
    *(uint4*)&Bl[b_col * 40 + b_ks] = *(const uint4*)(Wrow + k0);
    __syncthreads();
    bf16x8 af[4], bfr[2];
    #pragma unroll
    for (int m = 0; m < 4; ++m)
      af[m] = *(const bf16x8*)&Al[(wm + m * 16 + l15) * 40 + lk];
    #pragma unroll
    for (int n = 0; n < 2; ++n)
      bfr[n] = *(const bf16x8*)&Bl[(wn + n * 16 + l15) * 40 + lk];
    #pragma unroll
    for (int m = 0; m < 4; ++m)
      #pragma unroll
      for (int n = 0; n < 2; ++n)
        acc[m][n] = __builtin_amdgcn_mfma_f32_16x16x32_bf16(af[m], bfr[n], acc[m][n], 0, 0, 0);
    __syncthreads();
  }
  const int r4 = (lane >> 4) * 4;
  #pragma unroll
  for (int m = 0; m < 4; ++m)
    #pragma unroll
    for (int n = 0; n < 2; ++n) {
      const int col = wn + n * 16 + l15;
      #pragma unroll
      for (int r = 0; r < 4; ++r)
        Gl[wm + m * 16 + r4 + r][col] = acc[m][n][r];
    }
  __syncthreads();
  const int fl = lane & 7;
  const int rg = lane >> 3;
  const int dg = ((bn + wn) >> 2) + fl;
  const float bi = b_lstm[dg];
  const float bff = b_lstm[256 + dg];
  const float bg = b_lstm[512 + dg];
  const float bo = b_lstm[768 + dg];
  const int colb = wn + fl * 4;
  #pragma unroll
  for (int i = 0; i < 8; ++i) {
    const int rl = rg + i * 8;
    const int row = bm + wm + rl;
    if (row >= 12000) continue;
    const float g0 = Gl[wm + rl][colb + 0] + bi;
    const float g1 = Gl[wm + rl][colb + 1] + bff;
    const float g2 = Gl[wm + rl][colb + 2] + bg;
    const float g3 = Gl[wm + rl][colb + 3] + bo;
    const size_t idx = (size_t)row * 256 + dg;
    const float cn = sigm_(g1) * c[idx] + sigm_(g0) * tanhf(g2);
    if (hcMask & 2) c[idx] = cn;
    const float hn = sigm_(g3) * tanhf(cn);
    if (hcMask & 1) h[idx] = hn;
    hbOut[idx] = f2bf(hn);
  }
}

// ---------------------------------------------------------------------------
// Edge-head GEMM with fused ef gather (1-D grid + XCD swizzle, nbx=2):
// A row r = concat(hb[b,src[e]], hb[b,dst[e]]). K=512, N=128, relu, fp32 out.
// ---------------------------------------------------------------------------
__global__ __launch_bounds__(256) void gemm_ef_k(
    const unsigned short* __restrict__ hb, const int* __restrict__ srcA,
    const int* __restrict__ dstA, const unsigned short* __restrict__ Wt,
    const float* __restrict__ bias, float* __restrict__ Cf)
{
  __shared__ unsigned short Al[128 * 40];
  __shared__ unsigned short Bl[64 * 40];
  const int tid = threadIdx.x;
  const int logical = xcd_swz(blockIdx.x, gridDim.x);
  const int bm = (logical >> 1) * 128;
  const int bn = (logical & 1) * 64;
  const int lane = tid & 63;
  const int wv = tid >> 6;
  const int wm = (wv >> 1) * 64;
  const int wn = (wv & 1) * 32;
  const int s_row = tid >> 1;
  const int s_cb = (tid & 1) * 16;
  const int grow = bm + s_row;
  const unsigned short* Arow1 = nullptr;
  const unsigned short* Arow2 = nullptr;
  if (grow < 48000) {
    const int b = grow / E_;
    const int e = grow - b * E_;
    Arow1 = hb + ((size_t)(b * N_ + srcA[e])) * 256;
    Arow2 = hb + ((size_t)(b * N_ + dstA[e])) * 256;
  }
  const int b_col = tid >> 2;
  const int b_ks = (tid & 3) * 8;
  const unsigned short* Wrow = Wt + (size_t)(bn + b_col) * 512 + b_ks;

  f32x4 acc[4][2] = {};
  const int l15 = lane & 15;
  const int lk = (lane >> 4) * 8;

  for (int k0 = 0; k0 < 512; k0 += 32) {
    uint4 a0, a1;
    if (Arow1) {
      const unsigned short* p = (k0 < 256) ? (Arow1 + k0 + s_cb)
                                           : (Arow2 + (k0 - 256) + s_cb);
      a0 = *(const uint4*)p;
      a1 = *(const uint4*)(p + 8);
    } else {
      a0 = make_uint4(0, 0, 0, 0);
      a1 = a0;
    }
    *(uint4*)&Al[s_row * 40 + s_cb] = a0;
    *(uint4*)&Al[s_row * 40 + s_cb + 8] = a1;
    *(uint4*)&Bl[b_col * 40 + b_ks] = *(const uint4*)(Wrow + k0);
    __syncthreads();
    bf16x8 af[4], bfr[2];
    #pragma unroll
    for (int m = 0; m < 4; ++m)
      af[m] = *(const bf16x8*)&Al[(wm + m * 16 + l15) * 40 + lk];
    #pragma unroll
    for (int n = 0; n < 2; ++n)
      bfr[n] = *(const bf16x8*)&Bl[(wn + n * 16 + l15) * 40 + lk];
    #pragma unroll
    for (int m = 0; m < 4; ++m)
      #pragma unroll
      for (int n = 0; n < 2; ++n)
        acc[m][n] = __builtin_amdgcn_mfma_f32_16x16x32_bf16(af[m], bfr[n], acc[m][n], 0, 0, 0);
    __syncthreads();
  }
  const int r4 = (lane >> 4) * 4;
  #pragma unroll
  for (int m = 0; m < 4; ++m) {
    #pragma unroll
    for (int n = 0; n < 2; ++n) {
      const int col = bn + wn + n * 16 + l15;
      const float bv = bias[col];
      #pragma unroll
      for (int r = 0; r < 4; ++r) {
        const int row = bm + wm + m * 16 + r4 + r;
        if (row >= 48000) continue;
        Cf[(size_t)row * 128 + col] = fmaxf(acc[m][n][r] + bv, 0.f);
      }
    }
  }
}

// ---------------------------------------------------------------------------
// fp32 fallback GEMM (only the K=8 edge-emb GEMM); flags&4 -> bf16 C store
// ---------------------------------------------------------------------------
__global__ __launch_bounds__(256) void gemm_k(
    const float* __restrict__ A, const float* __restrict__ W,
    const float* __restrict__ bias, void* __restrict__ Cv,
    int M, int N, int K, int lda, int flags)
{
  __shared__ float As[16][68];
  __shared__ float Ws[16][64];
  const int tid = threadIdx.x;
  const int bm = blockIdx.y * 64;
  const int bn = blockIdx.x * 64;
  const int tx = tid & 15;
  const int ty = tid >> 4;
  const int ar = tid >> 2;
  const int ac = (tid & 3) << 2;
  const int wr = tid >> 4;
  const int wc = (tid & 15) << 2;
  const int grow = bm + ar;
  const float* Arow = (grow < M) ? A + (size_t)grow * lda : nullptr;
  float acc[4][4] = {};
  for (int k0 = 0; k0 < K; k0 += 16) {
    float4 av = make_float4(0.f, 0.f, 0.f, 0.f);
    if (Arow) {
      av.x = (k0 + ac + 0 < K) ? Arow[k0 + ac + 0] : 0.f;
      av.y = (k0 + ac + 1 < K) ? Arow[k0 + ac + 1] : 0.f;
      av.z = (k0 + ac + 2 < K) ? Arow[k0 + ac + 2] : 0.f;
      av.w = (k0 + ac + 3 < K) ? Arow[k0 + ac + 3] : 0.f;
    }
    As[ac + 0][ar] = av.x;
    As[ac + 1][ar] = av.y;
    As[ac + 2][ar] = av.z;
    As[ac + 3][ar] = av.w;
    float4 wv = make_float4(0.f, 0.f, 0.f, 0.f);
    if (k0 + wr < K) {
      const int gc = bn + wc;
      const float* wp = W + (size_t)(k0 + wr) * N + gc;
      wv.x = (gc + 0 < N) ? wp[0] : 0.f;
      wv.y = (gc + 1 < N) ? wp[1] : 0.f;
      wv.z = (gc + 2 < N) ? wp[2] : 0.f;
      wv.w = (gc + 3 < N) ? wp[3] : 0.f;
    }
    *(float4*)&Ws[wr][wc] = wv;
    __syncthreads();
    #pragma unroll
    for (int kk = 0; kk < 16; ++kk) {
      const float4 a = *(const float4*)&As[kk][ty << 2];
      const float4 b = *(const float4*)&Ws[kk][tx << 2];
      acc[0][0] += a.x * b.x; acc[0][1] += a.x * b.y; acc[0][2] += a.x * b.z; acc[0][3] += a.x * b.w;
      acc[1][0] += a.y * b.x; acc[1][1] += a.y * b.y; acc[1][2] += a.y * b.z; acc[1][3] += a.y * b.w;
      acc[2][0] += a.z * b.x; acc[2][1] += a.z * b.y; acc[2][2] += a.z * b.z; acc[2][3] += a.z * b.w;
      acc[3][0] += a.w * b.x; acc[3][1] += a.w * b.y; acc[3][2] += a.w * b.z; acc[3][3] += a.w * b.w;
    }
    __syncthreads();
  }
  float* Cf = (float*)Cv;
  unsigned short* Cb = (unsigned short*)Cv;
  #pragma unroll
  for (int i = 0; i < 4; ++i) {
    const int row = bm + (ty << 2) + i;
    if (row >= M) continue;
    #pragma unroll
    for (int j = 0; j < 4; ++j) {
      const int col = bn + (tx << 2) + j;
      if (col >= N) continue;
      float v = acc[i][j];
      if (bias) v += bias[col];
      if (flags & 2) v = fmaxf(v, 0.f);
      const size_t ci = (size_t)row * N + col;
      if (flags & 4) Cb[ci] = f2bf(v);
      else Cf[ci] = v;
    }
  }
}

// ---------------------------------------------------------------------------
// Stage A attention: ONE WAVE PER NODE (coalesced). Lane l -> head l>>3,
// elems (l&7)*4; qkv offset = node*2304 + 4*l. 9 dots reduce over the 8-lane
// subgroup via shfl_xor(1,2,4). 4 waves/block.
// ---------------------------------------------------------------------------
__global__ __launch_bounds__(256) void attn_avg_k(
    const unsigned short* __restrict__ qkv,
    unsigned short* __restrict__ obar, int nodes)
{
  const int node = blockIdx.x * 4 + (threadIdx.x >> 6);
  if (node >= nodes) return;
  const int lane = threadIdx.x & 63;
  const unsigned short* base = qkv + (size_t)node * 2304 + lane * 4;
  float qv[3][4], kv[3][4], vv[3][4];
  #pragma unroll
  for (int s = 0; s < 3; ++s) {
    const uint2 uq = *(const uint2*)(base + s * 768);
    const uint2 uk = *(const uint2*)(base + s * 768 + 256);
    const uint2 uv = *(const uint2*)(base + s * 768 + 512);
    qv[s][0] = bfl(uq.x); qv[s][1] = bfh(uq.x); qv[s][2] = bfl(uq.y); qv[s][3] = bfh(uq.y);
    kv[s][0] = bfl(uk.x); kv[s][1] = bfh(uk.x); kv[s][2] = bfl(uk.y); kv[s][3] = bfh(uk.y);
    vv[s][0] = bfl(uv.x); vv[s][1] = bfh(uv.x); vv[s][2] = bfl(uv.y); vv[s][3] = bfh(uv.y);
  }
  float att[3][3];
  #pragma unroll
  for (int s = 0; s < 3; ++s) {
    #pragma unroll
    for (int t = 0; t < 3; ++t) {
      float d = qv[s][0] * kv[t][0] + qv[s][1] * kv[t][1]
              + qv[s][2] * kv[t][2] + qv[s][3] * kv[t][3];
      d += __shfl_xor(d, 1, 64);
      d += __shfl_xor(d, 2, 64);
      d += __shfl_xor(d, 4, 64);
      att[s][t] = d * 0.17677669529663687f;
    }
  }
  float cs[3] = {0.f, 0.f, 0.f};
  #pragma unroll
  for (int s = 0; s < 3; ++s) {
    const float m = fmaxf(att[s][0], fmaxf(att[s][1], att[s][2]));
    const float e0 = expf(att[s][0] - m);
    const float e1 = expf(att[s][1] - m);
    const float e2 = expf(att[s][2] - m);
    const float inv = (1.f / 3.f) / (e0 + e1 + e2);
    cs[0] += e0 * inv; cs[1] += e1 * inv; cs[2] += e2 * inv;
  }
  float o0 = cs[0] * vv[0][0] + cs[1] * vv[1][0] + cs[2] * vv[2][0];
  float o1 = cs[0] * vv[0][1] + cs[1] * vv[1][1] + cs[2] * vv[2][1];
  float o2 = cs[0] * vv[0][2] + cs[1] * vv[1][2] + cs[2] * vv[2][2];
  float o3 = cs[0] * vv[0][3] + cs[1] * vv[1][3] + cs[2] * vv[2][3];
  uint2 ob;
  ob.x = f2bf2(o0, o1);
  ob.y = f2bf2(o2, o3);
  *(uint2*)(obar + (size_t)node * 256 + lane * 4) = ob;
}

// LayerNorm per row; bf16 in, bf16 out. 1 wave per row.
__global__ __launch_bounds__(64) void ln_k(
    const unsigned short* __restrict__ in, const float* __restrict__ g,
    const float* __restrict__ bta, unsigned short* __restrict__ outp)
{
  const int row = blockIdx.x;
  const int d0 = threadIdx.x << 2;
  const uint2 a = *(const uint2*)(in + (size_t)row * 256 + d0);
  float x[4] = { bfl(a.x), bfh(a.x), bfl(a.y), bfh(a.y) };
  float s = x[0] + x[1] + x[2] + x[3];
  s = wred_(s);
  const float mean = s * (1.f / 256.f);
  float vs = 0.f;
  #pragma unroll
  for (int i = 0; i < 4; ++i) { const float dd = x[i] - mean; vs += dd * dd; }
  vs = wred_(vs);
  const float inv = 1.0f / sqrtf(vs * (1.f / 256.f) + 1e-5f);
  const float4 gv = *(const float4*)(g + d0);
  const float4 bv = *(const float4*)(bta + d0);
  uint2 o;
  o.x = f2bf2((x[0] - mean) * inv * gv.x + bv.x, (x[1] - mean) * inv * gv.y + bv.y);
  o.y = f2bf2((x[2] - mean) * inv * gv.z + bv.z, (x[3] - mean) * inv * gv.w + bv.w);
  *(uint2*)(outp + (size_t)row * 256 + d0) = o;
}

// ---------------------------------------------------------------------------
// GAT kernels (bf16 feature inputs)
// ---------------------------------------------------------------------------
__global__ void alphas_k(const unsigned short* __restrict__ xw, const float* __restrict__ as,
                         const float* __restrict__ ad, float* __restrict__ sal,
                         float* __restrict__ dal, int rows)
{
  const int idx = blockIdx.x * blockDim.x + threadIdx.x;
  if (idx >= rows * 8) return;
  const int row = idx >> 3, h = idx & 7;
  const unsigned short* x = xw + (size_t)row * 256 + h * 32;
  const float* a1 = as + h * 32;
  const float* a2 = ad + h * 32;
  float s = 0.f, d = 0.f;
  #pragma unroll
  for (int i = 0; i < 4; ++i) {
    const uint4 ux = *(const uint4*)(x + i * 8);
    const unsigned* p = &ux.x;
    #pragma unroll
    for (int j = 0; j < 4; ++j) {
      const float lo = bfl(p[j]), hi = bfh(p[j]);
      s += lo * a1[i * 8 + 2 * j] + hi * a1[i * 8 + 2 * j + 1];
      d += lo * a2[i * 8 + 2 * j] + hi * a2[i * 8 + 2 * j + 1];
    }
  }
  sal[idx] = s; dal[idx] = d;
}

// all 4 edge-logit sets in one launch; ew is [48000][1024] (4 x 256 packed)
__global__ void elog4_k(const unsigned short* __restrict__ ew,
                        const float* __restrict__ tg_ae, const float* __restrict__ g_ae,
                        float* __restrict__ el)
{
  const int idx = blockIdx.x * blockDim.x + threadIdx.x;
  if (idx >= 4 * 48000 * 8) return;
  const int l = idx / (48000 * 8);
  const int r = idx - l * (48000 * 8);
  const int row = r >> 3, h = r & 7;
  const unsigned short* x = ew + (size_t)row * 1024 + l * 256 + h * 32;
  const float* a1 = (l == 0 ? tg_ae : g_ae + (l - 1) * 256) + h * 32;
  float s = 0.f;
  #pragma unroll
  for (int i = 0; i < 4; ++i) {
    const uint4 ux = *(const uint4*)(x + i * 8);
    const unsigned* p = &ux.x;
    #pragma unroll
    for (int j = 0; j < 4; ++j) {
      s += bfl(p[j]) * a1[i * 8 + 2 * j] + bfh(p[j]) * a1[i * 8 + 2 * j + 1];
    }
  }
  el[l * 384000 + r] = s;
}

// Fused GAT aggregation: one wave per (beta,node). Online softmax over incoming
// edges (CSR). bf16 gathers. OUTBF: 1 -> bf16 out, 0 -> fp32 out.
template<int OUTBF>
__global__ __launch_bounds__(256) void gat_k(
    const unsigned short* __restrict__ xw, const unsigned short* __restrict__ ew,
    const float* __restrict__ sal, const float* __restrict__ dal,
    const float* __restrict__ el, const int* __restrict__ roff,
    const int* __restrict__ eord, const int* __restrict__ srcArr,
    void* __restrict__ outp, int nwaves, int tshift, int ewStride, int ewOff)
{
  const int wid = blockIdx.x * 4 + (threadIdx.x >> 6);
  if (wid >= nwaves) return;
  const int beta = wid / N_;
  const int n = wid - beta * N_;
  const int b = beta >> tshift;
  const int lane = threadIdx.x & 63;
  const int h = lane >> 3;
  const int d0 = lane << 2;
  const float dal_h = dal[(size_t)wid * 8 + h];
  const int p0 = roff[n], p1 = roff[n + 1];
  float m = -1e30f, s = 0.f;
  float4 acc = make_float4(0.f, 0.f, 0.f, 0.f);
  for (int p = p0; p < p1; ++p) {
    const int e = eord[p];
    const int sc = srcArr[e];
    float lg = sal[((size_t)beta * N_ + sc) * 8 + h] + dal_h + el[((size_t)b * E_ + e) * 8 + h];
    lg = lg > 0.f ? lg : 0.2f * lg;
    const float mn = fmaxf(m, lg);
    const float scale = expf(m - mn);
    const float w = expf(lg - mn);
    s = s * scale + w;
    const uint2 ux = *(const uint2*)(xw + ((size_t)beta * N_ + sc) * 256 + d0);
    const uint2 ue = *(const uint2*)(ew + ((size_t)(b * E_ + e)) * ewStride + ewOff + d0);
    acc.x = acc.x * scale + w * (bfl(ux.x) + bfl(ue.x));
    acc.y = acc.y * scale + w * (bfh(ux.x) + bfh(ue.x));
    acc.z = acc.z * scale + w * (bfl(ux.y) + bfl(ue.y));
    acc.w = acc.w * scale + w * (bfh(ux.y) + bfh(ue.y));
    m = mn;
  }
  const float inv = 1.0f / (s + 1e-16f);
  if (OUTBF) {
    uint2 o;
    o.x = f2bf2(acc.x * inv, acc.y * inv);
    o.y = f2bf2(acc.z * inv, acc.w * inv);
    *(uint2*)((unsigned short*)outp + (size_t)wid * 256 + d0) = o;
  } else {
    *(float4*)((float*)outp + (size_t)wid * 256 + d0) =
        make_float4(acc.x * inv, acc.y * inv, acc.z * inv, acc.w * inv);
  }
}

// h = LN(h + add); writes fp32 h and bf16 hb
__global__ __launch_bounds__(64) void resln_k(float* __restrict__ h,
                                              const float* __restrict__ add,
                                              const float* __restrict__ g,
                                              const float* __restrict__ bta,
                                              unsigned short* __restrict__ hb)
{
  const int row = blockIdx.x;
  const int d0 = threadIdx.x << 2;
  float* hp = h + (size_t)row * 256;
  const float4 hv = *(const float4*)(hp + d0);
  const float4 av = *(const float4*)(add + (size_t)row * 256 + d0);
  float x[4] = { hv.x + av.x, hv.y + av.y, hv.z + av.z, hv.w + av.w };
  float s = x[0] + x[1] + x[2] + x[3];
  s = wred_(s);
  const float mean = s * (1.f / 256.f);
  float vs = 0.f;
  #pragma unroll
  for (int i = 0; i < 4; ++i) { const float dd = x[i] - mean; vs += dd * dd; }
  vs = wred_(vs);
  const float inv = 1.0f / sqrtf(vs * (1.f / 256.f) + 1e-5f);
  const float4 gv = *(const float4*)(g + d0);
  const float4 bv = *(const float4*)(bta + d0);
  float o0 = (x[0] - mean) * inv * gv.x + bv.x;
  float o1 = (x[1] - mean) * inv * gv.y + bv.y;
  float o2 = (x[2] - mean) * inv * gv.z + bv.z;
  float o3 = (x[3] - mean) * inv * gv.w + bv.w;
  *(float4*)(hp + d0) = make_float4(o0, o1, o2, o3);
  uint2 ob;
  ob.x = f2bf2(o0, o1);
  ob.y = f2bf2(o2, o3);
  *(uint2*)(hb + (size_t)row * 256 + d0) = ob;
}

// ---------------------------------------------------------------------------
// Head kernels
// ---------------------------------------------------------------------------
__global__ void nh2_k(const float* __restrict__ hidden, const float* __restrict__ w2,
                      const float* __restrict__ b2, float* __restrict__ outp)
{
  const int idx = blockIdx.x * blockDim.x + threadIdx.x;
  if (idx >= B_ * N_ * 7) return;
  const int row = idx / 7, j = idx % 7;
  const float* hp = hidden + (size_t)row * 448 + j * 64;
  const float* wp = w2 + j * 64;
  float a = 0.f;
  #pragma unroll
  for (int u = 0; u < 64; ++u) a += hp[u] * wp[u];
  a += b2[j];
  if (j == 0 || j == 6) a = sigm_(a);
  else if (j == 1) a = softplus_(a);
  const int b = row / N_, n = row % N_;
  outp[(size_t)b * OUTS_ + n * 7 + j] = a;
}

// two-stage deterministic h_global mean
__global__ __launch_bounds__(256) void hglob1_k(const float* __restrict__ h,
                                                float* __restrict__ hgp)
{
  const int b = blockIdx.x;
  const int seg = blockIdx.y;
  const int d = threadIdx.x;
  float s = 0.f;
  const int n0 = seg * 120;
  for (int n = n0; n < n0 + 120; ++n)
    s += h[((size_t)(b * N_ + n)) * 256 + d];
  hgp[((size_t)(b * 25 + seg)) * 256 + d] = s;
}

__global__ __launch_bounds__(256) void hglob2_k(const float* __restrict__ hgp,
                                                float* __restrict__ hg)
{
  const int b = blockIdx.x;
  const int d = threadIdx.x;
  float s = 0.f;
  for (int i = 0; i < 25; ++i) s += hgp[((size_t)(b * 25 + i)) * 256 + d];
  hg[b * 256 + d] = s * (1.f / (float)N_);
}

__global__ __launch_bounds__(64) void freq_k(const float* __restrict__ hg,
                                             const float* __restrict__ w1, const float* __restrict__ b1,
                                             const float* __restrict__ w2, const float* __restrict__ b2,
                                             float* __restrict__ outp)
{
  const int b = blockIdx.x;
  const int u = threadIdx.x;
  float a = b1[u];
  for (int k = 0; k < 256; ++k) a += hg[b * 256 + k] * w1[k * 64 + u];
  a = fmaxf(a, 0.f) * w2[u];
  a = wred_(a);
  if (u == 0) outp[(size_t)b * OUTS_ + 45000] = a + b2[0];
}

__global__ void eh2_k(const float* __restrict__ hidden, const float* __restrict__ w2,
                      const float* __restrict__ b2, float* __restrict__ outp)
{
  const int idx = blockIdx.x * blockDim.x + threadIdx.x;
  if (idx >= 2 * B_ * E_) return;
  const int jj = idx / (B_ * E_);
  const int r = idx - jj * (B_ * E_);
  const int b = r / E_, e = r % E_;
  const float* hp = hidden + (size_t)r * 128 + jj * 64;
  const float* wp = w2 + jj * 64;
  float a = 0.f;
  #pragma unroll
  for (int u = 0; u < 64; ++u) a += hp[u] * wp[u];
  a += b2[jj];
  outp[(size_t)b * OUTS_ + 21000 + jj * 12000 + e] = a;
}

// ---------------------------------------------------------------------------
extern "C" void kernel_launch(void* const* d_in, const int* in_sizes, int n_in,
                              void* d_out, int out_size, void* d_ws, size_t ws_size,
                              hipStream_t stream)
{
  const float* env      = (const float*)d_in[0];
  const float* infra    = (const float*)d_in[1];
  const float* robot    = (const float*)d_in[2];
  const float* edgeattr = (const float*)d_in[3];
  const int*   eidx     = (const int*)d_in[4];
  const float* wqkv     = (const float*)d_in[5];
  const float* bqkv     = (const float*)d_in[6];
  const float* wo       = (const float*)d_in[7];
  const float* bo       = (const float*)d_in[8];
  const float* lnf_g    = (const float*)d_in[9];
  const float* lnf_b    = (const float*)d_in[10];
  const float* we_emb   = (const float*)d_in[11];
  const float* be_emb   = (const float*)d_in[12];
  const float* tg_W     = (const float*)d_in[13];
  const float* tg_We    = (const float*)d_in[14];
  const float* tg_asrc  = (const float*)d_in[15];
  const float* tg_adst  = (const float*)d_in[16];
  const float* tg_aedge = (const float*)d_in[17];
  const float* w_ih     = (const float*)d_in[18];
  const float* w_hh     = (const float*)d_in[19];
  const float* b_lstm   = (const float*)d_in[20];
  const float* g_W      = (const float*)d_in[21];
  const float* g_We     = (const float*)d_in[22];
  const float* g_asrc   = (const float*)d_in[23];
  const float* g_adst   = (const float*)d_in[24];
  const float* g_aedge  = (const float*)d_in[25];
  const float* g_lng    = (const float*)d_in[26];
  const float* g_lnb    = (const float*)d_in[27];
  const float* hn_w1    = (const float*)d_in[28];
  const float* hn_b1    = (const float*)d_in[29];
  const float* hn_w2    = (const float*)d_in[30];
  const float* hn_b2    = (const float*)d_in[31];
  const float* he_w1    = (const float*)d_in[32];
  const float* he_b1    = (const float*)d_in[33];
  const float* he_w2    = (const float*)d_in[34];
  const float* he_b2    = (const float*)d_in[35];

  const int* src = eidx;
  const int* dst = eidx + E_;
  float* outp = (float*)d_out;
  float* ws = (float*)d_ws;

  // ---- bf16 transposed weights at ws start (short offsets) ----
  unsigned short* wtb0 = (unsigned short*)ws;
  unsigned short* wt_qkv  = wtb0;               // 196,608
  unsigned short* wt_wo   = wtb0 + 196608;      //  65,536
  unsigned short* wt_tgW  = wtb0 + 262144;      //  65,536
  unsigned short* wt_tgWe = wtb0 + 327680;      //  65,536  (rows 0..255 of edge-cat)
  unsigned short* wt_gWe  = wtb0 + 393216;      // 196,608  (rows 256..1023, contiguous)
  unsigned short* wt_lstm = wtb0 + 589824;      // 524,288  permuted [1024][512]
  unsigned short* wt_gW   = wtb0 + 1114112;     // 196,608
  unsigned short* wt_hn   = wtb0 + 1310720;     // 114,688
  unsigned short* wt_he   = wtb0 + 1425408;     //  65,536

  // ---- dynamic regions (float-unit offsets from D0) ----
  const size_t D0 = 1600000;
  // stage A (4 chunks of 24000 nodes):
  unsigned short* qkvb  = (unsigned short*)(ws + D0);              // 27.648M f (72000x768)
  unsigned short* tmpAb = qkvb;                                    // aliases dead qkvb
  unsigned short* obarb = (unsigned short*)(ws + D0 + 27648000);   // 12.288M f
  unsigned short* fseqb = (unsigned short*)(ws + D0 + 39936000);   // 12.288M f -> 52.224M
  // stage B (qkvb/obarb dead; fseqb live until xwall GEMM):
  unsigned short* xwallb  = (unsigned short*)(ws + D0);            // 12.288M f
  unsigned short* gatallb = (unsigned short*)(ws + D0 + 12288000); // 12.288M f
  unsigned short* eembb   = (unsigned short*)(ws + D0 + 24576000); //  6.144M f
  float* h  = ws + D0 + 30720000;                                  //  3.072M
  float* c  = ws + D0 + 33792000;                                  //  3.072M
  unsigned short* hb0 = (unsigned short*)(ws + D0 + 36864000);     //  1.536M f
  unsigned short* hb1 = (unsigned short*)(ws + D0 + 38400000);     //  1.536M f -> 39.936M
  unsigned short* ewall = (unsigned short*)(ws + D0 + 62976000);   // 24.576M f
  float* elogall = ws + D0 + 87552000;         //  1.536M (4 x 384000)
  float* sal     = ws + D0 + 89088000;         //    768,000
  float* dal     = ws + D0 + 89856000;         //    768,000
  int* ideg  = (int*)(ws + D0 + 90624000);
  int* iroff = ideg + 3008;
  int* ieord = iroff + 3008;
  float* hg  = ws + D0 + 90650000;
  float* hgp = ws + D0 + 90652048;
  // GAT-layers phase (fseqb dead by then):
  unsigned short* xw_sb = (unsigned short*)(ws + D0 + 40000000);   // 1.536M f
  float* gat_s = ws + D0 + 41600000;           //  3.072M
  // heads (xwallb/gatallb dead):
  float* hidn = ws + D0;                       //  5.376M
  float* hide = ws + D0 + 17664000;            //  6.144M

  auto mgemm = [&](const unsigned short* A, const unsigned short* Wt, const float* bias,
                   void* C, int M, int N, int K, int lda, int flags) {
    const int nwg = (N / 64) * ((M + 127) / 128);
    gemm_bfa_k<<<nwg, 256, 0, stream>>>(A, Wt, bias, C, M, N, K, lda, flags);
  };

  // ---- ONE weight convert/transpose/permute launch ----
  wtall_k<<<(1490944 + 255) / 256, 256, 0, stream>>>(
      wqkv, wo, tg_W, tg_We, g_We, w_ih, w_hh, g_W, hn_w1, he_w1, wtb0);

  // ---- CSR build (deterministic) ----
  hipMemsetAsync(ideg, 0, 3000 * sizeof(int), stream);
  hist_k<<<(E_ + 255) / 256, 256, 0, stream>>>(dst, ideg);
  scan_k<<<1, 256, 0, stream>>>(ideg, iroff);
  fill_k<<<750, 256, 0, stream>>>(dst, iroff, ieord);

  // ---------------- Stage A: 4 chunks of 24000 nodes ----------------
  for (int chunk = 0; chunk < 4; ++chunk) {
    gemm_qkv_k<<<563 * 6, 256, 0, stream>>>(env, infra, robot, wt_qkv, bqkv,
                                            qkvb, 72000, chunk * 24000);
    attn_avg_k<<<6000, 256, 0, stream>>>(qkvb, obarb + (size_t)chunk * 24000 * 256, 24000);
  }
  // tmpAb (aliases qkvb, dead) = obar @ wo + bo (bf16), then fseq = LN(tmpAb)
  mgemm(obarb, wt_wo, bo, tmpAb, 96000, 256, 256, 256, 4);
  ln_k<<<96000, 64, 0, stream>>>(tmpAb, lnf_g, lnf_b, fseqb);

  // ---------------- Stage B prep ----------------
  {  // edge_emb = relu(edge_attr @ we_emb + be_emb) -> bf16
    dim3 grid(4, 750);
    gemm_k<<<grid, dim3(256), 0, stream>>>(edgeattr, we_emb, be_emb, eembb,
                                           48000, 256, 8, 8, 2 | 4);
  }
  // one batched edge-transform GEMM: [tgWe | gWe0 | gWe1 | gWe2], N=1024
  mgemm(eembb, wt_tgWe, nullptr, ewall, 48000, 1024, 256, 256, 4);
  elog4_k<<<6000, 256, 0, stream>>>(ewall, tg_aedge, g_aedge, elogall);

  mgemm(fseqb, wt_tgW, nullptr, xwallb, 96000, 256, 256, 256, 4);
  alphas_k<<<3000, 256, 0, stream>>>(xwallb, tg_asrc, tg_adst, sal, dal, 96000);
  gat_k<1><<<24000, 256, 0, stream>>>(xwallb, ewall, sal, dal, elogall, iroff, ieord,
                                      src, gatallb, 96000, 3, 1024, 0);

  // ---------------- LSTM over T (fused GEMM + pointwise) ----------------
  hipMemsetAsync(c, 0, 12288000, stream);
  unsigned short* hbq[2] = { hb0, hb1 };
  for (int t = 0; t < T_; ++t) {
    // t=0: h==0 -> K=256 only (exact). h fp32 stored only at final t;
    // c stored only when still needed (t<7).
    const int hcMask = (t == T_ - 1) ? 1 : 2;
    gemm_lstm_k<<<16 * 94, 256, 0, stream>>>(gatallb, hbq[t & 1], wt_lstm, b_lstm,
                                             h, c, hbq[(t + 1) & 1], t,
                                             t == 0 ? 256 : 512, hcMask);
  }
  unsigned short* hbf = hbq[0];  // T=8 even -> final h in hb0

  // ---------------- 3 GAT layers with residual LN ----------------
  for (int l = 0; l < 3; ++l) {
    mgemm(hbf, wt_gW + (size_t)l * 65536, nullptr, xw_sb, 12000, 256, 256, 256, 4);
    alphas_k<<<375, 256, 0, stream>>>(xw_sb, g_asrc + l * 256, g_adst + l * 256, sal, dal, 12000);
    gat_k<0><<<3000, 256, 0, stream>>>(xw_sb, ewall, sal, dal, elogall + 384000 * (l + 1),
                                       iroff, ieord, src, gat_s, 12000, 0,
                                       1024, 256 * (l + 1));
    resln_k<<<12000, 64, 0, stream>>>(h, gat_s, g_lng + l * 256, g_lnb + l * 256, hbf);
  }

  // ---------------- Heads ----------------
  mgemm(hbf, wt_hn, hn_b1, hidn, 12000, 448, 256, 256, 2);
  nh2_k<<<(84000 + 255) / 256, 256, 0, stream>>>(hidn, hn_w2, hn_b2, outp);

  hglob1_k<<<dim3(4, 25), 256, 0, stream>>>(h, hgp);
  hglob2_k<<<4, 256, 0, stream>>>(hgp, hg);
  freq_k<<<4, 64, 0, stream>>>(hg, hn_w1 + 7 * 16384, hn_b1 + 7 * 64,
                               hn_w2 + 7 * 64, hn_b2 + 7, outp);

  // edge heads: fused gather GEMM (no ef buffer)
  gemm_ef_k<<<750, 256, 0, stream>>>(hbf, src, dst, wt_he, he_b1, hide);
  eh2_k<<<(96000 + 255) / 256, 256, 0, stream>>>(hide, he_w2, he_b2, outp);
}